// Round 1
// baseline (1557.351 us; speedup 1.0000x reference)
//
#include <hip/hip_runtime.h>
#include <math.h>

#define TOK   16384
#define DIM   48
#define EMB   256
#define MF    128
#define IMGsz 129

// ---------------- kernel 1: unfold + LN + kqv + prm_exp (16 tokens/block) --------
__global__ __launch_bounds__(256) void k1_unfold_ln_kqv_prm(
    const float* __restrict__ x, const float* __restrict__ g1, const float* __restrict__ b1,
    const float* __restrict__ w_kqv, const float* __restrict__ b_kqv,
    const float* __restrict__ w_prm,
    float* __restrict__ v_out, float* __restrict__ kp_out, float* __restrict__ qp_out)
{
    __shared__ float t_s[16][DIM];
    __shared__ float k_s[16][EMB];
    __shared__ float q_s[16][EMB];
    __shared__ float xd_s[16][2];
    __shared__ float red_s[16][16];

    const int blk = blockIdx.x;
    const int b  = blk >> 10;            // 1024 blocks per batch
    const int t0 = (blk & 1023) << 4;
    const int tid = threadIdx.x;

    // unfold 16 tokens x 48 (c,kh,kw order), pad=1
    for (int e = tid; e < 16*DIM; e += 256) {
        int tok = e / DIM, j = e % DIM;
        int t = t0 + tok;
        int lh = t >> 7, lw = t & 127;
        int c = j >> 4, kh = (j >> 2) & 3, kw = j & 3;
        int ih = lh + kh - 1, iw = lw + kw - 1;
        float val = 0.f;
        if (ih >= 0 && ih < IMGsz && iw >= 0 && iw < IMGsz)
            val = x[((b*3 + c)*IMGsz + ih)*IMGsz + iw];
        t_s[tok][j] = val;
    }
    __syncthreads();
    // LayerNorm over DIM=48, one thread per token
    if (tid < 16) {
        float mu = 0.f;
        for (int j = 0; j < DIM; j++) mu += t_s[tid][j];
        mu *= (1.f/DIM);
        float var = 0.f;
        for (int j = 0; j < DIM; j++) { float dd = t_s[tid][j]-mu; var += dd*dd; }
        var *= (1.f/DIM);
        float inv = rsqrtf(var + 1e-5f);
        for (int j = 0; j < DIM; j++)
            t_s[tid][j] = (t_s[tid][j]-mu)*inv*g1[j] + b1[j];
    }
    __syncthreads();

    // kqv GEMM: thread tid -> columns tid (k), tid+256 (q), tid+512 (v), 16 tokens
    float accK[16], accQ[16], accV[16];
    {
        float bk = b_kqv[tid], bq = b_kqv[tid+EMB], bv = b_kqv[tid+2*EMB];
        #pragma unroll
        for (int i=0;i<16;i++){accK[i]=bk;accQ[i]=bq;accV[i]=bv;}
    }
    for (int d = 0; d < DIM; d++) {
        float wk = w_kqv[d*768 + tid];
        float wq = w_kqv[d*768 + tid + EMB];
        float wv = w_kqv[d*768 + tid + 2*EMB];
        #pragma unroll
        for (int i=0;i<16;i++){
            float h = t_s[i][d];
            accK[i] = fmaf(h, wk, accK[i]);
            accQ[i] = fmaf(h, wq, accQ[i]);
            accV[i] = fmaf(h, wv, accV[i]);
        }
    }
    for (int i=0;i<16;i++){
        k_s[i][tid] = accK[i];
        q_s[i][tid] = accQ[i];
        v_out[((size_t)b*TOK + t0 + i)*EMB + tid] = accV[i];
    }
    __syncthreads();

    // xd = 0.5*|k|^2, 0.5*|q|^2 per token
    {
        int tok = tid >> 4, lane = tid & 15;
        float sk=0.f, sq=0.f;
        for (int j = lane; j < EMB; j += 16) {
            float kv = k_s[tok][j]; sk = fmaf(kv,kv,sk);
            float qv = q_s[tok][j]; sq = fmaf(qv,qv,sq);
        }
        red_s[tok][lane] = sk;
        __syncthreads();
        if (lane == 0) { float s=0; for (int j=0;j<16;j++) s+=red_s[tok][j]; xd_s[tok][0]=0.5f*s; }
        __syncthreads();
        red_s[tok][lane] = sq;
        __syncthreads();
        if (lane == 0) { float s=0; for (int j=0;j<16;j++) s+=red_s[tok][j]; xd_s[tok][1]=0.5f*s; }
    }
    __syncthreads();

    // performer features: waves 0-1 -> kp feature tid; waves 2-3 -> qp feature tid-128
    float acc[16];
    #pragma unroll
    for (int i=0;i<16;i++) acc[i]=0.f;
    const int f = tid & 127;
    const bool isK = tid < 128;
    if (isK) {
        for (int d = 0; d < EMB; d++) {
            float w = w_prm[f*EMB + d];
            #pragma unroll
            for (int i=0;i<16;i++) acc[i] = fmaf(k_s[i][d], w, acc[i]);
        }
    } else {
        for (int d = 0; d < EMB; d++) {
            float w = w_prm[f*EMB + d];
            #pragma unroll
            for (int i=0;i<16;i++) acc[i] = fmaf(q_s[i][d], w, acc[i]);
        }
    }
    const float scale = 0.08838834764831845f;  // 1/sqrt(128)
    float* outp = isK ? kp_out : qp_out;
    for (int i=0;i<16;i++) {
        float xd = xd_s[i][isK ? 0 : 1];
        outp[((size_t)b*TOK + t0 + i)*MF + f] = expf(acc[i]-xd)*scale;
    }
}

// ---------------- kernel 2: ksum[b][m] = sum_t kp[b,t,m] -------------------------
__global__ __launch_bounds__(256) void k2_ksum(const float* __restrict__ kp, float* __restrict__ ksum)
{
    int blk = blockIdx.x;           // 64 blocks: b*16+chunk
    int b = blk >> 4, chunk = blk & 15;
    int m = threadIdx.x & 127, half = threadIdx.x >> 7;
    size_t base = ((size_t)b*TOK + chunk*1024 + half*512)*MF + m;
    float s = 0.f;
    for (int i = 0; i < 512; i++) s += kp[base + (size_t)i*MF];
    atomicAdd(&ksum[b*MF + m], s);
}

// ---------------- kernel 3: kptv[b][n][m] = sum_t v[b,t,n]*kp[b,t,m] -------------
__global__ __launch_bounds__(256) void k3_kptv(const float* __restrict__ v, const float* __restrict__ kp,
                                               float* __restrict__ kptv)
{
    __shared__ float v_s[4][32];
    __shared__ float kp_s[4][MF];
    int blk = blockIdx.x;               // 512 blocks: b(2b) | nt(3b) | tc(4b)
    int b = blk >> 7, nt = (blk >> 4) & 7, tc = blk & 15;
    int tid = threadIdx.x;
    int nl = tid & 31, mg = tid >> 5;   // 32 n-cols x 8 m-groups of 16
    float acc[16];
    #pragma unroll
    for (int i=0;i<16;i++) acc[i]=0.f;
    int t0 = tc * 1024;
    for (int tt = 0; tt < 1024; tt += 4) {
        __syncthreads();
        if (tid < 128) {
            int tok = tid >> 5, j = tid & 31;
            v_s[tok][j] = v[((size_t)b*TOK + t0+tt+tok)*EMB + nt*32 + j];
        }
        for (int e = tid; e < 4*MF; e += 256) {
            int tok = e >> 7, m = e & 127;
            kp_s[tok][m] = kp[((size_t)b*TOK + t0+tt+tok)*MF + m];
        }
        __syncthreads();
        #pragma unroll
        for (int tok=0; tok<4; tok++) {
            float vv = v_s[tok][nl];
            #pragma unroll
            for (int i=0;i<16;i++) acc[i] = fmaf(vv, kp_s[tok][mg*16+i], acc[i]);
        }
    }
    for (int i=0;i<16;i++)
        atomicAdd(&kptv[((size_t)b*EMB + nt*32 + nl)*MF + mg*16 + i], acc[i]);
}

// ---------------- kernel 4: D, attention out, proj, LN, MLP (16 tokens/block) ----
__global__ __launch_bounds__(256) void k4_attn_tail(
    const float* __restrict__ qp, const float* __restrict__ v_in,
    const float* __restrict__ ksum, const float* __restrict__ kptv,
    const float* __restrict__ w_proj, const float* __restrict__ b_proj,
    const float* __restrict__ g2, const float* __restrict__ b2,
    const float* __restrict__ w_mlp1, const float* __restrict__ b_mlp1,
    const float* __restrict__ w_mlp2, const float* __restrict__ b_mlp2,
    float* __restrict__ img)
{
    __shared__ float qp_s[16][MF];
    __shared__ float bufB[16][EMB];   // v  -> h1
    __shared__ float bufC[16][EMB];   // ya -> z
    __shared__ float bufD[16][EMB];   // y2
    __shared__ float red_s[16][16];
    __shared__ float D_s[16], mu_s[16], iv_s[16];

    const int blk = blockIdx.x;
    const int b  = blk >> 10;
    const int t0 = (blk & 1023) << 4;
    const int tid = threadIdx.x;
    const int tok = tid >> 4, lane = tid & 15;

    for (int e = tid; e < 16*MF; e += 256) {
        int tk = e >> 7, m = e & 127;
        qp_s[tk][m] = qp[((size_t)b*TOK + t0 + tk)*MF + m];
    }
    for (int e = tid; e < 16*EMB; e += 256) {
        int tk = e >> 8, n = e & 255;
        bufB[tk][n] = v_in[((size_t)b*TOK + t0 + tk)*EMB + n];
    }
    __syncthreads();
    // D = qp . ksum
    {
        float s = 0.f;
        for (int m = lane; m < MF; m += 16) s = fmaf(qp_s[tok][m], ksum[b*MF+m], s);
        red_s[tok][lane] = s;
        __syncthreads();
        if (lane == 0) { float dd=0; for (int j=0;j<16;j++) dd+=red_s[tok][j]; D_s[tok]=dd+1e-8f; }
        __syncthreads();
    }
    // y_att = (qp @ kptv^T) / D
    {
        float acc[16];
        #pragma unroll
        for (int i=0;i<16;i++) acc[i]=0.f;
        const float4* kvp = (const float4*)(kptv + ((size_t)b*EMB + tid)*MF);
        for (int m4 = 0; m4 < MF/4; m4++) {
            float4 kv = kvp[m4];
            #pragma unroll
            for (int tk=0; tk<16; tk++) {
                acc[tk] = fmaf(qp_s[tk][4*m4+0], kv.x, acc[tk]);
                acc[tk] = fmaf(qp_s[tk][4*m4+1], kv.y, acc[tk]);
                acc[tk] = fmaf(qp_s[tk][4*m4+2], kv.z, acc[tk]);
                acc[tk] = fmaf(qp_s[tk][4*m4+3], kv.w, acc[tk]);
            }
        }
        for (int tk=0; tk<16; tk++) bufC[tk][tid] = acc[tk] / D_s[tk];
    }
    __syncthreads();
    // y2 = v + ya @ w_proj + b_proj
    {
        float acc[16];
        float bp = b_proj[tid];
        #pragma unroll
        for (int i=0;i<16;i++) acc[i]=bp;
        for (int d = 0; d < EMB; d++) {
            float w = w_proj[d*EMB + tid];
            #pragma unroll
            for (int tk=0; tk<16; tk++) acc[tk] = fmaf(bufC[tk][d], w, acc[tk]);
        }
        for (int tk=0; tk<16; tk++) bufD[tk][tid] = bufB[tk][tid] + acc[tk];
    }
    __syncthreads();
    // z = LayerNorm(y2)
    {
        float s = 0.f;
        for (int n = lane; n < EMB; n += 16) s += bufD[tok][n];
        red_s[tok][lane] = s;
        __syncthreads();
        if (lane == 0) { float m=0; for (int j=0;j<16;j++) m+=red_s[tok][j]; mu_s[tok]=m*(1.f/EMB); }
        __syncthreads();
        float mu = mu_s[tok];
        s = 0.f;
        for (int n = lane; n < EMB; n += 16) { float dd = bufD[tok][n]-mu; s = fmaf(dd,dd,s); }
        red_s[tok][lane] = s;
        __syncthreads();
        if (lane == 0) { float vv=0; for (int j=0;j<16;j++) vv+=red_s[tok][j]; iv_s[tok]=rsqrtf(vv*(1.f/EMB)+1e-5f); }
        __syncthreads();
        float gg = g2[tid], bb = b2[tid];
        for (int tk=0; tk<16; tk++)
            bufC[tk][tid] = (bufD[tk][tid]-mu_s[tk])*iv_s[tk]*gg + bb;
    }
    __syncthreads();
    // h1 = gelu(z @ w_mlp1 + b_mlp1)   (exact gelu)
    {
        float acc[16];
        float bm = b_mlp1[tid];
        #pragma unroll
        for (int i=0;i<16;i++) acc[i]=bm;
        for (int d = 0; d < EMB; d++) {
            float w = w_mlp1[d*EMB + tid];
            #pragma unroll
            for (int tk=0; tk<16; tk++) acc[tk] = fmaf(bufC[tk][d], w, acc[tk]);
        }
        for (int tk=0; tk<16; tk++) {
            float a = acc[tk];
            bufB[tk][tid] = 0.5f*a*(1.f+erff(a*0.70710678118654752f));
        }
    }
    __syncthreads();
    // y3 = y2 + h1 @ w_mlp2 + b_mlp2
    {
        float acc[16];
        float bm = b_mlp2[tid];
        #pragma unroll
        for (int i=0;i<16;i++) acc[i]=bm;
        for (int d = 0; d < EMB; d++) {
            float w = w_mlp2[d*EMB + tid];
            #pragma unroll
            for (int tk=0; tk<16; tk++) acc[tk] = fmaf(bufB[tk][d], w, acc[tk]);
        }
        for (int tk=0; tk<16; tk++)
            img[((size_t)b*TOK + t0 + tk)*EMB + tid] = bufD[tk][tid] + acc[tk];
    }
}

// ---------------- kernel 5: [b,t,c] -> [b,c,t] transpose -------------------------
__global__ __launch_bounds__(256) void k5_transpose(const float* __restrict__ img, float* __restrict__ img2)
{
    __shared__ float tile[32][33];
    int blk = blockIdx.x;               // b(2b) | tt(9b) | ct(3b)
    int b = blk >> 12;
    int tt = (blk >> 3) & 511;
    int ct = blk & 7;
    int tid = threadIdx.x;
    int i = tid >> 5, j = tid & 31;     // i in 0..7
    #pragma unroll
    for (int ii = 0; ii < 4; ii++) {
        int row = i + ii*8;
        tile[row][j] = img[((size_t)b*TOK + tt*32 + row)*EMB + ct*32 + j];
    }
    __syncthreads();
    #pragma unroll
    for (int ii = 0; ii < 4; ii++) {
        int row = i + ii*8;
        img2[((size_t)b*EMB + ct*32 + row)*TOK + tt*32 + j] = tile[j][row];
    }
}

// ---------------- kernel 6: bilinear upsample x2, align_corners=True -------------
__global__ __launch_bounds__(256) void k6_upsample(const float* __restrict__ img2, float* __restrict__ out)
{
    int idx = blockIdx.x*256 + threadIdx.x;      // 4*256*256*256 total
    int wo = idx & 255;
    int ho = (idx >> 8) & 255;
    int c  = (idx >> 16) & 255;
    int b  = idx >> 24;
    const float sc = 127.f/255.f;
    float fh = ho * sc; int h0 = (int)fh; if (h0 > 126) h0 = 126; float th = fh - h0;
    float fw = wo * sc; int w0 = (int)fw; if (w0 > 126) w0 = 126; float tw = fw - w0;
    const float* p = img2 + (((size_t)b*EMB + c)*128 + h0)*128 + w0;
    float a00 = p[0], a01 = p[1], a10 = p[128], a11 = p[129];
    float top = fmaf(a01 - a00, tw, a00);
    float bot = fmaf(a11 - a10, tw, a10);
    out[idx] = fmaf(bot - top, th, top);
}

extern "C" void kernel_launch(void* const* d_in, const int* in_sizes, int n_in,
                              void* d_out, int out_size, void* d_ws, size_t ws_size,
                              hipStream_t stream)
{
    const float* x      = (const float*)d_in[0];
    const float* g1     = (const float*)d_in[1];
    const float* b1     = (const float*)d_in[2];
    const float* w_kqv  = (const float*)d_in[3];
    const float* b_kqv  = (const float*)d_in[4];
    const float* w_prm  = (const float*)d_in[5];
    const float* w_proj = (const float*)d_in[6];
    const float* b_proj = (const float*)d_in[7];
    const float* g2     = (const float*)d_in[8];
    const float* b2     = (const float*)d_in[9];
    const float* w_mlp1 = (const float*)d_in[10];
    const float* b_mlp1 = (const float*)d_in[11];
    const float* w_mlp2 = (const float*)d_in[12];
    const float* b_mlp2 = (const float*)d_in[13];
    float* out = (float*)d_out;
    float* ws  = (float*)d_ws;

    // ws layout (floats): v | kp | qp | ksum | kptv | img   (img2 aliases kp+qp)
    float* v_buf  = ws + 0;            // 16,777,216
    float* kp_buf = ws + 16777216;     //  8,388,608
    float* qp_buf = ws + 25165824;     //  8,388,608
    float* img2   = ws + 16777216;     // aliases kp+qp (dead after k4)
    float* ksum   = ws + 33554432;     //        512
    float* kptv   = ws + 33554944;     //    131,072
    float* img    = ws + 33686016;     // 16,777,216   total ~201.9 MB

    hipMemsetAsync(ksum, 0, (512 + 131072)*sizeof(float), stream);
    hipLaunchKernelGGL(k1_unfold_ln_kqv_prm, dim3(4096), dim3(256), 0, stream,
                       x, g1, b1, w_kqv, b_kqv, w_prm, v_buf, kp_buf, qp_buf);
    hipLaunchKernelGGL(k2_ksum, dim3(64), dim3(256), 0, stream, kp_buf, ksum);
    hipLaunchKernelGGL(k3_kptv, dim3(512), dim3(256), 0, stream, v_buf, kp_buf, kptv);
    hipLaunchKernelGGL(k4_attn_tail, dim3(4096), dim3(256), 0, stream,
                       qp_buf, v_buf, ksum, kptv, w_proj, b_proj, g2, b2,
                       w_mlp1, b_mlp1, w_mlp2, b_mlp2, img);
    hipLaunchKernelGGL(k5_transpose, dim3(16384), dim3(256), 0, stream, img, img2);
    hipLaunchKernelGGL(k6_upsample, dim3(262144), dim3(256), 0, stream, img2, out);
}

// Round 2
// 1049.080 us; speedup vs baseline: 1.4845x; 1.4845x over previous
//
#include <hip/hip_runtime.h>
#include <math.h>

#define TOK   16384
#define DIM   48
#define EMB   256
#define MF    128
#define IMGsz 129

typedef __attribute__((ext_vector_type(8))) short    bf16x8;
typedef __attribute__((ext_vector_type(8))) unsigned short u16x8;
typedef __attribute__((ext_vector_type(4))) float    f32x4;

__device__ __forceinline__ ushort f2bf(float f) {
    union { float f; unsigned u; } v; v.f = f;
    unsigned u = v.u;
    return (ushort)((u + 0x7fffu + ((u >> 16) & 1u)) >> 16);   // RNE
}

// ---------------- kernel 1: unfold + LN + kqv + prm_exp (16 tokens/block) --------
__global__ __launch_bounds__(256) void k1_unfold_ln_kqv_prm(
    const float* __restrict__ x, const float* __restrict__ g1, const float* __restrict__ b1,
    const float* __restrict__ w_kqv, const float* __restrict__ b_kqv,
    const float* __restrict__ w_prm,
    float* __restrict__ v_out, float* __restrict__ kp_out, float* __restrict__ qp_out)
{
    __shared__ float t_s[16][DIM];
    __shared__ float k_s[16][EMB];
    __shared__ float q_s[16][EMB];
    __shared__ float xd_s[16][2];
    __shared__ float red_s[16][16];

    const int blk = blockIdx.x;
    const int b  = blk >> 10;            // 1024 blocks per batch
    const int t0 = (blk & 1023) << 4;
    const int tid = threadIdx.x;

    // unfold 16 tokens x 48 (c,kh,kw order), pad=1
    for (int e = tid; e < 16*DIM; e += 256) {
        int tok = e / DIM, j = e % DIM;
        int t = t0 + tok;
        int lh = t >> 7, lw = t & 127;
        int c = j >> 4, kh = (j >> 2) & 3, kw = j & 3;
        int ih = lh + kh - 1, iw = lw + kw - 1;
        float val = 0.f;
        if (ih >= 0 && ih < IMGsz && iw >= 0 && iw < IMGsz)
            val = x[((b*3 + c)*IMGsz + ih)*IMGsz + iw];
        t_s[tok][j] = val;
    }
    __syncthreads();
    // LayerNorm over DIM=48, one thread per token
    if (tid < 16) {
        float mu = 0.f;
        for (int j = 0; j < DIM; j++) mu += t_s[tid][j];
        mu *= (1.f/DIM);
        float var = 0.f;
        for (int j = 0; j < DIM; j++) { float dd = t_s[tid][j]-mu; var += dd*dd; }
        var *= (1.f/DIM);
        float inv = rsqrtf(var + 1e-5f);
        for (int j = 0; j < DIM; j++)
            t_s[tid][j] = (t_s[tid][j]-mu)*inv*g1[j] + b1[j];
    }
    __syncthreads();

    // kqv GEMM: thread tid -> columns tid (k), tid+256 (q), tid+512 (v), 16 tokens
    float accK[16], accQ[16], accV[16];
    {
        float bk = b_kqv[tid], bq = b_kqv[tid+EMB], bv = b_kqv[tid+2*EMB];
        #pragma unroll
        for (int i=0;i<16;i++){accK[i]=bk;accQ[i]=bq;accV[i]=bv;}
    }
    for (int d = 0; d < DIM; d++) {
        float wk = w_kqv[d*768 + tid];
        float wq = w_kqv[d*768 + tid + EMB];
        float wv = w_kqv[d*768 + tid + 2*EMB];
        #pragma unroll
        for (int i=0;i<16;i++){
            float h = t_s[i][d];
            accK[i] = fmaf(h, wk, accK[i]);
            accQ[i] = fmaf(h, wq, accQ[i]);
            accV[i] = fmaf(h, wv, accV[i]);
        }
    }
    for (int i=0;i<16;i++){
        k_s[i][tid] = accK[i];
        q_s[i][tid] = accQ[i];
        v_out[((size_t)b*TOK + t0 + i)*EMB + tid] = accV[i];
    }
    __syncthreads();

    // xd = 0.5*|k|^2, 0.5*|q|^2 per token
    {
        int tok = tid >> 4, lane = tid & 15;
        float sk=0.f, sq=0.f;
        for (int j = lane; j < EMB; j += 16) {
            float kv = k_s[tok][j]; sk = fmaf(kv,kv,sk);
            float qv = q_s[tok][j]; sq = fmaf(qv,qv,sq);
        }
        red_s[tok][lane] = sk;
        __syncthreads();
        if (lane == 0) { float s=0; for (int j=0;j<16;j++) s+=red_s[tok][j]; xd_s[tok][0]=0.5f*s; }
        __syncthreads();
        red_s[tok][lane] = sq;
        __syncthreads();
        if (lane == 0) { float s=0; for (int j=0;j<16;j++) s+=red_s[tok][j]; xd_s[tok][1]=0.5f*s; }
    }
    __syncthreads();

    // performer features: waves 0-1 -> kp feature tid; waves 2-3 -> qp feature tid-128
    float acc[16];
    #pragma unroll
    for (int i=0;i<16;i++) acc[i]=0.f;
    const int f = tid & 127;
    const bool isK = tid < 128;
    if (isK) {
        for (int d = 0; d < EMB; d++) {
            float w = w_prm[f*EMB + d];
            #pragma unroll
            for (int i=0;i<16;i++) acc[i] = fmaf(k_s[i][d], w, acc[i]);
        }
    } else {
        for (int d = 0; d < EMB; d++) {
            float w = w_prm[f*EMB + d];
            #pragma unroll
            for (int i=0;i<16;i++) acc[i] = fmaf(q_s[i][d], w, acc[i]);
        }
    }
    const float scale = 0.08838834764831845f;  // 1/sqrt(128)
    float* outp = isK ? kp_out : qp_out;
    for (int i=0;i<16;i++) {
        float xd = xd_s[i][isK ? 0 : 1];
        outp[((size_t)b*TOK + t0 + i)*MF + f] = expf(acc[i]-xd)*scale;
    }
}

// ---------------- kernel 2: ksum[b][m] = sum_t kp[b,t,m] -------------------------
__global__ __launch_bounds__(256) void k2_ksum(const float* __restrict__ kp, float* __restrict__ ksum)
{
    int blk = blockIdx.x;           // 64 blocks: b*16+chunk
    int b = blk >> 4, chunk = blk & 15;
    int m = threadIdx.x & 127, half = threadIdx.x >> 7;
    size_t base = ((size_t)b*TOK + chunk*1024 + half*512)*MF + m;
    float s = 0.f;
    for (int i = 0; i < 512; i++) s += kp[base + (size_t)i*MF];
    atomicAdd(&ksum[b*MF + m], s);
}

// ---------------- kernel 3: kptv[b][n][m] = sum_t v[b,t,n]*kp[b,t,m] -------------
__global__ __launch_bounds__(256) void k3_kptv(const float* __restrict__ v, const float* __restrict__ kp,
                                               float* __restrict__ kptv)
{
    __shared__ float v_s[4][32];
    __shared__ float kp_s[4][MF];
    int blk = blockIdx.x;               // 512 blocks: b(2b) | nt(3b) | tc(4b)
    int b = blk >> 7, nt = (blk >> 4) & 7, tc = blk & 15;
    int tid = threadIdx.x;
    int nl = tid & 31, mg = tid >> 5;   // 32 n-cols x 8 m-groups of 16
    float acc[16];
    #pragma unroll
    for (int i=0;i<16;i++) acc[i]=0.f;
    int t0 = tc * 1024;
    for (int tt = 0; tt < 1024; tt += 4) {
        __syncthreads();
        if (tid < 128) {
            int tok = tid >> 5, j = tid & 31;
            v_s[tok][j] = v[((size_t)b*TOK + t0+tt+tok)*EMB + nt*32 + j];
        }
        for (int e = tid; e < 4*MF; e += 256) {
            int tok = e >> 7, m = e & 127;
            kp_s[tok][m] = kp[((size_t)b*TOK + t0+tt+tok)*MF + m];
        }
        __syncthreads();
        #pragma unroll
        for (int tok=0; tok<4; tok++) {
            float vv = v_s[tok][nl];
            #pragma unroll
            for (int i=0;i<16;i++) acc[i] = fmaf(vv, kp_s[tok][mg*16+i], acc[i]);
        }
    }
    for (int i=0;i<16;i++)
        atomicAdd(&kptv[((size_t)b*EMB + nt*32 + nl)*MF + mg*16 + i], acc[i]);
}

// ---------------- kernel 3b: kptv f32 -> bf16 ------------------------------------
__global__ __launch_bounds__(256) void k3b_cvt(const float* __restrict__ kptv, ushort* __restrict__ kptv_bf)
{
    int i = blockIdx.x*256 + threadIdx.x;   // 131072 total
    kptv_bf[i] = f2bf(kptv[i]);
}

// ---------------- weight prep: wT_bf16[w][n][k] = bf16(w[k][n]) ------------------
__global__ __launch_bounds__(256) void kprep_w(const float* __restrict__ w_proj,
                                               const float* __restrict__ w_mlp1,
                                               const float* __restrict__ w_mlp2,
                                               ushort* __restrict__ wT)
{
    int blk = blockIdx.x;   // 3*256
    int w = blk >> 8, n = blk & 255;
    const float* src = (w == 0) ? w_proj : ((w == 1) ? w_mlp1 : w_mlp2);
    int d = threadIdx.x;
    wT[w*65536 + n*256 + d] = f2bf(src[d*256 + n]);
}

// ---------------- kernel 4: D, attention, proj, LN, MLP via MFMA (32 tok/block) --
// A-operand LDS layout: bf16 [32][256], row stride 256 ushorts (512B), with
// 16B-chunk XOR swizzle: chunk' = chunk ^ (row&7)  -> ds_read_b128 conflict-free.
#define SWZ(row, col) ((row)*256 + (((((col) >> 3) ^ ((row) & 7))) << 3) + ((col) & 7))

template<int K>
__device__ __forceinline__ void gemm_step(const ushort* A_s, const ushort* __restrict__ B,
                                          f32x4 acc[2][4], int l15, int l4, int wid)
{
    #pragma unroll
    for (int kc = 0; kc < (K >> 5); kc++) {
        const int ch = ((kc*4 + l4) ^ (l15 & 7)) << 3;
        bf16x8 a0 = *(const bf16x8*)&A_s[ l15      *256 + ch];
        bf16x8 a1 = *(const bf16x8*)&A_s[(16 + l15)*256 + ch];
        #pragma unroll
        for (int nt = 0; nt < 4; nt++) {
            bf16x8 bb = *(const bf16x8*)&B[(wid*64 + nt*16 + l15)*K + kc*32 + l4*8];
            acc[0][nt] = __builtin_amdgcn_mfma_f32_16x16x32_bf16(a0, bb, acc[0][nt], 0, 0, 0);
            acc[1][nt] = __builtin_amdgcn_mfma_f32_16x16x32_bf16(a1, bb, acc[1][nt], 0, 0, 0);
        }
    }
}

__global__ __launch_bounds__(256) void k4_attn_tail(
    const float* __restrict__ qp, const float* __restrict__ v_in,
    const float* __restrict__ ksum, const ushort* __restrict__ kptv_bf,
    const ushort* __restrict__ wT,
    const float* __restrict__ b_proj,
    const float* __restrict__ g2, const float* __restrict__ b2,
    const float* __restrict__ b_mlp1, const float* __restrict__ b_mlp2,
    float* __restrict__ img)
{
    __shared__ __align__(16) ushort A_s[32*256];   // 16 KB bf16 A-operand (swizzled)
    __shared__ float y2_s[32][256];                // 32 KB
    __shared__ float D_s[32];
    __shared__ float red_s[32][8];
    __shared__ float mu_s[32], iv_s[32];

    const int blk = blockIdx.x;                    // 2048 blocks
    const int b  = blk >> 9;
    const int t0 = (blk & 511) << 5;               // 32 tokens/block
    const int tid = threadIdx.x;
    const int wid = tid >> 6;
    const int lane = tid & 63;
    const int l15 = lane & 15, l4 = lane >> 4;

    // ---- stage 1: qp f32 -> bf16 A_s (swizzled); partial D = qp . ksum ----
    {
        int tk = tid >> 3, seg = tid & 7;          // 16 cols per thread
        const float* qrow = qp + ((size_t)(b*TOK + t0 + tk))*MF + seg*16;
        const float* ks = ksum + b*MF + seg*16;
        float dd = 0.f;
        ushort tmp[16];
        #pragma unroll
        for (int j = 0; j < 16; j++) {
            float qv = qrow[j];
            dd = fmaf(qv, ks[j], dd);
            tmp[j] = f2bf(qv);
        }
        red_s[tk][seg] = dd;
        int xr = tk & 7;
        u16x8 c0, c1;
        #pragma unroll
        for (int j = 0; j < 8; j++) { c0[j] = tmp[j]; c1[j] = tmp[8+j]; }
        *(u16x8*)&A_s[tk*256 + (((seg*2  ) ^ xr) << 3)] = c0;
        *(u16x8*)&A_s[tk*256 + (((seg*2+1) ^ xr) << 3)] = c1;
    }
    __syncthreads();
    if (tid < 32) {
        float s = 0.f;
        #pragma unroll
        for (int j = 0; j < 8; j++) s += red_s[tid][j];
        D_s[tid] = s + 1e-8f;
    }
    __syncthreads();

    f32x4 acc[2][4];
    #define ZACC() { _Pragma("unroll") for (int m_=0;m_<2;m_++) _Pragma("unroll") for (int n_=0;n_<4;n_++) { acc[m_][n_][0]=0.f;acc[m_][n_][1]=0.f;acc[m_][n_][2]=0.f;acc[m_][n_][3]=0.f; } }

    // ---- GEMM1: y_att[32][256] = qp[32][128] @ kptv^T, then /D ----
    ZACC();
    gemm_step<MF>(A_s, kptv_bf + (size_t)b*EMB*MF, acc, l15, l4, wid);
    __syncthreads();                               // everyone done reading qp in A_s
    #pragma unroll
    for (int m = 0; m < 2; m++)
        #pragma unroll
        for (int nt = 0; nt < 4; nt++) {
            int col = wid*64 + nt*16 + l15;
            #pragma unroll
            for (int r = 0; r < 4; r++) {
                int row = m*16 + l4*4 + r;
                A_s[SWZ(row, col)] = f2bf(acc[m][nt][r] / D_s[row]);
            }
        }
    __syncthreads();

    // ---- GEMM2: y2 = v + y_att @ w_proj + b_proj  (y2 kept f32 in LDS) ----
    ZACC();
    gemm_step<EMB>(A_s, wT, acc, l15, l4, wid);
    #pragma unroll
    for (int m = 0; m < 2; m++)
        #pragma unroll
        for (int nt = 0; nt < 4; nt++) {
            int col = wid*64 + nt*16 + l15;
            float bp = b_proj[col];
            #pragma unroll
            for (int r = 0; r < 4; r++) {
                int row = m*16 + l4*4 + r;
                y2_s[row][col] = acc[m][nt][r] + bp
                               + v_in[((size_t)(b*TOK + t0 + row))*EMB + col];
            }
        }
    __syncthreads();

    // ---- LayerNorm(y2) -> z bf16 into A_s ----
    {
        int tk = tid >> 3, seg = tid & 7;          // 32 cols per thread
        const float* yr = &y2_s[tk][seg*32];
        float s = 0.f;
        #pragma unroll
        for (int j = 0; j < 32; j++) s += yr[j];
        red_s[tk][seg] = s;
        __syncthreads();
        if (tid < 32) {
            float m = 0.f;
            #pragma unroll
            for (int j = 0; j < 8; j++) m += red_s[tid][j];
            mu_s[tid] = m * (1.f/EMB);
        }
        __syncthreads();
        float mu = mu_s[tk];
        s = 0.f;
        #pragma unroll
        for (int j = 0; j < 32; j++) { float d = yr[j]-mu; s = fmaf(d, d, s); }
        red_s[tk][seg] = s;
        __syncthreads();
        if (tid < 32) {
            float v2 = 0.f;
            #pragma unroll
            for (int j = 0; j < 8; j++) v2 += red_s[tid][j];
            iv_s[tid] = rsqrtf(v2 * (1.f/EMB) + 1e-5f);
        }
        __syncthreads();
        float iv = iv_s[tk];
        int xr = tk & 7;
        #pragma unroll
        for (int c8 = 0; c8 < 4; c8++) {
            u16x8 pk;
            #pragma unroll
            for (int j = 0; j < 8; j++) {
                int c = seg*32 + c8*8 + j;
                pk[j] = f2bf((yr[c8*8+j] - mu)*iv*g2[c] + b2[c]);
            }
            *(u16x8*)&A_s[tk*256 + ((((seg*4 + c8) ^ xr)) << 3)] = pk;
        }
    }
    __syncthreads();

    // ---- GEMM3: h1 = gelu(z @ w_mlp1 + b_mlp1) -> bf16 into A_s ----
    ZACC();
    gemm_step<EMB>(A_s, wT + 65536, acc, l15, l4, wid);
    __syncthreads();                               // everyone done reading z
    #pragma unroll
    for (int m = 0; m < 2; m++)
        #pragma unroll
        for (int nt = 0; nt < 4; nt++) {
            int col = wid*64 + nt*16 + l15;
            float bm = b_mlp1[col];
            #pragma unroll
            for (int r = 0; r < 4; r++) {
                int row = m*16 + l4*4 + r;
                float a = acc[m][nt][r] + bm;
                A_s[SWZ(row, col)] = f2bf(0.5f*a*(1.f + erff(a*0.70710678118654752f)));
            }
        }
    __syncthreads();

    // ---- GEMM4: y3 = y2 + h1 @ w_mlp2 + b_mlp2 -> global img ----
    ZACC();
    gemm_step<EMB>(A_s, wT + 131072, acc, l15, l4, wid);
    #pragma unroll
    for (int m = 0; m < 2; m++)
        #pragma unroll
        for (int nt = 0; nt < 4; nt++) {
            int col = wid*64 + nt*16 + l15;
            float bm = b_mlp2[col];
            #pragma unroll
            for (int r = 0; r < 4; r++) {
                int row = m*16 + l4*4 + r;
                img[((size_t)(b*TOK + t0 + row))*EMB + col] =
                    y2_s[row][col] + acc[m][nt][r] + bm;
            }
        }
}

// ---------------- kernel 5: [b,t,c] -> [b,c,t] transpose -------------------------
__global__ __launch_bounds__(256) void k5_transpose(const float* __restrict__ img, float* __restrict__ img2)
{
    __shared__ float tile[32][33];
    int blk = blockIdx.x;               // b(2b) | tt(9b) | ct(3b)
    int b = blk >> 12;
    int tt = (blk >> 3) & 511;
    int ct = blk & 7;
    int tid = threadIdx.x;
    int i = tid >> 5, j = tid & 31;     // i in 0..7
    #pragma unroll
    for (int ii = 0; ii < 4; ii++) {
        int row = i + ii*8;
        tile[row][j] = img[((size_t)b*TOK + tt*32 + row)*EMB + ct*32 + j];
    }
    __syncthreads();
    #pragma unroll
    for (int ii = 0; ii < 4; ii++) {
        int row = i + ii*8;
        img2[((size_t)b*EMB + ct*32 + row)*TOK + tt*32 + j] = tile[j][row];
    }
}

// ---------------- kernel 6: bilinear upsample x2, align_corners=True -------------
__global__ __launch_bounds__(256) void k6_upsample(const float* __restrict__ img2, float* __restrict__ out)
{
    int idx = blockIdx.x*256 + threadIdx.x;      // 4*256*256*256 total
    int wo = idx & 255;
    int ho = (idx >> 8) & 255;
    int c  = (idx >> 16) & 255;
    int b  = idx >> 24;
    const float sc = 127.f/255.f;
    float fh = ho * sc; int h0 = (int)fh; if (h0 > 126) h0 = 126; float th = fh - h0;
    float fw = wo * sc; int w0 = (int)fw; if (w0 > 126) w0 = 126; float tw = fw - w0;
    const float* p = img2 + (((size_t)b*EMB + c)*128 + h0)*128 + w0;
    float a00 = p[0], a01 = p[1], a10 = p[128], a11 = p[129];
    float top = fmaf(a01 - a00, tw, a00);
    float bot = fmaf(a11 - a10, tw, a10);
    out[idx] = fmaf(bot - top, th, top);
}

extern "C" void kernel_launch(void* const* d_in, const int* in_sizes, int n_in,
                              void* d_out, int out_size, void* d_ws, size_t ws_size,
                              hipStream_t stream)
{
    const float* x      = (const float*)d_in[0];
    const float* g1     = (const float*)d_in[1];
    const float* b1     = (const float*)d_in[2];
    const float* w_kqv  = (const float*)d_in[3];
    const float* b_kqv  = (const float*)d_in[4];
    const float* w_prm  = (const float*)d_in[5];
    const float* w_proj = (const float*)d_in[6];
    const float* b_proj = (const float*)d_in[7];
    const float* g2     = (const float*)d_in[8];
    const float* b2     = (const float*)d_in[9];
    const float* w_mlp1 = (const float*)d_in[10];
    const float* b_mlp1 = (const float*)d_in[11];
    const float* w_mlp2 = (const float*)d_in[12];
    const float* b_mlp2 = (const float*)d_in[13];
    float* out = (float*)d_out;
    float* ws  = (float*)d_ws;

    // ws layout (floats): v | kp | qp | ksum | kptv | img
    // kp region is dead after k3 -> reused for wT_bf16 + kptv_bf16 during k4,
    // then for img2 during k5/k6.
    float*  v_buf    = ws + 0;            // 16,777,216
    float*  kp_buf   = ws + 16777216;     //  8,388,608
    float*  qp_buf   = ws + 25165824;     //  8,388,608
    ushort* wT_bf    = (ushort*)(ws + 16777216);           // 196,608 ushorts
    ushort* kptv_bf  = (ushort*)(ws + 16777216 + 98304);   // 131,072 ushorts
    float*  img2     = ws + 16777216;     // aliases kp+qp (k5/k6 only)
    float*  ksum     = ws + 33554432;     //        512
    float*  kptv     = ws + 33554944;     //    131,072
    float*  img      = ws + 33686016;     // 16,777,216

    hipMemsetAsync(ksum, 0, (512 + 131072)*sizeof(float), stream);
    hipLaunchKernelGGL(k1_unfold_ln_kqv_prm, dim3(4096), dim3(256), 0, stream,
                       x, g1, b1, w_kqv, b_kqv, w_prm, v_buf, kp_buf, qp_buf);
    hipLaunchKernelGGL(k2_ksum, dim3(64), dim3(256), 0, stream, kp_buf, ksum);
    hipLaunchKernelGGL(k3_kptv, dim3(512), dim3(256), 0, stream, v_buf, kp_buf, kptv);
    // kp region dead from here -> safe to fill with bf16 operands
    hipLaunchKernelGGL(k3b_cvt, dim3(512), dim3(256), 0, stream, kptv, kptv_bf);
    hipLaunchKernelGGL(kprep_w, dim3(768), dim3(256), 0, stream, w_proj, w_mlp1, w_mlp2, wT_bf);
    hipLaunchKernelGGL(k4_attn_tail, dim3(2048), dim3(256), 0, stream,
                       qp_buf, v_buf, ksum, kptv_bf, wT_bf, b_proj, g2, b2,
                       b_mlp1, b_mlp2, img);
    hipLaunchKernelGGL(k5_transpose, dim3(16384), dim3(256), 0, stream, img, img2);
    hipLaunchKernelGGL(k6_upsample, dim3(262144), dim3(256), 0, stream, img2, out);
}

// Round 3
// 427.480 us; speedup vs baseline: 3.6431x; 2.4541x over previous
//
#include <hip/hip_runtime.h>
#include <math.h>

#define TOK   16384
#define DIM   48
#define EMB   256
#define MF    128
#define IMGsz 129

typedef __attribute__((ext_vector_type(8))) short    bf16x8;
typedef __attribute__((ext_vector_type(8))) unsigned short u16x8;
typedef __attribute__((ext_vector_type(4))) float    f32x4;

__device__ __forceinline__ ushort f2bf(float f) {
    union { float f; unsigned u; } v; v.f = f;
    unsigned u = v.u;
    return (ushort)((u + 0x7fffu + ((u >> 16) & 1u)) >> 16);   // RNE
}
__device__ __forceinline__ float bf2f(ushort h) {
    union { unsigned u; float f; } v; v.u = ((unsigned)h) << 16; return v.f;
}

// swizzles: XOR 16B-chunk index with (row&7) -> conflict-free ds_read_b128
#define SWZ512(r,c) ((r)*512 + (((((c)>>3) ^ ((r)&7))) << 3) + ((c)&7))
#define SWZ64(r,c)  ((r)*64  + (((((c)>>3) ^ ((r)&7)) & 7) << 3) + ((c)&7))
#define SWZ256(r,c) ((r)*256 + (((((c)>>3) ^ ((r)&7))) << 3) + ((c)&7))

// ---------------- kprep: bf16 weight staging -------------------------------------
// blk 0..767   : w_kqvT [768][64]  (K zero-padded 48->64)
// blk 768..895 : w_prm  [128][256] straight bf16
// blk 896..1663: wT3    [3][256 n][256 k] transposed proj/mlp1/mlp2
__global__ __launch_bounds__(256) void kprep(
    const float* __restrict__ w_kqv, const float* __restrict__ w_prm,
    const float* __restrict__ w_proj, const float* __restrict__ w_mlp1,
    const float* __restrict__ w_mlp2,
    ushort* __restrict__ wkqvT, ushort* __restrict__ wprm_bf, ushort* __restrict__ wT3)
{
    int blk = blockIdx.x, tid = threadIdx.x;
    if (blk < 768) {
        if (tid < 64) {
            float v = (tid < DIM) ? w_kqv[tid*768 + blk] : 0.f;
            wkqvT[blk*64 + tid] = f2bf(v);
        }
    } else if (blk < 896) {
        int m = blk - 768;
        wprm_bf[m*256 + tid] = f2bf(w_prm[m*256 + tid]);
    } else {
        int q = blk - 896;
        int w = q >> 8, n = q & 255;
        const float* src = (w == 0) ? w_proj : ((w == 1) ? w_mlp1 : w_mlp2);
        wT3[w*65536 + n*256 + tid] = f2bf(src[tid*256 + n]);
    }
}

// ---------------- kernel 1: unfold+LN+kqv+prm via MFMA (32 tokens/block) ---------
__global__ __launch_bounds__(256, 2) void k1_mfma(
    const float* __restrict__ x, const float* __restrict__ g1, const float* __restrict__ b1,
    const ushort* __restrict__ wkqvT, const float* __restrict__ b_kqv,
    const ushort* __restrict__ wprm_bf,
    ushort* __restrict__ v_out, ushort* __restrict__ vT_out,
    ushort* __restrict__ kpT_out, ushort* __restrict__ qp_out)
{
    __shared__ __align__(16) ushort kq_bf[32*512];   // 32KB: k cols 0-255, q cols 256-511 (swizzled)
    __shared__ __align__(16) ushort vt_bf[32*256];   // 16KB: v staging / h_bf / kp staging
    __shared__ float xdp[4][32][2];
    __shared__ float xd2[32][2];
    __shared__ float red1[32][8], red2[32][8];
    __shared__ float mu_s[32], iv_s[32];

    float*  t_s  = (float*)kq_bf;    // [32][48] unfold buffer (dead before kq_bf written)
    ushort* h_bf = vt_bf;            // [32][64] swizzled LN output (dead before v staged)

    const int blk = blockIdx.x;                    // 2048
    const int b  = blk >> 9;
    const int t0 = (blk & 511) << 5;
    const int tid = threadIdx.x;
    const int wid = tid >> 6;
    const int l15 = tid & 15, l4 = (tid >> 4) & 3;

    // ---- P1: unfold 32 tokens x 48 ----
    for (int e = tid; e < 32*DIM; e += 256) {
        int tok = e / DIM, j = e - tok*DIM;
        int t = t0 + tok;
        int lh = t >> 7, lw = t & 127;
        int c = j >> 4, kh = (j >> 2) & 3, kw = j & 3;
        int ih = lh + kh - 1, iw = lw + kw - 1;
        float val = 0.f;
        if (ih >= 0 && ih < IMGsz && iw >= 0 && iw < IMGsz)
            val = x[((b*3 + c)*IMGsz + ih)*IMGsz + iw];
        t_s[tok*DIM + j] = val;
    }
    __syncthreads();

    // ---- P1b: LayerNorm, 8 threads/token ----
    {
        int tg = tid >> 3, sl = tid & 7;
        const float* tr = &t_s[tg*DIM + sl*6];
        float s1 = 0.f, s2 = 0.f;
        #pragma unroll
        for (int j = 0; j < 6; j++) { float a = tr[j]; s1 += a; s2 = fmaf(a, a, s2); }
        red1[tg][sl] = s1; red2[tg][sl] = s2;
        __syncthreads();
        if (tid < 32) {
            float a = 0.f, q = 0.f;
            #pragma unroll
            for (int j = 0; j < 8; j++) { a += red1[tid][j]; q += red2[tid][j]; }
            float mu = a * (1.f/DIM);
            mu_s[tid] = mu;
            iv_s[tid] = rsqrtf(q*(1.f/DIM) - mu*mu + 1e-5f);
        }
        __syncthreads();
        float mu = mu_s[tg], iv = iv_s[tg];
        #pragma unroll
        for (int j = 0; j < 6; j++) {
            int c = sl*6 + j;
            h_bf[SWZ64(tg, c)] = f2bf((tr[j]-mu)*iv*g1[c] + b1[c]);
        }
        h_bf[SWZ64(tg, 48 + sl*2    )] = 0;   // K-pad
        h_bf[SWZ64(tg, 48 + sl*2 + 1)] = 0;
    }
    __syncthreads();

    // ---- P2: kqv GEMM [32][768] = h[32][64] @ wkqvT^T, n-tile = wid + 4*j ----
    f32x4 acc[2][12];
    #pragma unroll
    for (int m = 0; m < 2; m++)
        #pragma unroll
        for (int j = 0; j < 12; j++) { acc[m][j][0]=0.f; acc[m][j][1]=0.f; acc[m][j][2]=0.f; acc[m][j][3]=0.f; }
    #pragma unroll
    for (int kc = 0; kc < 2; kc++) {
        int ch = ((kc*4 + l4) ^ (l15 & 7)) << 3;
        bf16x8 a0 = *(const bf16x8*)&h_bf[ l15      *64 + ch];
        bf16x8 a1 = *(const bf16x8*)&h_bf[(16 + l15)*64 + ch];
        #pragma unroll
        for (int j = 0; j < 12; j++) {
            int base = (wid + 4*j) * 16;
            bf16x8 bb = *(const bf16x8*)&wkqvT[(base + l15)*64 + kc*32 + l4*8];
            acc[0][j] = __builtin_amdgcn_mfma_f32_16x16x32_bf16(a0, bb, acc[0][j], 0, 0, 0);
            acc[1][j] = __builtin_amdgcn_mfma_f32_16x16x32_bf16(a1, bb, acc[1][j], 0, 0, 0);
        }
    }
    __syncthreads();   // all waves done reading h_bf (vt_bf) before restaging

    // ---- P3: split k/q/v, bias, xd partials, stage LDS ----
    {
        float pk[2][4], pq[2][4];
        #pragma unroll
        for (int m = 0; m < 2; m++)
            #pragma unroll
            for (int r = 0; r < 4; r++) { pk[m][r] = 0.f; pq[m][r] = 0.f; }
        #pragma unroll
        for (int j = 0; j < 12; j++) {
            int col = (wid + 4*j)*16 + l15;
            float bias = b_kqv[col];
            #pragma unroll
            for (int m = 0; m < 2; m++)
                #pragma unroll
                for (int r = 0; r < 4; r++) {
                    int row = m*16 + l4*4 + r;
                    float a = acc[m][j][r] + bias;
                    if (j < 4) {        // k
                        pk[m][r] = fmaf(a, a, pk[m][r]);
                        kq_bf[SWZ512(row, col)] = f2bf(a);
                    } else if (j < 8) { // q
                        pq[m][r] = fmaf(a, a, pq[m][r]);
                        kq_bf[SWZ512(row, col)] = f2bf(a);
                    } else {            // v
                        int n = col - 512;
                        ushort vb = f2bf(a);
                        v_out[(size_t)(b*TOK + t0 + row)*EMB + n] = vb;
                        vt_bf[row*256 + n] = vb;
                    }
                }
        }
        // deterministic xd reduce: intra-16-lane shuffle, then cross-wave via LDS
        #pragma unroll
        for (int m = 0; m < 2; m++)
            #pragma unroll
            for (int r = 0; r < 4; r++) {
                float a = pk[m][r], q = pq[m][r];
                #pragma unroll
                for (int msk = 8; msk >= 1; msk >>= 1) {
                    a += __shfl_xor(a, msk);
                    q += __shfl_xor(q, msk);
                }
                if (l15 == 0) {
                    int row = m*16 + l4*4 + r;
                    xdp[wid][row][0] = a; xdp[wid][row][1] = q;
                }
            }
    }
    __syncthreads();
    if (tid < 64) {
        int row = tid >> 1, ty = tid & 1;
        xd2[row][ty] = 0.5f*(xdp[0][row][ty] + xdp[1][row][ty] + xdp[2][row][ty] + xdp[3][row][ty]);
    }

    // ---- P4: v^T coalesced write (thread = n channel) ----
    {
        ushort* dst = vT_out + ((size_t)(b*EMB + tid))*TOK + t0;
        #pragma unroll
        for (int t8 = 0; t8 < 4; t8++) {
            u16x8 pk8;
            #pragma unroll
            for (int j = 0; j < 8; j++) pk8[j] = vt_bf[(t8*8 + j)*256 + tid];
            *(u16x8*)&dst[t8*8] = pk8;
        }
    }
    __syncthreads();

    // ---- P5: prm GEMM: waves 0,1 -> kp (A = k cols 0-255); waves 2,3 -> qp ----
    f32x4 acc2[2][4];
    #pragma unroll
    for (int m = 0; m < 2; m++)
        #pragma unroll
        for (int n = 0; n < 4; n++) { acc2[m][n][0]=0.f; acc2[m][n][1]=0.f; acc2[m][n][2]=0.f; acc2[m][n][3]=0.f; }
    {
        const int cbase = (wid >= 2) ? 32 : 0;
        #pragma unroll
        for (int kc = 0; kc < 8; kc++) {
            int chunk = cbase + kc*4 + l4;
            int ch = (chunk ^ (l15 & 7)) << 3;
            bf16x8 a0 = *(const bf16x8*)&kq_bf[ l15      *512 + ch];
            bf16x8 a1 = *(const bf16x8*)&kq_bf[(16 + l15)*512 + ch];
            #pragma unroll
            for (int nt = 0; nt < 4; nt++) {
                int mcol = (wid & 1)*64 + nt*16 + l15;
                bf16x8 bb = *(const bf16x8*)&wprm_bf[mcol*256 + kc*32 + l4*8];
                acc2[0][nt] = __builtin_amdgcn_mfma_f32_16x16x32_bf16(a0, bb, acc2[0][nt], 0, 0, 0);
                acc2[1][nt] = __builtin_amdgcn_mfma_f32_16x16x32_bf16(a1, bb, acc2[1][nt], 0, 0, 0);
            }
        }
    }

    // ---- P6: exp epilogue; kp -> LDS staging, qp -> global row-major ----
    {
        const float scale = 0.08838834764831845f;  // 1/sqrt(128)
        const bool isK = (wid < 2);
        #pragma unroll
        for (int m = 0; m < 2; m++)
            #pragma unroll
            for (int nt = 0; nt < 4; nt++) {
                #pragma unroll
                for (int r = 0; r < 4; r++) {
                    int row = m*16 + l4*4 + r;
                    int mcol = (wid & 1)*64 + nt*16 + l15;
                    float e = expf(acc2[m][nt][r] - xd2[row][isK ? 0 : 1]) * scale;
                    ushort bf = f2bf(e);
                    if (isK) vt_bf[row*256 + mcol] = bf;
                    else qp_out[(size_t)(b*TOK + t0 + row)*MF + mcol] = bf;
                }
            }
    }
    __syncthreads();

    // ---- P7: kp^T coalesced write (thread 0-127 = feature m) ----
    if (tid < 128) {
        ushort* dst = kpT_out + ((size_t)(b*MF + tid))*TOK + t0;
        #pragma unroll
        for (int t8 = 0; t8 < 4; t8++) {
            u16x8 pk8;
            #pragma unroll
            for (int j = 0; j < 8; j++) pk8[j] = vt_bf[(t8*8 + j)*256 + tid];
            *(u16x8*)&dst[t8*8] = pk8;
        }
    }
}

// ---------------- kernel 2: ksum[b][m] = row-sum of kp^T (no atomics) ------------
__global__ __launch_bounds__(256) void k2_ksum(const ushort* __restrict__ kpT, float* __restrict__ ksum)
{
    __shared__ float red[4];
    int blk = blockIdx.x;            // 512: b(2b) | m(7b)
    int b = blk >> 7, m = blk & 127;
    int tid = threadIdx.x;
    const ushort* row = kpT + (size_t)(b*MF + m)*TOK;
    float s = 0.f;
    for (int i = tid; i < TOK/8; i += 256) {
        u16x8 v = *(const u16x8*)&row[i*8];
        #pragma unroll
        for (int j = 0; j < 8; j++) s += bf2f(v[j]);
    }
    #pragma unroll
    for (int msk = 32; msk >= 1; msk >>= 1) s += __shfl_xor(s, msk);
    if ((tid & 63) == 0) red[tid >> 6] = s;
    __syncthreads();
    if (tid == 0) ksum[b*MF + m] = red[0] + red[1] + red[2] + red[3];
}

// ---------------- kernel 3: kptv partials via MFMA -------------------------------
// C[n=256][m=128] = sum_t vT[n][t] * kpT[m][t], K split into 64 chunks of 256
__global__ __launch_bounds__(256) void k3_kptv_mfma(
    const ushort* __restrict__ vT, const ushort* __restrict__ kpT, float* __restrict__ part)
{
    int blk = blockIdx.x;            // 512: b(2b) | ns(1b) | kc(6b)
    int b = blk >> 7, ns = (blk >> 6) & 1, kc = blk & 63;
    const int tid = threadIdx.x;
    const int wid = tid >> 6;
    const int l15 = tid & 15, l4 = (tid >> 4) & 3;
    const int t0 = kc * 256;
    const int n0 = ns*128 + wid*32;

    f32x4 acc[2][8];
    #pragma unroll
    for (int m = 0; m < 2; m++)
        #pragma unroll
        for (int n = 0; n < 8; n++) { acc[m][n][0]=0.f; acc[m][n][1]=0.f; acc[m][n][2]=0.f; acc[m][n][3]=0.f; }

    #pragma unroll
    for (int ks = 0; ks < 8; ks++) {
        int k0 = t0 + ks*32 + l4*8;
        bf16x8 a0 = *(const bf16x8*)&vT[((size_t)(b*EMB + n0      + l15))*TOK + k0];
        bf16x8 a1 = *(const bf16x8*)&vT[((size_t)(b*EMB + n0 + 16 + l15))*TOK + k0];
        #pragma unroll
        for (int nt = 0; nt < 8; nt++) {
            bf16x8 bb = *(const bf16x8*)&kpT[((size_t)(b*MF + nt*16 + l15))*TOK + k0];
            acc[0][nt] = __builtin_amdgcn_mfma_f32_16x16x32_bf16(a0, bb, acc[0][nt], 0, 0, 0);
            acc[1][nt] = __builtin_amdgcn_mfma_f32_16x16x32_bf16(a1, bb, acc[1][nt], 0, 0, 0);
        }
    }
    #pragma unroll
    for (int mt = 0; mt < 2; mt++)
        #pragma unroll
        for (int nt = 0; nt < 8; nt++) {
            int n = n0 + mt*16 + l4*4;
            int m = nt*16 + l15;
            #pragma unroll
            for (int r = 0; r < 4; r++)
                part[(size_t)kc*131072 + (size_t)((b*EMB + n + r)*MF + m)] = acc[mt][nt][r];
        }
}

// ---------------- kernel 3r: reduce partials -> kptv bf16 ------------------------
__global__ __launch_bounds__(256) void k3r_reduce(const float* __restrict__ part, ushort* __restrict__ kptv_bf)
{
    int e = blockIdx.x*256 + threadIdx.x;   // 131072
    float s = 0.f;
    #pragma unroll 8
    for (int kc = 0; kc < 64; kc++) s += part[(size_t)kc*131072 + e];
    kptv_bf[e] = f2bf(s);
}

// ---------------- kernel 4: attention tail via MFMA + fused transpose ------------
template<int K>
__device__ __forceinline__ void gemm_step(const ushort* A_s, const ushort* __restrict__ B,
                                          f32x4 acc[2][4], int l15, int l4, int wid)
{
    #pragma unroll
    for (int kc = 0; kc < (K >> 5); kc++) {
        const int ch = ((kc*4 + l4) ^ (l15 & 7)) << 3;
        bf16x8 a0 = *(const bf16x8*)&A_s[ l15      *256 + ch];
        bf16x8 a1 = *(const bf16x8*)&A_s[(16 + l15)*256 + ch];
        #pragma unroll
        for (int nt = 0; nt < 4; nt++) {
            bf16x8 bb = *(const bf16x8*)&B[(wid*64 + nt*16 + l15)*K + kc*32 + l4*8];
            acc[0][nt] = __builtin_amdgcn_mfma_f32_16x16x32_bf16(a0, bb, acc[0][nt], 0, 0, 0);
            acc[1][nt] = __builtin_amdgcn_mfma_f32_16x16x32_bf16(a1, bb, acc[1][nt], 0, 0, 0);
        }
    }
}

__global__ __launch_bounds__(256) void k4_attn_tail(
    const ushort* __restrict__ qp, const ushort* __restrict__ v_in,
    const float* __restrict__ ksum, const ushort* __restrict__ kptv_bf,
    const ushort* __restrict__ wT,
    const float* __restrict__ b_proj,
    const float* __restrict__ g2, const float* __restrict__ b2,
    const float* __restrict__ b_mlp1, const float* __restrict__ b_mlp2,
    float* __restrict__ img2)
{
    __shared__ __align__(16) ushort A_s[32*256];   // 16 KB swizzled A operand
    __shared__ float y2_s[32][256];                // 32 KB
    __shared__ float D_s[32];
    __shared__ float red_s[32][8];
    __shared__ float mu_s[32], iv_s[32];

    const int blk = blockIdx.x;                    // 2048
    const int b  = blk >> 9;
    const int t0 = (blk & 511) << 5;
    const int tid = threadIdx.x;
    const int wid = tid >> 6;
    const int lane = tid & 63;
    const int l15 = lane & 15, l4 = lane >> 4;

    // ---- stage 1: qp bf16 -> A_s (swizzled copy); D = qp . ksum ----
    {
        int tk = tid >> 3, seg = tid & 7;
        const ushort* qrow = qp + (size_t)(b*TOK + t0 + tk)*MF + seg*16;
        u16x8 q0 = *(const u16x8*)&qrow[0];
        u16x8 q1 = *(const u16x8*)&qrow[8];
        const float* ks = ksum + b*MF + seg*16;
        float dd = 0.f;
        #pragma unroll
        for (int j = 0; j < 8; j++) {
            dd = fmaf(bf2f(q0[j]), ks[j],   dd);
            dd = fmaf(bf2f(q1[j]), ks[j+8], dd);
        }
        red_s[tk][seg] = dd;
        int xr = tk & 7;
        *(u16x8*)&A_s[tk*256 + (((seg*2  ) ^ xr) << 3)] = q0;
        *(u16x8*)&A_s[tk*256 + (((seg*2+1) ^ xr) << 3)] = q1;
    }
    __syncthreads();
    if (tid < 32) {
        float s = 0.f;
        #pragma unroll
        for (int j = 0; j < 8; j++) s += red_s[tid][j];
        D_s[tid] = s + 1e-8f;
    }
    __syncthreads();

    f32x4 acc[2][4];
    #define ZACC() { _Pragma("unroll") for (int m_=0;m_<2;m_++) _Pragma("unroll") for (int n_=0;n_<4;n_++) { acc[m_][n_][0]=0.f;acc[m_][n_][1]=0.f;acc[m_][n_][2]=0.f;acc[m_][n_][3]=0.f; } }

    // ---- GEMM1: y_att = qp @ kptv^T, /D ----
    ZACC();
    gemm_step<MF>(A_s, kptv_bf + (size_t)b*EMB*MF, acc, l15, l4, wid);
    __syncthreads();
    #pragma unroll
    for (int m = 0; m < 2; m++)
        #pragma unroll
        for (int nt = 0; nt < 4; nt++) {
            int col = wid*64 + nt*16 + l15;
            #pragma unroll
            for (int r = 0; r < 4; r++) {
                int row = m*16 + l4*4 + r;
                A_s[SWZ256(row, col)] = f2bf(acc[m][nt][r] / D_s[row]);
            }
        }
    __syncthreads();

    // ---- GEMM2: y2 = v + y_att @ w_proj + b_proj ----
    ZACC();
    gemm_step<EMB>(A_s, wT, acc, l15, l4, wid);
    #pragma unroll
    for (int m = 0; m < 2; m++)
        #pragma unroll
        for (int nt = 0; nt < 4; nt++) {
            int col = wid*64 + nt*16 + l15;
            float bp = b_proj[col];
            #pragma unroll
            for (int r = 0; r < 4; r++) {
                int row = m*16 + l4*4 + r;
                y2_s[row][col] = acc[m][nt][r] + bp
                               + bf2f(v_in[(size_t)(b*TOK + t0 + row)*EMB + col]);
            }
        }
    __syncthreads();

    // ---- LayerNorm(y2) -> z bf16 into A_s ----
    {
        int tk = tid >> 3, seg = tid & 7;
        const float* yr = &y2_s[tk][seg*32];
        float s = 0.f;
        #pragma unroll
        for (int j = 0; j < 32; j++) s += yr[j];
        red_s[tk][seg] = s;
        __syncthreads();
        if (tid < 32) {
            float m = 0.f;
            #pragma unroll
            for (int j = 0; j < 8; j++) m += red_s[tid][j];
            mu_s[tid] = m * (1.f/EMB);
        }
        __syncthreads();
        float mu = mu_s[tk];
        s = 0.f;
        #pragma unroll
        for (int j = 0; j < 32; j++) { float d = yr[j]-mu; s = fmaf(d, d, s); }
        red_s[tk][seg] = s;
        __syncthreads();
        if (tid < 32) {
            float v2 = 0.f;
            #pragma unroll
            for (int j = 0; j < 8; j++) v2 += red_s[tid][j];
            iv_s[tid] = rsqrtf(v2 * (1.f/EMB) + 1e-5f);
        }
        __syncthreads();
        float iv = iv_s[tk];
        int xr = tk & 7;
        #pragma unroll
        for (int c8 = 0; c8 < 4; c8++) {
            u16x8 pk;
            #pragma unroll
            for (int j = 0; j < 8; j++) {
                int c = seg*32 + c8*8 + j;
                pk[j] = f2bf((yr[c8*8+j] - mu)*iv*g2[c] + b2[c]);
            }
            *(u16x8*)&A_s[tk*256 + ((((seg*4 + c8) ^ xr)) << 3)] = pk;
        }
    }
    __syncthreads();

    // ---- GEMM3: h1 = gelu(z @ w_mlp1 + b_mlp1) ----
    ZACC();
    gemm_step<EMB>(A_s, wT + 65536, acc, l15, l4, wid);
    __syncthreads();
    #pragma unroll
    for (int m = 0; m < 2; m++)
        #pragma unroll
        for (int nt = 0; nt < 4; nt++) {
            int col = wid*64 + nt*16 + l15;
            float bm = b_mlp1[col];
            #pragma unroll
            for (int r = 0; r < 4; r++) {
                int row = m*16 + l4*4 + r;
                float a = acc[m][nt][r] + bm;
                A_s[SWZ256(row, col)] = f2bf(0.5f*a*(1.f + erff(a*0.70710678118654752f)));
            }
        }
    __syncthreads();

    // ---- GEMM4: y3 = y2 + h1 @ w_mlp2 + b_mlp2 -> back into y2_s ----
    ZACC();
    gemm_step<EMB>(A_s, wT + 131072, acc, l15, l4, wid);
    #pragma unroll
    for (int m = 0; m < 2; m++)
        #pragma unroll
        for (int nt = 0; nt < 4; nt++) {
            int col = wid*64 + nt*16 + l15;
            float bm = b_mlp2[col];
            #pragma unroll
            for (int r = 0; r < 4; r++) {
                int row = m*16 + l4*4 + r;
                y2_s[row][col] = y2_s[row][col] + acc[m][nt][r] + bm;
            }
        }
    __syncthreads();

    // ---- fused transpose: img2[b][c][t] (channel-major) ----
    {
        float* dst = img2 + ((size_t)(b*EMB + tid))*TOK + t0;
        #pragma unroll
        for (int t4 = 0; t4 < 32; t4 += 4) {
            f32x4 pk;
            #pragma unroll
            for (int j = 0; j < 4; j++) pk[j] = y2_s[t4+j][tid];
            *(f32x4*)&dst[t4] = pk;
        }
    }
}

// ---------------- kernel 6: bilinear upsample x2, align_corners=True -------------
__global__ __launch_bounds__(256) void k6_upsample(const float* __restrict__ img2, float* __restrict__ out)
{
    int idx = blockIdx.x*256 + threadIdx.x;      // 4*256*256*256 total
    int wo = idx & 255;
    int ho = (idx >> 8) & 255;
    int c  = (idx >> 16) & 255;
    int b  = idx >> 24;
    const float sc = 127.f/255.f;
    float fh = ho * sc; int h0 = (int)fh; if (h0 > 126) h0 = 126; float th = fh - h0;
    float fw = wo * sc; int w0 = (int)fw; if (w0 > 126) w0 = 126; float tw = fw - w0;
    const float* p = img2 + (((size_t)b*EMB + c)*128 + h0)*128 + w0;
    float a00 = p[0], a01 = p[1], a10 = p[128], a11 = p[129];
    float top = fmaf(a01 - a00, tw, a00);
    float bot = fmaf(a11 - a10, tw, a10);
    out[idx] = fmaf(bot - top, th, top);
}

extern "C" void kernel_launch(void* const* d_in, const int* in_sizes, int n_in,
                              void* d_out, int out_size, void* d_ws, size_t ws_size,
                              hipStream_t stream)
{
    const float* x      = (const float*)d_in[0];
    const float* g1     = (const float*)d_in[1];
    const float* b1     = (const float*)d_in[2];
    const float* w_kqv  = (const float*)d_in[3];
    const float* b_kqv  = (const float*)d_in[4];
    const float* w_prm  = (const float*)d_in[5];
    const float* w_proj = (const float*)d_in[6];
    const float* b_proj = (const float*)d_in[7];
    const float* g2     = (const float*)d_in[8];
    const float* b2     = (const float*)d_in[9];
    const float* w_mlp1 = (const float*)d_in[10];
    const float* b_mlp1 = (const float*)d_in[11];
    const float* w_mlp2 = (const float*)d_in[12];
    const float* b_mlp2 = (const float*)d_in[13];
    float* out = (float*)d_out;
    float* ws  = (float*)d_ws;

    // ws layout (float-slot offsets):
    ushort* v_bf    = (ushort*)(ws);               // 16,777,216 ushorts (8,388,608 slots)
    ushort* qp_bf   = (ushort*)(ws + 8388608);     //  8,388,608 ushorts (4,194,304 slots)
    ushort* vT_bf   = (ushort*)(ws + 12582912);    // 16,777,216 ushorts (8,388,608 slots)
    ushort* kpT_bf  = (ushort*)(ws + 20971520);    //  8,388,608 ushorts (4,194,304 slots)
    float*  img2    = ws + 12582912;               // overlays vT+kpT (dead after k3): 16,777,216 slots -> ends 29,360,128
    float*  ksum    = ws + 29360128;               // 512
    ushort* wkqvT   = (ushort*)(ws + 29360640);    // 49,152 ushorts (24,576 slots)
    ushort* wprm_bf = (ushort*)(ws + 29385216);    // 32,768 ushorts (16,384 slots)
    ushort* wT3     = (ushort*)(ws + 29401600);    // 196,608 ushorts (98,304 slots)
    ushort* kptv_bf = (ushort*)(ws + 29499904);    // 65,536 ushorts (32,768 slots)
    float*  part    = ws + 29532672;               // 8,388,608 slots -> ends 37,921,280 (151.7 MB)

    hipLaunchKernelGGL(kprep, dim3(1664), dim3(256), 0, stream,
                       w_kqv, w_prm, w_proj, w_mlp1, w_mlp2, wkqvT, wprm_bf, wT3);
    hipLaunchKernelGGL(k1_mfma, dim3(2048), dim3(256), 0, stream,
                       x, g1, b1, wkqvT, b_kqv, wprm_bf, v_bf, vT_bf, kpT_bf, qp_bf);
    hipLaunchKernelGGL(k2_ksum, dim3(512), dim3(256), 0, stream, kpT_bf, ksum);
    hipLaunchKernelGGL(k3_kptv_mfma, dim3(512), dim3(256), 0, stream, vT_bf, kpT_bf, part);
    hipLaunchKernelGGL(k3r_reduce, dim3(512), dim3(256), 0, stream, part, kptv_bf);
    hipLaunchKernelGGL(k4_attn_tail, dim3(2048), dim3(256), 0, stream,
                       qp_bf, v_bf, ksum, kptv_bf, wT3, b_proj, g2, b2,
                       b_mlp1, b_mlp2, img2);
    hipLaunchKernelGGL(k6_upsample, dim3(262144), dim3(256), 0, stream, img2, out);
}

// Round 4
// 419.859 us; speedup vs baseline: 3.7092x; 1.0182x over previous
//
#include <hip/hip_runtime.h>
#include <math.h>

#define TOK   16384
#define DIM   48
#define EMB   256
#define MF    128
#define IMGsz 129

typedef __attribute__((ext_vector_type(8))) short    bf16x8;
typedef __attribute__((ext_vector_type(8))) unsigned short u16x8;
typedef __attribute__((ext_vector_type(4))) float    f32x4;

__device__ __forceinline__ ushort f2bf(float f) {
    union { float f; unsigned u; } v; v.f = f;
    unsigned u = v.u;
    return (ushort)((u + 0x7fffu + ((u >> 16) & 1u)) >> 16);   // RNE
}
__device__ __forceinline__ float bf2f(ushort h) {
    union { unsigned u; float f; } v; v.u = ((unsigned)h) << 16; return v.f;
}

// swizzles: XOR 16B-chunk index with (row&7) -> conflict-free ds_read_b128
#define SWZ512(r,c) ((r)*512 + (((((c)>>3) ^ ((r)&7))) << 3) + ((c)&7))
#define SWZ64(r,c)  ((r)*64  + (((((c)>>3) ^ ((r)&7)) & 7) << 3) + ((c)&7))
#define SWZ256(r,c) ((r)*256 + (((((c)>>3) ^ ((r)&7))) << 3) + ((c)&7))

// ---------------- kprep: bf16 weight staging -------------------------------------
__global__ __launch_bounds__(256) void kprep(
    const float* __restrict__ w_kqv, const float* __restrict__ w_prm,
    const float* __restrict__ w_proj, const float* __restrict__ w_mlp1,
    const float* __restrict__ w_mlp2,
    ushort* __restrict__ wkqvT, ushort* __restrict__ wprm_bf, ushort* __restrict__ wT3)
{
    int blk = blockIdx.x, tid = threadIdx.x;
    if (blk < 768) {
        if (tid < 64) {
            float v = (tid < DIM) ? w_kqv[tid*768 + blk] : 0.f;
            wkqvT[blk*64 + tid] = f2bf(v);
        }
    } else if (blk < 896) {
        int m = blk - 768;
        wprm_bf[m*256 + tid] = f2bf(w_prm[m*256 + tid]);
    } else {
        int q = blk - 896;
        int w = q >> 8, n = q & 255;
        const float* src = (w == 0) ? w_proj : ((w == 1) ? w_mlp1 : w_mlp2);
        wT3[w*65536 + n*256 + tid] = f2bf(src[tid*256 + n]);
    }
}

// ---------------- kernel 1: unfold+LN+kqv+prm via MFMA (32 tokens/block) ---------
__global__ __launch_bounds__(256, 2) void k1_mfma(
    const float* __restrict__ x, const float* __restrict__ g1, const float* __restrict__ b1,
    const ushort* __restrict__ wkqvT, const float* __restrict__ b_kqv,
    const ushort* __restrict__ wprm_bf,
    ushort* __restrict__ v_out, ushort* __restrict__ vT_out,
    ushort* __restrict__ kpT_out, ushort* __restrict__ qp_out)
{
    __shared__ __align__(16) ushort kq_bf[32*512];
    __shared__ __align__(16) ushort vt_bf[32*256];
    __shared__ float xdp[4][32][2];
    __shared__ float xd2[32][2];
    __shared__ float red1[32][8], red2[32][8];
    __shared__ float mu_s[32], iv_s[32];

    float*  t_s  = (float*)kq_bf;
    ushort* h_bf = vt_bf;

    const int blk = blockIdx.x;                    // 2048
    const int b  = blk >> 9;
    const int t0 = (blk & 511) << 5;
    const int tid = threadIdx.x;
    const int wid = tid >> 6;
    const int l15 = tid & 15, l4 = (tid >> 4) & 3;

    for (int e = tid; e < 32*DIM; e += 256) {
        int tok = e / DIM, j = e - tok*DIM;
        int t = t0 + tok;
        int lh = t >> 7, lw = t & 127;
        int c = j >> 4, kh = (j >> 2) & 3, kw = j & 3;
        int ih = lh + kh - 1, iw = lw + kw - 1;
        float val = 0.f;
        if (ih >= 0 && ih < IMGsz && iw >= 0 && iw < IMGsz)
            val = x[((b*3 + c)*IMGsz + ih)*IMGsz + iw];
        t_s[tok*DIM + j] = val;
    }
    __syncthreads();

    {
        int tg = tid >> 3, sl = tid & 7;
        const float* tr = &t_s[tg*DIM + sl*6];
        float s1 = 0.f, s2 = 0.f;
        #pragma unroll
        for (int j = 0; j < 6; j++) { float a = tr[j]; s1 += a; s2 = fmaf(a, a, s2); }
        red1[tg][sl] = s1; red2[tg][sl] = s2;
        __syncthreads();
        if (tid < 32) {
            float a = 0.f, q = 0.f;
            #pragma unroll
            for (int j = 0; j < 8; j++) { a += red1[tid][j]; q += red2[tid][j]; }
            float mu = a * (1.f/DIM);
            mu_s[tid] = mu;
            iv_s[tid] = rsqrtf(q*(1.f/DIM) - mu*mu + 1e-5f);
        }
        __syncthreads();
        float mu = mu_s[tg], iv = iv_s[tg];
        #pragma unroll
        for (int j = 0; j < 6; j++) {
            int c = sl*6 + j;
            h_bf[SWZ64(tg, c)] = f2bf((tr[j]-mu)*iv*g1[c] + b1[c]);
        }
        h_bf[SWZ64(tg, 48 + sl*2    )] = 0;
        h_bf[SWZ64(tg, 48 + sl*2 + 1)] = 0;
    }
    __syncthreads();

    f32x4 acc[2][12];
    #pragma unroll
    for (int m = 0; m < 2; m++)
        #pragma unroll
        for (int j = 0; j < 12; j++) { acc[m][j][0]=0.f; acc[m][j][1]=0.f; acc[m][j][2]=0.f; acc[m][j][3]=0.f; }
    #pragma unroll
    for (int kc = 0; kc < 2; kc++) {
        int ch = ((kc*4 + l4) ^ (l15 & 7)) << 3;
        bf16x8 a0 = *(const bf16x8*)&h_bf[ l15      *64 + ch];
        bf16x8 a1 = *(const bf16x8*)&h_bf[(16 + l15)*64 + ch];
        #pragma unroll
        for (int j = 0; j < 12; j++) {
            int base = (wid + 4*j) * 16;
            bf16x8 bb = *(const bf16x8*)&wkqvT[(base + l15)*64 + kc*32 + l4*8];
            acc[0][j] = __builtin_amdgcn_mfma_f32_16x16x32_bf16(a0, bb, acc[0][j], 0, 0, 0);
            acc[1][j] = __builtin_amdgcn_mfma_f32_16x16x32_bf16(a1, bb, acc[1][j], 0, 0, 0);
        }
    }
    __syncthreads();

    {
        float pk[2][4], pq[2][4];
        #pragma unroll
        for (int m = 0; m < 2; m++)
            #pragma unroll
            for (int r = 0; r < 4; r++) { pk[m][r] = 0.f; pq[m][r] = 0.f; }
        #pragma unroll
        for (int j = 0; j < 12; j++) {
            int col = (wid + 4*j)*16 + l15;
            float bias = b_kqv[col];
            #pragma unroll
            for (int m = 0; m < 2; m++)
                #pragma unroll
                for (int r = 0; r < 4; r++) {
                    int row = m*16 + l4*4 + r;
                    float a = acc[m][j][r] + bias;
                    if (j < 4) {
                        pk[m][r] = fmaf(a, a, pk[m][r]);
                        kq_bf[SWZ512(row, col)] = f2bf(a);
                    } else if (j < 8) {
                        pq[m][r] = fmaf(a, a, pq[m][r]);
                        kq_bf[SWZ512(row, col)] = f2bf(a);
                    } else {
                        int n = col - 512;
                        ushort vb = f2bf(a);
                        v_out[(size_t)(b*TOK + t0 + row)*EMB + n] = vb;
                        vt_bf[row*256 + n] = vb;
                    }
                }
        }
        #pragma unroll
        for (int m = 0; m < 2; m++)
            #pragma unroll
            for (int r = 0; r < 4; r++) {
                float a = pk[m][r], q = pq[m][r];
                #pragma unroll
                for (int msk = 8; msk >= 1; msk >>= 1) {
                    a += __shfl_xor(a, msk);
                    q += __shfl_xor(q, msk);
                }
                if (l15 == 0) {
                    int row = m*16 + l4*4 + r;
                    xdp[wid][row][0] = a; xdp[wid][row][1] = q;
                }
            }
    }
    __syncthreads();
    if (tid < 64) {
        int row = tid >> 1, ty = tid & 1;
        xd2[row][ty] = 0.5f*(xdp[0][row][ty] + xdp[1][row][ty] + xdp[2][row][ty] + xdp[3][row][ty]);
    }

    {
        ushort* dst = vT_out + ((size_t)(b*EMB + tid))*TOK + t0;
        #pragma unroll
        for (int t8 = 0; t8 < 4; t8++) {
            u16x8 pk8;
            #pragma unroll
            for (int j = 0; j < 8; j++) pk8[j] = vt_bf[(t8*8 + j)*256 + tid];
            *(u16x8*)&dst[t8*8] = pk8;
        }
    }
    __syncthreads();

    f32x4 acc2[2][4];
    #pragma unroll
    for (int m = 0; m < 2; m++)
        #pragma unroll
        for (int n = 0; n < 4; n++) { acc2[m][n][0]=0.f; acc2[m][n][1]=0.f; acc2[m][n][2]=0.f; acc2[m][n][3]=0.f; }
    {
        const int cbase = (wid >= 2) ? 32 : 0;
        #pragma unroll
        for (int kc = 0; kc < 8; kc++) {
            int chunk = cbase + kc*4 + l4;
            int ch = (chunk ^ (l15 & 7)) << 3;
            bf16x8 a0 = *(const bf16x8*)&kq_bf[ l15      *512 + ch];
            bf16x8 a1 = *(const bf16x8*)&kq_bf[(16 + l15)*512 + ch];
            #pragma unroll
            for (int nt = 0; nt < 4; nt++) {
                int mcol = (wid & 1)*64 + nt*16 + l15;
                bf16x8 bb = *(const bf16x8*)&wprm_bf[mcol*256 + kc*32 + l4*8];
                acc2[0][nt] = __builtin_amdgcn_mfma_f32_16x16x32_bf16(a0, bb, acc2[0][nt], 0, 0, 0);
                acc2[1][nt] = __builtin_amdgcn_mfma_f32_16x16x32_bf16(a1, bb, acc2[1][nt], 0, 0, 0);
            }
        }
    }

    {
        const float scale = 0.08838834764831845f;
        const bool isK = (wid < 2);
        #pragma unroll
        for (int m = 0; m < 2; m++)
            #pragma unroll
            for (int nt = 0; nt < 4; nt++) {
                #pragma unroll
                for (int r = 0; r < 4; r++) {
                    int row = m*16 + l4*4 + r;
                    int mcol = (wid & 1)*64 + nt*16 + l15;
                    float e = expf(acc2[m][nt][r] - xd2[row][isK ? 0 : 1]) * scale;
                    ushort bf = f2bf(e);
                    if (isK) vt_bf[row*256 + mcol] = bf;
                    else qp_out[(size_t)(b*TOK + t0 + row)*MF + mcol] = bf;
                }
            }
    }
    __syncthreads();

    if (tid < 128) {
        ushort* dst = kpT_out + ((size_t)(b*MF + tid))*TOK + t0;
        #pragma unroll
        for (int t8 = 0; t8 < 4; t8++) {
            u16x8 pk8;
            #pragma unroll
            for (int j = 0; j < 8; j++) pk8[j] = vt_bf[(t8*8 + j)*256 + tid];
            *(u16x8*)&dst[t8*8] = pk8;
        }
    }
}

// ---------------- kernel 2: ksum[b][m] = row-sum of kp^T ------------------------
__global__ __launch_bounds__(256) void k2_ksum(const ushort* __restrict__ kpT, float* __restrict__ ksum)
{
    __shared__ float red[4];
    int blk = blockIdx.x;
    int b = blk >> 7, m = blk & 127;
    int tid = threadIdx.x;
    const ushort* row = kpT + (size_t)(b*MF + m)*TOK;
    float s = 0.f;
    for (int i = tid; i < TOK/8; i += 256) {
        u16x8 v = *(const u16x8*)&row[i*8];
        #pragma unroll
        for (int j = 0; j < 8; j++) s += bf2f(v[j]);
    }
    #pragma unroll
    for (int msk = 32; msk >= 1; msk >>= 1) s += __shfl_xor(s, msk);
    if ((tid & 63) == 0) red[tid >> 6] = s;
    __syncthreads();
    if (tid == 0) ksum[b*MF + m] = red[0] + red[1] + red[2] + red[3];
}

// ---------------- kernel 3: kptv partials via MFMA -------------------------------
__global__ __launch_bounds__(256) void k3_kptv_mfma(
    const ushort* __restrict__ vT, const ushort* __restrict__ kpT, float* __restrict__ part)
{
    int blk = blockIdx.x;            // 512: b(2b) | ns(1b) | kc(6b)
    int b = blk >> 7, ns = (blk >> 6) & 1, kc = blk & 63;
    const int tid = threadIdx.x;
    const int wid = tid >> 6;
    const int l15 = tid & 15, l4 = (tid >> 4) & 3;
    const int t0 = kc * 256;
    const int n0 = ns*128 + wid*32;

    f32x4 acc[2][8];
    #pragma unroll
    for (int m = 0; m < 2; m++)
        #pragma unroll
        for (int n = 0; n < 8; n++) { acc[m][n][0]=0.f; acc[m][n][1]=0.f; acc[m][n][2]=0.f; acc[m][n][3]=0.f; }

    #pragma unroll
    for (int ks = 0; ks < 8; ks++) {
        int k0 = t0 + ks*32 + l4*8;
        bf16x8 a0 = *(const bf16x8*)&vT[((size_t)(b*EMB + n0      + l15))*TOK + k0];
        bf16x8 a1 = *(const bf16x8*)&vT[((size_t)(b*EMB + n0 + 16 + l15))*TOK + k0];
        #pragma unroll
        for (int nt = 0; nt < 8; nt++) {
            bf16x8 bb = *(const bf16x8*)&kpT[((size_t)(b*MF + nt*16 + l15))*TOK + k0];
            acc[0][nt] = __builtin_amdgcn_mfma_f32_16x16x32_bf16(a0, bb, acc[0][nt], 0, 0, 0);
            acc[1][nt] = __builtin_amdgcn_mfma_f32_16x16x32_bf16(a1, bb, acc[1][nt], 0, 0, 0);
        }
    }
    #pragma unroll
    for (int mt = 0; mt < 2; mt++)
        #pragma unroll
        for (int nt = 0; nt < 8; nt++) {
            int n = n0 + mt*16 + l4*4;
            int m = nt*16 + l15;
            #pragma unroll
            for (int r = 0; r < 4; r++)
                part[(size_t)kc*131072 + (size_t)((b*EMB + n + r)*MF + m)] = acc[mt][nt][r];
        }
}

// ---------------- kernel 3r: reduce partials -> kptv bf16 ------------------------
__global__ __launch_bounds__(256) void k3r_reduce(const float* __restrict__ part, ushort* __restrict__ kptv_bf)
{
    int e = blockIdx.x*256 + threadIdx.x;
    float s = 0.f;
    #pragma unroll 8
    for (int kc = 0; kc < 64; kc++) s += part[(size_t)kc*131072 + e];
    kptv_bf[e] = f2bf(s);
}

// ---------------- kernel 4 v2: 64 tokens/block, y2 in registers ------------------
// A_s: bf16 [64][256] XOR-swizzled (32KB); reused as f32 [32][256] for output stage.
template<int K>
__device__ __forceinline__ void gemm4m(const ushort* A_s, const ushort* __restrict__ B,
                                       f32x4 acc[4][4], int l15, int l4, int wid)
{
    #pragma unroll
    for (int kc = 0; kc < (K >> 5); kc++) {
        const int ch = ((kc*4 + l4) ^ (l15 & 7)) << 3;
        bf16x8 a0 = *(const bf16x8*)&A_s[( 0 + l15)*256 + ch];
        bf16x8 a1 = *(const bf16x8*)&A_s[(16 + l15)*256 + ch];
        bf16x8 a2 = *(const bf16x8*)&A_s[(32 + l15)*256 + ch];
        bf16x8 a3 = *(const bf16x8*)&A_s[(48 + l15)*256 + ch];
        #pragma unroll
        for (int nt = 0; nt < 4; nt++) {
            bf16x8 bb = *(const bf16x8*)&B[(wid*64 + nt*16 + l15)*K + kc*32 + l4*8];
            acc[0][nt] = __builtin_amdgcn_mfma_f32_16x16x32_bf16(a0, bb, acc[0][nt], 0, 0, 0);
            acc[1][nt] = __builtin_amdgcn_mfma_f32_16x16x32_bf16(a1, bb, acc[1][nt], 0, 0, 0);
            acc[2][nt] = __builtin_amdgcn_mfma_f32_16x16x32_bf16(a2, bb, acc[2][nt], 0, 0, 0);
            acc[3][nt] = __builtin_amdgcn_mfma_f32_16x16x32_bf16(a3, bb, acc[3][nt], 0, 0, 0);
        }
    }
}

__global__ __launch_bounds__(256) void k4_attn_tail(
    const ushort* __restrict__ qp, const ushort* __restrict__ v_in,
    const float* __restrict__ ksum, const ushort* __restrict__ kptv_bf,
    const ushort* __restrict__ wT,
    const float* __restrict__ b_proj,
    const float* __restrict__ g2, const float* __restrict__ b2,
    const float* __restrict__ b_mlp1, const float* __restrict__ b_mlp2,
    float* __restrict__ img2)
{
    __shared__ __align__(16) ushort A_s[64*256];   // 32 KB
    __shared__ float D_s[64];
    __shared__ float redD[64][4];
    __shared__ float red1[4][64], red2[4][64];
    __shared__ float mu_s[64], iv_s[64];

    const int blk = blockIdx.x;                    // 1024
    const int b  = blk >> 8;
    const int t0 = (blk & 255) << 6;               // 64 tokens/block
    const int tid = threadIdx.x;
    const int wid = tid >> 6;
    const int lane = tid & 63;
    const int l15 = lane & 15, l4 = lane >> 4;

    // ---- stage qp (bf16 copy, swizzled) + D = qp . ksum ----
    {
        int tk = tid >> 2, sg = tid & 3;           // 64 rows x 4 segs of 32 cols
        const ushort* qrow = qp + (size_t)(b*TOK + t0 + tk)*MF + sg*32;
        const float* ks = ksum + b*MF + sg*32;
        float dd = 0.f;
        int xr = tk & 7;
        #pragma unroll
        for (int j8 = 0; j8 < 4; j8++) {
            u16x8 q0 = *(const u16x8*)&qrow[j8*8];
            #pragma unroll
            for (int j = 0; j < 8; j++) dd = fmaf(bf2f(q0[j]), ks[j8*8+j], dd);
            *(u16x8*)&A_s[tk*256 + (((sg*4 + j8) ^ xr) << 3)] = q0;
        }
        redD[tk][sg] = dd;
    }
    __syncthreads();
    if (tid < 64)
        D_s[tid] = redD[tid][0] + redD[tid][1] + redD[tid][2] + redD[tid][3] + 1e-8f;

    f32x4 acc[4][4];
    #define ZACC4() { _Pragma("unroll") for (int m_=0;m_<4;m_++) _Pragma("unroll") for (int n_=0;n_<4;n_++) { acc[m_][n_][0]=0.f;acc[m_][n_][1]=0.f;acc[m_][n_][2]=0.f;acc[m_][n_][3]=0.f; } }

    // ---- GEMM1: y_att = qp @ kptv^T, /D ----
    ZACC4();
    gemm4m<MF>(A_s, kptv_bf + (size_t)b*EMB*MF, acc, l15, l4, wid);
    __syncthreads();                               // qp reads done; D_s visible
    #pragma unroll
    for (int m = 0; m < 4; m++)
        #pragma unroll
        for (int nt = 0; nt < 4; nt++) {
            int col = wid*64 + nt*16 + l15;
            #pragma unroll
            for (int r = 0; r < 4; r++) {
                int row = m*16 + l4*4 + r;
                A_s[SWZ256(row, col)] = f2bf(acc[m][nt][r] / D_s[row]);
            }
        }
    __syncthreads();

    // ---- GEMM2: y2 = v + y_att @ w_proj + b_proj (y2 -> registers, f32) ----
    ZACC4();
    gemm4m<EMB>(A_s, wT, acc, l15, l4, wid);
    float y2[4][4][4];
    #pragma unroll
    for (int nt = 0; nt < 4; nt++) {
        int col = wid*64 + nt*16 + l15;
        float bp = b_proj[col];
        #pragma unroll
        for (int m = 0; m < 4; m++)
            #pragma unroll
            for (int r = 0; r < 4; r++) {
                int row = m*16 + l4*4 + r;
                y2[m][nt][r] = acc[m][nt][r] + bp
                             + bf2f(v_in[(size_t)(b*TOK + t0 + row)*EMB + col]);
            }
    }

    // ---- LayerNorm(y2) from registers: shfl over l15 + cross-wave LDS ----
    {
        #pragma unroll
        for (int m = 0; m < 4; m++)
            #pragma unroll
            for (int r = 0; r < 4; r++) {
                float s1 = 0.f, s2 = 0.f;
                #pragma unroll
                for (int nt = 0; nt < 4; nt++) {
                    float a = y2[m][nt][r];
                    s1 += a; s2 = fmaf(a, a, s2);
                }
                #pragma unroll
                for (int msk = 8; msk >= 1; msk >>= 1) {
                    s1 += __shfl_xor(s1, msk);
                    s2 += __shfl_xor(s2, msk);
                }
                if (l15 == 0) {
                    int row = m*16 + l4*4 + r;
                    red1[wid][row] = s1; red2[wid][row] = s2;
                }
            }
        __syncthreads();
        if (tid < 64) {
            float a = red1[0][tid] + red1[1][tid] + red1[2][tid] + red1[3][tid];
            float q = red2[0][tid] + red2[1][tid] + red2[2][tid] + red2[3][tid];
            float mu = a * (1.f/EMB);
            mu_s[tid] = mu;
            iv_s[tid] = rsqrtf(q*(1.f/EMB) - mu*mu + 1e-5f);
        }
        __syncthreads();
        // z -> A_s (bf16, swizzled)
        #pragma unroll
        for (int nt = 0; nt < 4; nt++) {
            int col = wid*64 + nt*16 + l15;
            float gg = g2[col], bb = b2[col];
            #pragma unroll
            for (int m = 0; m < 4; m++)
                #pragma unroll
                for (int r = 0; r < 4; r++) {
                    int row = m*16 + l4*4 + r;
                    A_s[SWZ256(row, col)] = f2bf((y2[m][nt][r] - mu_s[row])*iv_s[row]*gg + bb);
                }
        }
    }
    __syncthreads();

    // ---- GEMM3: h1 = gelu(z @ w_mlp1 + b_mlp1) ----
    ZACC4();
    gemm4m<EMB>(A_s, wT + 65536, acc, l15, l4, wid);
    __syncthreads();                               // z reads done
    #pragma unroll
    for (int nt = 0; nt < 4; nt++) {
        int col = wid*64 + nt*16 + l15;
        float bm = b_mlp1[col];
        #pragma unroll
        for (int m = 0; m < 4; m++)
            #pragma unroll
            for (int r = 0; r < 4; r++) {
                int row = m*16 + l4*4 + r;
                float a = acc[m][nt][r] + bm;
                A_s[SWZ256(row, col)] = f2bf(0.5f*a*(1.f + erff(a*0.70710678118654752f)));
            }
    }
    __syncthreads();

    // ---- GEMM4: y3 = y2 + h1 @ w_mlp2 + b_mlp2 ----
    ZACC4();
    gemm4m<EMB>(A_s, wT + 131072, acc, l15, l4, wid);
    #pragma unroll
    for (int nt = 0; nt < 4; nt++) {
        int col = wid*64 + nt*16 + l15;
        float bm = b_mlp2[col];
        #pragma unroll
        for (int m = 0; m < 4; m++)
            #pragma unroll
            for (int r = 0; r < 4; r++)
                y2[m][nt][r] += acc[m][nt][r] + bm;   // y2 now holds y3
    }
    __syncthreads();                                  // h1 reads done; A_s reusable

    // ---- output: two passes via A_s as f32 [32][256], channel-major write ----
    float* A_f = (float*)A_s;
    #pragma unroll
    for (int mh = 0; mh < 2; mh++) {
        #pragma unroll
        for (int nt = 0; nt < 4; nt++) {
            int col = wid*64 + nt*16 + l15;
            #pragma unroll
            for (int mi = 0; mi < 2; mi++) {
                int m = mh*2 + mi;
                #pragma unroll
                for (int r = 0; r < 4; r++)
                    A_f[(mi*16 + l4*4 + r)*256 + col] = y2[m][nt][r];
            }
        }
        __syncthreads();
        {
            float* dst = img2 + ((size_t)(b*EMB + tid))*TOK + t0 + mh*32;
            #pragma unroll
            for (int t4 = 0; t4 < 32; t4 += 4) {
                f32x4 pk;
                #pragma unroll
                for (int j = 0; j < 4; j++) pk[j] = A_f[(t4+j)*256 + tid];
                *(f32x4*)&dst[t4] = pk;
            }
        }
        __syncthreads();
    }
}

// ---------------- kernel 6: bilinear upsample x2, align_corners=True -------------
__global__ __launch_bounds__(256) void k6_upsample(const float* __restrict__ img2, float* __restrict__ out)
{
    int idx = blockIdx.x*256 + threadIdx.x;
    int wo = idx & 255;
    int ho = (idx >> 8) & 255;
    int c  = (idx >> 16) & 255;
    int b  = idx >> 24;
    const float sc = 127.f/255.f;
    float fh = ho * sc; int h0 = (int)fh; if (h0 > 126) h0 = 126; float th = fh - h0;
    float fw = wo * sc; int w0 = (int)fw; if (w0 > 126) w0 = 126; float tw = fw - w0;
    const float* p = img2 + (((size_t)b*EMB + c)*128 + h0)*128 + w0;
    float a00 = p[0], a01 = p[1], a10 = p[128], a11 = p[129];
    float top = fmaf(a01 - a00, tw, a00);
    float bot = fmaf(a11 - a10, tw, a10);
    out[idx] = fmaf(bot - top, th, top);
}

extern "C" void kernel_launch(void* const* d_in, const int* in_sizes, int n_in,
                              void* d_out, int out_size, void* d_ws, size_t ws_size,
                              hipStream_t stream)
{
    const float* x      = (const float*)d_in[0];
    const float* g1     = (const float*)d_in[1];
    const float* b1     = (const float*)d_in[2];
    const float* w_kqv  = (const float*)d_in[3];
    const float* b_kqv  = (const float*)d_in[4];
    const float* w_prm  = (const float*)d_in[5];
    const float* w_proj = (const float*)d_in[6];
    const float* b_proj = (const float*)d_in[7];
    const float* g2     = (const float*)d_in[8];
    const float* b2     = (const float*)d_in[9];
    const float* w_mlp1 = (const float*)d_in[10];
    const float* b_mlp1 = (const float*)d_in[11];
    const float* w_mlp2 = (const float*)d_in[12];
    const float* b_mlp2 = (const float*)d_in[13];
    float* out = (float*)d_out;
    float* ws  = (float*)d_ws;

    ushort* v_bf    = (ushort*)(ws);
    ushort* qp_bf   = (ushort*)(ws + 8388608);
    ushort* vT_bf   = (ushort*)(ws + 12582912);
    ushort* kpT_bf  = (ushort*)(ws + 20971520);
    float*  img2    = ws + 12582912;
    float*  ksum    = ws + 29360128;
    ushort* wkqvT   = (ushort*)(ws + 29360640);
    ushort* wprm_bf = (ushort*)(ws + 29385216);
    ushort* wT3     = (ushort*)(ws + 29401600);
    ushort* kptv_bf = (ushort*)(ws + 29499904);
    float*  part    = ws + 29532672;

    hipLaunchKernelGGL(kprep, dim3(1664), dim3(256), 0, stream,
                       w_kqv, w_prm, w_proj, w_mlp1, w_mlp2, wkqvT, wprm_bf, wT3);
    hipLaunchKernelGGL(k1_mfma, dim3(2048), dim3(256), 0, stream,
                       x, g1, b1, wkqvT, b_kqv, wprm_bf, v_bf, vT_bf, kpT_bf, qp_bf);
    hipLaunchKernelGGL(k2_ksum, dim3(512), dim3(256), 0, stream, kpT_bf, ksum);
    hipLaunchKernelGGL(k3_kptv_mfma, dim3(512), dim3(256), 0, stream, vT_bf, kpT_bf, part);
    hipLaunchKernelGGL(k3r_reduce, dim3(512), dim3(256), 0, stream, part, kptv_bf);
    hipLaunchKernelGGL(k4_attn_tail, dim3(1024), dim3(256), 0, stream,
                       qp_bf, v_bf, ksum, kptv_bf, wT3, b_proj, g2, b2,
                       b_mlp1, b_mlp2, img2);
    hipLaunchKernelGGL(k6_upsample, dim3(262144), dim3(256), 0, stream, img2, out);
}

// Round 5
// 408.182 us; speedup vs baseline: 3.8153x; 1.0286x over previous
//
#include <hip/hip_runtime.h>
#include <math.h>

#define TOK   16384
#define DIM   48
#define EMB   256
#define MF    128
#define IMGsz 129

typedef __attribute__((ext_vector_type(8))) short    bf16x8;
typedef __attribute__((ext_vector_type(8))) unsigned short u16x8;
typedef __attribute__((ext_vector_type(4))) float    f32x4;

__device__ __forceinline__ ushort f2bf(float f) {
    union { float f; unsigned u; } v; v.f = f;
    unsigned u = v.u;
    return (ushort)((u + 0x7fffu + ((u >> 16) & 1u)) >> 16);   // RNE
}
__device__ __forceinline__ float bf2f(ushort h) {
    union { unsigned u; float f; } v; v.u = ((unsigned)h) << 16; return v.f;
}

// swizzles: XOR 16B-chunk index with (row&7) -> conflict-free ds_read_b128
#define SWZ512(r,c) ((r)*512 + (((((c)>>3) ^ ((r)&7))) << 3) + ((c)&7))
#define SWZ64(r,c)  ((r)*64  + (((((c)>>3) ^ ((r)&7)) & 7) << 3) + ((c)&7))
#define SWZ256(r,c) ((r)*256 + (((((c)>>3) ^ ((r)&7))) << 3) + ((c)&7))

// ---------------- kprep: bf16 weight staging -------------------------------------
__global__ __launch_bounds__(256) void kprep(
    const float* __restrict__ w_kqv, const float* __restrict__ w_prm,
    const float* __restrict__ w_proj, const float* __restrict__ w_mlp1,
    const float* __restrict__ w_mlp2,
    ushort* __restrict__ wkqvT, ushort* __restrict__ wprm_bf, ushort* __restrict__ wT3)
{
    int blk = blockIdx.x, tid = threadIdx.x;
    if (blk < 768) {
        if (tid < 64) {
            float v = (tid < DIM) ? w_kqv[tid*768 + blk] : 0.f;
            wkqvT[blk*64 + tid] = f2bf(v);
        }
    } else if (blk < 896) {
        int m = blk - 768;
        wprm_bf[m*256 + tid] = f2bf(w_prm[m*256 + tid]);
    } else {
        int q = blk - 896;
        int w = q >> 8, n = q & 255;
        const float* src = (w == 0) ? w_proj : ((w == 1) ? w_mlp1 : w_mlp2);
        wT3[w*65536 + n*256 + tid] = f2bf(src[tid*256 + n]);
    }
}

// ---------------- kernel 1: unfold+LN+kqv+prm via MFMA (32 tokens/block) ---------
__global__ __launch_bounds__(256, 2) void k1_mfma(
    const float* __restrict__ x, const float* __restrict__ g1, const float* __restrict__ b1,
    const ushort* __restrict__ wkqvT, const float* __restrict__ b_kqv,
    const ushort* __restrict__ wprm_bf,
    ushort* __restrict__ v_out, ushort* __restrict__ vT_out,
    ushort* __restrict__ kpT_out, ushort* __restrict__ qp_out)
{
    __shared__ __align__(16) ushort kq_bf[32*512];
    __shared__ __align__(16) ushort vt_bf[32*256];
    __shared__ float xdp[4][32][2];
    __shared__ float xd2[32][2];
    __shared__ float red1[32][8], red2[32][8];
    __shared__ float mu_s[32], iv_s[32];

    float*  t_s  = (float*)kq_bf;
    ushort* h_bf = vt_bf;

    const int blk = blockIdx.x;                    // 2048
    const int b  = blk >> 9;
    const int t0 = (blk & 511) << 5;
    const int tid = threadIdx.x;
    const int wid = tid >> 6;
    const int l15 = tid & 15, l4 = (tid >> 4) & 3;

    for (int e = tid; e < 32*DIM; e += 256) {
        int tok = e / DIM, j = e - tok*DIM;
        int t = t0 + tok;
        int lh = t >> 7, lw = t & 127;
        int c = j >> 4, kh = (j >> 2) & 3, kw = j & 3;
        int ih = lh + kh - 1, iw = lw + kw - 1;
        float val = 0.f;
        if (ih >= 0 && ih < IMGsz && iw >= 0 && iw < IMGsz)
            val = x[((b*3 + c)*IMGsz + ih)*IMGsz + iw];
        t_s[tok*DIM + j] = val;
    }
    __syncthreads();

    {
        int tg = tid >> 3, sl = tid & 7;
        const float* tr = &t_s[tg*DIM + sl*6];
        float s1 = 0.f, s2 = 0.f;
        #pragma unroll
        for (int j = 0; j < 6; j++) { float a = tr[j]; s1 += a; s2 = fmaf(a, a, s2); }
        red1[tg][sl] = s1; red2[tg][sl] = s2;
        __syncthreads();
        if (tid < 32) {
            float a = 0.f, q = 0.f;
            #pragma unroll
            for (int j = 0; j < 8; j++) { a += red1[tid][j]; q += red2[tid][j]; }
            float mu = a * (1.f/DIM);
            mu_s[tid] = mu;
            iv_s[tid] = rsqrtf(q*(1.f/DIM) - mu*mu + 1e-5f);
        }
        __syncthreads();
        float mu = mu_s[tg], iv = iv_s[tg];
        #pragma unroll
        for (int j = 0; j < 6; j++) {
            int c = sl*6 + j;
            h_bf[SWZ64(tg, c)] = f2bf((tr[j]-mu)*iv*g1[c] + b1[c]);
        }
        h_bf[SWZ64(tg, 48 + sl*2    )] = 0;
        h_bf[SWZ64(tg, 48 + sl*2 + 1)] = 0;
    }
    __syncthreads();

    f32x4 acc[2][12];
    #pragma unroll
    for (int m = 0; m < 2; m++)
        #pragma unroll
        for (int j = 0; j < 12; j++) { acc[m][j][0]=0.f; acc[m][j][1]=0.f; acc[m][j][2]=0.f; acc[m][j][3]=0.f; }
    #pragma unroll
    for (int kc = 0; kc < 2; kc++) {
        int ch = ((kc*4 + l4) ^ (l15 & 7)) << 3;
        bf16x8 a0 = *(const bf16x8*)&h_bf[ l15      *64 + ch];
        bf16x8 a1 = *(const bf16x8*)&h_bf[(16 + l15)*64 + ch];
        #pragma unroll
        for (int j = 0; j < 12; j++) {
            int base = (wid + 4*j) * 16;
            bf16x8 bb = *(const bf16x8*)&wkqvT[(base + l15)*64 + kc*32 + l4*8];
            acc[0][j] = __builtin_amdgcn_mfma_f32_16x16x32_bf16(a0, bb, acc[0][j], 0, 0, 0);
            acc[1][j] = __builtin_amdgcn_mfma_f32_16x16x32_bf16(a1, bb, acc[1][j], 0, 0, 0);
        }
    }
    __syncthreads();

    {
        float pk[2][4], pq[2][4];
        #pragma unroll
        for (int m = 0; m < 2; m++)
            #pragma unroll
            for (int r = 0; r < 4; r++) { pk[m][r] = 0.f; pq[m][r] = 0.f; }
        #pragma unroll
        for (int j = 0; j < 12; j++) {
            int col = (wid + 4*j)*16 + l15;
            float bias = b_kqv[col];
            #pragma unroll
            for (int m = 0; m < 2; m++)
                #pragma unroll
                for (int r = 0; r < 4; r++) {
                    int row = m*16 + l4*4 + r;
                    float a = acc[m][j][r] + bias;
                    if (j < 4) {
                        pk[m][r] = fmaf(a, a, pk[m][r]);
                        kq_bf[SWZ512(row, col)] = f2bf(a);
                    } else if (j < 8) {
                        pq[m][r] = fmaf(a, a, pq[m][r]);
                        kq_bf[SWZ512(row, col)] = f2bf(a);
                    } else {
                        int n = col - 512;
                        ushort vb = f2bf(a);
                        v_out[(size_t)(b*TOK + t0 + row)*EMB + n] = vb;
                        vt_bf[row*256 + n] = vb;
                    }
                }
        }
        #pragma unroll
        for (int m = 0; m < 2; m++)
            #pragma unroll
            for (int r = 0; r < 4; r++) {
                float a = pk[m][r], q = pq[m][r];
                #pragma unroll
                for (int msk = 8; msk >= 1; msk >>= 1) {
                    a += __shfl_xor(a, msk);
                    q += __shfl_xor(q, msk);
                }
                if (l15 == 0) {
                    int row = m*16 + l4*4 + r;
                    xdp[wid][row][0] = a; xdp[wid][row][1] = q;
                }
            }
    }
    __syncthreads();
    if (tid < 64) {
        int row = tid >> 1, ty = tid & 1;
        xd2[row][ty] = 0.5f*(xdp[0][row][ty] + xdp[1][row][ty] + xdp[2][row][ty] + xdp[3][row][ty]);
    }

    {
        ushort* dst = vT_out + ((size_t)(b*EMB + tid))*TOK + t0;
        #pragma unroll
        for (int t8 = 0; t8 < 4; t8++) {
            u16x8 pk8;
            #pragma unroll
            for (int j = 0; j < 8; j++) pk8[j] = vt_bf[(t8*8 + j)*256 + tid];
            *(u16x8*)&dst[t8*8] = pk8;
        }
    }
    __syncthreads();

    f32x4 acc2[2][4];
    #pragma unroll
    for (int m = 0; m < 2; m++)
        #pragma unroll
        for (int n = 0; n < 4; n++) { acc2[m][n][0]=0.f; acc2[m][n][1]=0.f; acc2[m][n][2]=0.f; acc2[m][n][3]=0.f; }
    {
        const int cbase = (wid >= 2) ? 32 : 0;
        #pragma unroll
        for (int kc = 0; kc < 8; kc++) {
            int chunk = cbase + kc*4 + l4;
            int ch = (chunk ^ (l15 & 7)) << 3;
            bf16x8 a0 = *(const bf16x8*)&kq_bf[ l15      *512 + ch];
            bf16x8 a1 = *(const bf16x8*)&kq_bf[(16 + l15)*512 + ch];
            #pragma unroll
            for (int nt = 0; nt < 4; nt++) {
                int mcol = (wid & 1)*64 + nt*16 + l15;
                bf16x8 bb = *(const bf16x8*)&wprm_bf[mcol*256 + kc*32 + l4*8];
                acc2[0][nt] = __builtin_amdgcn_mfma_f32_16x16x32_bf16(a0, bb, acc2[0][nt], 0, 0, 0);
                acc2[1][nt] = __builtin_amdgcn_mfma_f32_16x16x32_bf16(a1, bb, acc2[1][nt], 0, 0, 0);
            }
        }
    }

    {
        const float scale = 0.08838834764831845f;
        const bool isK = (wid < 2);
        #pragma unroll
        for (int m = 0; m < 2; m++)
            #pragma unroll
            for (int nt = 0; nt < 4; nt++) {
                #pragma unroll
                for (int r = 0; r < 4; r++) {
                    int row = m*16 + l4*4 + r;
                    int mcol = (wid & 1)*64 + nt*16 + l15;
                    float e = expf(acc2[m][nt][r] - xd2[row][isK ? 0 : 1]) * scale;
                    ushort bf = f2bf(e);
                    if (isK) vt_bf[row*256 + mcol] = bf;
                    else qp_out[(size_t)(b*TOK + t0 + row)*MF + mcol] = bf;
                }
            }
    }
    __syncthreads();

    if (tid < 128) {
        ushort* dst = kpT_out + ((size_t)(b*MF + tid))*TOK + t0;
        #pragma unroll
        for (int t8 = 0; t8 < 4; t8++) {
            u16x8 pk8;
            #pragma unroll
            for (int j = 0; j < 8; j++) pk8[j] = vt_bf[(t8*8 + j)*256 + tid];
            *(u16x8*)&dst[t8*8] = pk8;
        }
    }
}

// ---------------- kernel 2: ksum[b][m] = row-sum of kp^T ------------------------
__global__ __launch_bounds__(256) void k2_ksum(const ushort* __restrict__ kpT, float* __restrict__ ksum)
{
    __shared__ float red[4];
    int blk = blockIdx.x;
    int b = blk >> 7, m = blk & 127;
    int tid = threadIdx.x;
    const ushort* row = kpT + (size_t)(b*MF + m)*TOK;
    float s = 0.f;
    for (int i = tid; i < TOK/8; i += 256) {
        u16x8 v = *(const u16x8*)&row[i*8];
        #pragma unroll
        for (int j = 0; j < 8; j++) s += bf2f(v[j]);
    }
    #pragma unroll
    for (int msk = 32; msk >= 1; msk >>= 1) s += __shfl_xor(s, msk);
    if ((tid & 63) == 0) red[tid >> 6] = s;
    __syncthreads();
    if (tid == 0) ksum[b*MF + m] = red[0] + red[1] + red[2] + red[3];
}

// ---------------- kernel 3: kptv partials via MFMA -------------------------------
__global__ __launch_bounds__(256) void k3_kptv_mfma(
    const ushort* __restrict__ vT, const ushort* __restrict__ kpT, float* __restrict__ part)
{
    int blk = blockIdx.x;            // 512: b(2b) | ns(1b) | kc(6b)
    int b = blk >> 7, ns = (blk >> 6) & 1, kc = blk & 63;
    const int tid = threadIdx.x;
    const int wid = tid >> 6;
    const int l15 = tid & 15, l4 = (tid >> 4) & 3;
    const int t0 = kc * 256;
    const int n0 = ns*128 + wid*32;

    f32x4 acc[2][8];
    #pragma unroll
    for (int m = 0; m < 2; m++)
        #pragma unroll
        for (int n = 0; n < 8; n++) { acc[m][n][0]=0.f; acc[m][n][1]=0.f; acc[m][n][2]=0.f; acc[m][n][3]=0.f; }

    #pragma unroll
    for (int ks = 0; ks < 8; ks++) {
        int k0 = t0 + ks*32 + l4*8;
        bf16x8 a0 = *(const bf16x8*)&vT[((size_t)(b*EMB + n0      + l15))*TOK + k0];
        bf16x8 a1 = *(const bf16x8*)&vT[((size_t)(b*EMB + n0 + 16 + l15))*TOK + k0];
        #pragma unroll
        for (int nt = 0; nt < 8; nt++) {
            bf16x8 bb = *(const bf16x8*)&kpT[((size_t)(b*MF + nt*16 + l15))*TOK + k0];
            acc[0][nt] = __builtin_amdgcn_mfma_f32_16x16x32_bf16(a0, bb, acc[0][nt], 0, 0, 0);
            acc[1][nt] = __builtin_amdgcn_mfma_f32_16x16x32_bf16(a1, bb, acc[1][nt], 0, 0, 0);
        }
    }
    #pragma unroll
    for (int mt = 0; mt < 2; mt++)
        #pragma unroll
        for (int nt = 0; nt < 8; nt++) {
            int n = n0 + mt*16 + l4*4;
            int m = nt*16 + l15;
            #pragma unroll
            for (int r = 0; r < 4; r++)
                part[(size_t)kc*131072 + (size_t)((b*EMB + n + r)*MF + m)] = acc[mt][nt][r];
        }
}

// ---------------- kernel 3r: reduce partials -> kptv bf16 ------------------------
__global__ __launch_bounds__(256) void k3r_reduce(const float* __restrict__ part, ushort* __restrict__ kptv_bf)
{
    int e = blockIdx.x*256 + threadIdx.x;
    float s = 0.f;
    #pragma unroll 8
    for (int kc = 0; kc < 64; kc++) s += part[(size_t)kc*131072 + e];
    kptv_bf[e] = f2bf(s);
}

// ---------------- kernel 4 v3: 32 tok/block, y2 in regs, 4 blocks/CU -------------
// A_s: bf16 [32][256] swizzled (16KB) for GEMM A-operands; same 32KB allocation
// reused as f32 [32][256] for the channel-major output staging.
template<int K>
__device__ __forceinline__ void gemm32(const ushort* A_s, const ushort* __restrict__ B,
                                       f32x4 acc[2][4], int l15, int l4, int wid)
{
    #pragma unroll
    for (int kc = 0; kc < (K >> 5); kc++) {
        const int ch = ((kc*4 + l4) ^ (l15 & 7)) << 3;
        bf16x8 a0 = *(const bf16x8*)&A_s[ l15      *256 + ch];
        bf16x8 a1 = *(const bf16x8*)&A_s[(16 + l15)*256 + ch];
        #pragma unroll
        for (int nt = 0; nt < 4; nt++) {
            bf16x8 bb = *(const bf16x8*)&B[(wid*64 + nt*16 + l15)*K + kc*32 + l4*8];
            acc[0][nt] = __builtin_amdgcn_mfma_f32_16x16x32_bf16(a0, bb, acc[0][nt], 0, 0, 0);
            acc[1][nt] = __builtin_amdgcn_mfma_f32_16x16x32_bf16(a1, bb, acc[1][nt], 0, 0, 0);
        }
    }
}

__global__ __launch_bounds__(256, 4) void k4_attn_tail(
    const ushort* __restrict__ qp, const ushort* __restrict__ v_in,
    const float* __restrict__ ksum, const ushort* __restrict__ kptv_bf,
    const ushort* __restrict__ wT,
    const float* __restrict__ b_proj,
    const float* __restrict__ g2, const float* __restrict__ b2,
    const float* __restrict__ b_mlp1, const float* __restrict__ b_mlp2,
    float* __restrict__ img2)
{
    __shared__ __align__(16) ushort A_s[64*256];   // 32 KB (bf16 A tile + f32 out staging)
    __shared__ float D_s[32];
    __shared__ float redD[32][8];
    __shared__ float red1[4][32], red2[4][32];
    __shared__ float mu_s[32], iv_s[32];

    const int blk = blockIdx.x;                    // 2048
    const int b  = blk >> 9;
    const int t0 = (blk & 511) << 5;               // 32 tokens/block
    const int tid = threadIdx.x;
    const int wid = tid >> 6;
    const int lane = tid & 63;
    const int l15 = lane & 15, l4 = lane >> 4;

    // ---- stage qp (bf16 swizzled copy) + D = qp . ksum ----
    {
        int tk = tid >> 3, seg = tid & 7;          // 32 rows x 8 segs of 16 cols
        const ushort* qrow = qp + (size_t)(b*TOK + t0 + tk)*MF + seg*16;
        u16x8 q0 = *(const u16x8*)&qrow[0];
        u16x8 q1 = *(const u16x8*)&qrow[8];
        const float* ks = ksum + b*MF + seg*16;
        float dd = 0.f;
        #pragma unroll
        for (int j = 0; j < 8; j++) {
            dd = fmaf(bf2f(q0[j]), ks[j],   dd);
            dd = fmaf(bf2f(q1[j]), ks[j+8], dd);
        }
        redD[tk][seg] = dd;
        int xr = tk & 7;
        *(u16x8*)&A_s[tk*256 + (((seg*2  ) ^ xr) << 3)] = q0;
        *(u16x8*)&A_s[tk*256 + (((seg*2+1) ^ xr) << 3)] = q1;
    }
    __syncthreads();
    if (tid < 32) {
        float s = 0.f;
        #pragma unroll
        for (int j = 0; j < 8; j++) s += redD[tid][j];
        D_s[tid] = s + 1e-8f;
    }

    f32x4 acc[2][4];
    #define ZACC() { _Pragma("unroll") for (int m_=0;m_<2;m_++) _Pragma("unroll") for (int n_=0;n_<4;n_++) { acc[m_][n_][0]=0.f;acc[m_][n_][1]=0.f;acc[m_][n_][2]=0.f;acc[m_][n_][3]=0.f; } }

    // ---- GEMM1: y_att = qp @ kptv^T, /D ----
    ZACC();
    gemm32<MF>(A_s, kptv_bf + (size_t)b*EMB*MF, acc, l15, l4, wid);
    __syncthreads();                               // qp reads done; D_s visible
    #pragma unroll
    for (int m = 0; m < 2; m++)
        #pragma unroll
        for (int nt = 0; nt < 4; nt++) {
            int col = wid*64 + nt*16 + l15;
            #pragma unroll
            for (int r = 0; r < 4; r++) {
                int row = m*16 + l4*4 + r;
                A_s[SWZ256(row, col)] = f2bf(acc[m][nt][r] / D_s[row]);
            }
        }
    __syncthreads();

    // ---- GEMM2: y2 = v + y_att @ w_proj + b_proj (y2 -> 32 f32 regs) ----
    ZACC();
    gemm32<EMB>(A_s, wT, acc, l15, l4, wid);
    float y2[2][4][4];
    #pragma unroll
    for (int nt = 0; nt < 4; nt++) {
        int col = wid*64 + nt*16 + l15;
        float bp = b_proj[col];
        #pragma unroll
        for (int m = 0; m < 2; m++)
            #pragma unroll
            for (int r = 0; r < 4; r++) {
                int row = m*16 + l4*4 + r;
                y2[m][nt][r] = acc[m][nt][r] + bp
                             + bf2f(v_in[(size_t)(b*TOK + t0 + row)*EMB + col]);
            }
    }

    // ---- LayerNorm(y2): shfl over l15 + cross-wave LDS ----
    {
        #pragma unroll
        for (int m = 0; m < 2; m++)
            #pragma unroll
            for (int r = 0; r < 4; r++) {
                float s1 = 0.f, s2 = 0.f;
                #pragma unroll
                for (int nt = 0; nt < 4; nt++) {
                    float a = y2[m][nt][r];
                    s1 += a; s2 = fmaf(a, a, s2);
                }
                #pragma unroll
                for (int msk = 8; msk >= 1; msk >>= 1) {
                    s1 += __shfl_xor(s1, msk);
                    s2 += __shfl_xor(s2, msk);
                }
                if (l15 == 0) {
                    int row = m*16 + l4*4 + r;
                    red1[wid][row] = s1; red2[wid][row] = s2;
                }
            }
        __syncthreads();
        if (tid < 32) {
            float a = red1[0][tid] + red1[1][tid] + red1[2][tid] + red1[3][tid];
            float q = red2[0][tid] + red2[1][tid] + red2[2][tid] + red2[3][tid];
            float mu = a * (1.f/EMB);
            mu_s[tid] = mu;
            iv_s[tid] = rsqrtf(q*(1.f/EMB) - mu*mu + 1e-5f);
        }
        __syncthreads();
        #pragma unroll
        for (int nt = 0; nt < 4; nt++) {
            int col = wid*64 + nt*16 + l15;
            float gg = g2[col], bb = b2[col];
            #pragma unroll
            for (int m = 0; m < 2; m++)
                #pragma unroll
                for (int r = 0; r < 4; r++) {
                    int row = m*16 + l4*4 + r;
                    A_s[SWZ256(row, col)] = f2bf((y2[m][nt][r] - mu_s[row])*iv_s[row]*gg + bb);
                }
        }
    }
    __syncthreads();

    // ---- GEMM3: h1 = gelu(z @ w_mlp1 + b_mlp1) ----
    ZACC();
    gemm32<EMB>(A_s, wT + 65536, acc, l15, l4, wid);
    __syncthreads();                               // z reads done
    #pragma unroll
    for (int nt = 0; nt < 4; nt++) {
        int col = wid*64 + nt*16 + l15;
        float bm = b_mlp1[col];
        #pragma unroll
        for (int m = 0; m < 2; m++)
            #pragma unroll
            for (int r = 0; r < 4; r++) {
                int row = m*16 + l4*4 + r;
                float a = acc[m][nt][r] + bm;
                A_s[SWZ256(row, col)] = f2bf(0.5f*a*(1.f + erff(a*0.70710678118654752f)));
            }
    }
    __syncthreads();

    // ---- GEMM4: y3 = y2 + h1 @ w_mlp2 + b_mlp2 ----
    ZACC();
    gemm32<EMB>(A_s, wT + 131072, acc, l15, l4, wid);
    #pragma unroll
    for (int nt = 0; nt < 4; nt++) {
        int col = wid*64 + nt*16 + l15;
        float bm = b_mlp2[col];
        #pragma unroll
        for (int m = 0; m < 2; m++)
            #pragma unroll
            for (int r = 0; r < 4; r++)
                y2[m][nt][r] += acc[m][nt][r] + bm;   // y2 now holds y3
    }
    __syncthreads();                                  // h1 reads done; A_s reusable

    // ---- output: stage all 32 rows as f32 in A_s (32KB), channel-major write ----
    float* A_f = (float*)A_s;                        // [32][256] f32
    #pragma unroll
    for (int nt = 0; nt < 4; nt++) {
        int col = wid*64 + nt*16 + l15;
        #pragma unroll
        for (int m = 0; m < 2; m++)
            #pragma unroll
            for (int r = 0; r < 4; r++)
                A_f[(m*16 + l4*4 + r)*256 + col] = y2[m][nt][r];
    }
    __syncthreads();
    {
        float* dst = img2 + ((size_t)(b*EMB + tid))*TOK + t0;
        #pragma unroll
        for (int t4 = 0; t4 < 32; t4 += 4) {
            f32x4 pk;
            #pragma unroll
            for (int j = 0; j < 4; j++) pk[j] = A_f[(t4+j)*256 + tid];
            *(f32x4*)&dst[t4] = pk;
        }
    }
}

// ---------------- kernel 6: bilinear upsample x2, align_corners=True -------------
__global__ __launch_bounds__(256) void k6_upsample(const float* __restrict__ img2, float* __restrict__ out)
{
    int idx = blockIdx.x*256 + threadIdx.x;
    int wo = idx & 255;
    int ho = (idx >> 8) & 255;
    int c  = (idx >> 16) & 255;
    int b  = idx >> 24;
    const float sc = 127.f/255.f;
    float fh = ho * sc; int h0 = (int)fh; if (h0 > 126) h0 = 126; float th = fh - h0;
    float fw = wo * sc; int w0 = (int)fw; if (w0 > 126) w0 = 126; float tw = fw - w0;
    const float* p = img2 + (((size_t)b*EMB + c)*128 + h0)*128 + w0;
    float a00 = p[0], a01 = p[1], a10 = p[128], a11 = p[129];
    float top = fmaf(a01 - a00, tw, a00);
    float bot = fmaf(a11 - a10, tw, a10);
    out[idx] = fmaf(bot - top, th, top);
}

extern "C" void kernel_launch(void* const* d_in, const int* in_sizes, int n_in,
                              void* d_out, int out_size, void* d_ws, size_t ws_size,
                              hipStream_t stream)
{
    const float* x      = (const float*)d_in[0];
    const float* g1     = (const float*)d_in[1];
    const float* b1     = (const float*)d_in[2];
    const float* w_kqv  = (const float*)d_in[3];
    const float* b_kqv  = (const float*)d_in[4];
    const float* w_prm  = (const float*)d_in[5];
    const float* w_proj = (const float*)d_in[6];
    const float* b_proj = (const float*)d_in[7];
    const float* g2     = (const float*)d_in[8];
    const float* b2     = (const float*)d_in[9];
    const float* w_mlp1 = (const float*)d_in[10];
    const float* b_mlp1 = (const float*)d_in[11];
    const float* w_mlp2 = (const float*)d_in[12];
    const float* b_mlp2 = (const float*)d_in[13];
    float* out = (float*)d_out;
    float* ws  = (float*)d_ws;

    ushort* v_bf    = (ushort*)(ws);
    ushort* qp_bf   = (ushort*)(ws + 8388608);
    ushort* vT_bf   = (ushort*)(ws + 12582912);
    ushort* kpT_bf  = (ushort*)(ws + 20971520);
    float*  img2    = ws + 12582912;
    float*  ksum    = ws + 29360128;
    ushort* wkqvT   = (ushort*)(ws + 29360640);
    ushort* wprm_bf = (ushort*)(ws + 29385216);
    ushort* wT3     = (ushort*)(ws + 29401600);
    ushort* kptv_bf = (ushort*)(ws + 29499904);
    float*  part    = ws + 29532672;

    hipLaunchKernelGGL(kprep, dim3(1664), dim3(256), 0, stream,
                       w_kqv, w_prm, w_proj, w_mlp1, w_mlp2, wkqvT, wprm_bf, wT3);
    hipLaunchKernelGGL(k1_mfma, dim3(2048), dim3(256), 0, stream,
                       x, g1, b1, wkqvT, b_kqv, wprm_bf, v_bf, vT_bf, kpT_bf, qp_bf);
    hipLaunchKernelGGL(k2_ksum, dim3(512), dim3(256), 0, stream, kpT_bf, ksum);
    hipLaunchKernelGGL(k3_kptv_mfma, dim3(512), dim3(256), 0, stream, vT_bf, kpT_bf, part);
    hipLaunchKernelGGL(k3r_reduce, dim3(512), dim3(256), 0, stream, part, kptv_bf);
    hipLaunchKernelGGL(k4_attn_tail, dim3(2048), dim3(256), 0, stream,
                       qp_bf, v_bf, ksum, kptv_bf, wT3, b_proj, g2, b2,
                       b_mlp1, b_mlp2, img2);
    hipLaunchKernelGGL(k6_upsample, dim3(262144), dim3(256), 0, stream, img2, out);
}

// Round 6
// 404.240 us; speedup vs baseline: 3.8525x; 1.0098x over previous
//
#include <hip/hip_runtime.h>
#include <math.h>

#define TOK   16384
#define DIM   48
#define EMB   256
#define MF    128
#define IMGsz 129

typedef __attribute__((ext_vector_type(8))) short    bf16x8;
typedef __attribute__((ext_vector_type(8))) unsigned short u16x8;
typedef __attribute__((ext_vector_type(4))) float    f32x4;

__device__ __forceinline__ ushort f2bf(float f) {
    union { float f; unsigned u; } v; v.f = f;
    unsigned u = v.u;
    return (ushort)((u + 0x7fffu + ((u >> 16) & 1u)) >> 16);   // RNE
}
__device__ __forceinline__ float bf2f(ushort h) {
    union { unsigned u; float f; } v; v.u = ((unsigned)h) << 16; return v.f;
}

// swizzles: XOR 16B-chunk index with (row&7) -> conflict-free ds_read_b128
#define SWZ512(r,c) ((r)*512 + (((((c)>>3) ^ ((r)&7))) << 3) + ((c)&7))
#define SWZ64(r,c)  ((r)*64  + (((((c)>>3) ^ ((r)&7)) & 7) << 3) + ((c)&7))
#define SWZ256(r,c) ((r)*256 + (((((c)>>3) ^ ((r)&7))) << 3) + ((c)&7))

// ---------------- kprep: bf16 weight staging -------------------------------------
__global__ __launch_bounds__(256) void kprep(
    const float* __restrict__ w_kqv, const float* __restrict__ w_prm,
    const float* __restrict__ w_proj, const float* __restrict__ w_mlp1,
    const float* __restrict__ w_mlp2,
    ushort* __restrict__ wkqvT, ushort* __restrict__ wprm_bf, ushort* __restrict__ wT3)
{
    int blk = blockIdx.x, tid = threadIdx.x;
    if (blk < 768) {
        if (tid < 64) {
            float v = (tid < DIM) ? w_kqv[tid*768 + blk] : 0.f;
            wkqvT[blk*64 + tid] = f2bf(v);
        }
    } else if (blk < 896) {
        int m = blk - 768;
        wprm_bf[m*256 + tid] = f2bf(w_prm[m*256 + tid]);
    } else {
        int q = blk - 896;
        int w = q >> 8, n = q & 255;
        const float* src = (w == 0) ? w_proj : ((w == 1) ? w_mlp1 : w_mlp2);
        wT3[w*65536 + n*256 + tid] = f2bf(src[tid*256 + n]);
    }
}

// ---------------- kernel 1: unfold+LN+kqv+prm via MFMA (32 tokens/block) ---------
__global__ __launch_bounds__(256, 2) void k1_mfma(
    const float* __restrict__ x, const float* __restrict__ g1, const float* __restrict__ b1,
    const ushort* __restrict__ wkqvT, const float* __restrict__ b_kqv,
    const ushort* __restrict__ wprm_bf,
    ushort* __restrict__ vfrag_out, ushort* __restrict__ vT_out,
    ushort* __restrict__ kpT_out, ushort* __restrict__ qp_out)
{
    __shared__ __align__(16) ushort kq_bf[32*512];
    __shared__ __align__(16) ushort vt_bf[32*256];
    __shared__ float xdp[4][32][2];
    __shared__ float xd2[32][2];
    __shared__ float red1[32][8], red2[32][8];
    __shared__ float mu_s[32], iv_s[32];

    float*  t_s  = (float*)kq_bf;
    ushort* h_bf = vt_bf;

    const int blk = blockIdx.x;                    // 2048
    const int b  = blk >> 9;
    const int t0 = (blk & 511) << 5;
    const int tid = threadIdx.x;
    const int wid = tid >> 6;
    const int l15 = tid & 15, l4 = (tid >> 4) & 3;

    for (int e = tid; e < 32*DIM; e += 256) {
        int tok = e / DIM, j = e - tok*DIM;
        int t = t0 + tok;
        int lh = t >> 7, lw = t & 127;
        int c = j >> 4, kh = (j >> 2) & 3, kw = j & 3;
        int ih = lh + kh - 1, iw = lw + kw - 1;
        float val = 0.f;
        if (ih >= 0 && ih < IMGsz && iw >= 0 && iw < IMGsz)
            val = x[((b*3 + c)*IMGsz + ih)*IMGsz + iw];
        t_s[tok*DIM + j] = val;
    }
    __syncthreads();

    {
        int tg = tid >> 3, sl = tid & 7;
        const float* tr = &t_s[tg*DIM + sl*6];
        float s1 = 0.f, s2 = 0.f;
        #pragma unroll
        for (int j = 0; j < 6; j++) { float a = tr[j]; s1 += a; s2 = fmaf(a, a, s2); }
        red1[tg][sl] = s1; red2[tg][sl] = s2;
        __syncthreads();
        if (tid < 32) {
            float a = 0.f, q = 0.f;
            #pragma unroll
            for (int j = 0; j < 8; j++) { a += red1[tid][j]; q += red2[tid][j]; }
            float mu = a * (1.f/DIM);
            mu_s[tid] = mu;
            iv_s[tid] = rsqrtf(q*(1.f/DIM) - mu*mu + 1e-5f);
        }
        __syncthreads();
        float mu = mu_s[tg], iv = iv_s[tg];
        #pragma unroll
        for (int j = 0; j < 6; j++) {
            int c = sl*6 + j;
            h_bf[SWZ64(tg, c)] = f2bf((tr[j]-mu)*iv*g1[c] + b1[c]);
        }
        h_bf[SWZ64(tg, 48 + sl*2    )] = 0;
        h_bf[SWZ64(tg, 48 + sl*2 + 1)] = 0;
    }
    __syncthreads();

    f32x4 acc[2][12];
    #pragma unroll
    for (int m = 0; m < 2; m++)
        #pragma unroll
        for (int j = 0; j < 12; j++) { acc[m][j][0]=0.f; acc[m][j][1]=0.f; acc[m][j][2]=0.f; acc[m][j][3]=0.f; }
    #pragma unroll
    for (int kc = 0; kc < 2; kc++) {
        int ch = ((kc*4 + l4) ^ (l15 & 7)) << 3;
        bf16x8 a0 = *(const bf16x8*)&h_bf[ l15      *64 + ch];
        bf16x8 a1 = *(const bf16x8*)&h_bf[(16 + l15)*64 + ch];
        #pragma unroll
        for (int j = 0; j < 12; j++) {
            int base = (wid + 4*j) * 16;
            bf16x8 bb = *(const bf16x8*)&wkqvT[(base + l15)*64 + kc*32 + l4*8];
            acc[0][j] = __builtin_amdgcn_mfma_f32_16x16x32_bf16(a0, bb, acc[0][j], 0, 0, 0);
            acc[1][j] = __builtin_amdgcn_mfma_f32_16x16x32_bf16(a1, bb, acc[1][j], 0, 0, 0);
        }
    }
    __syncthreads();

    {
        float pk[2][4], pq[2][4];
        #pragma unroll
        for (int m = 0; m < 2; m++)
            #pragma unroll
            for (int r = 0; r < 4; r++) { pk[m][r] = 0.f; pq[m][r] = 0.f; }
        #pragma unroll
        for (int j = 0; j < 12; j++) {
            int col = (wid + 4*j)*16 + l15;
            float bias = b_kqv[col];
            #pragma unroll
            for (int m = 0; m < 2; m++)
                #pragma unroll
                for (int r = 0; r < 4; r++) {
                    int row = m*16 + l4*4 + r;
                    float a = acc[m][j][r] + bias;
                    if (j < 4) {
                        pk[m][r] = fmaf(a, a, pk[m][r]);
                        kq_bf[SWZ512(row, col)] = f2bf(a);
                    } else if (j < 8) {
                        pq[m][r] = fmaf(a, a, pq[m][r]);
                        kq_bf[SWZ512(row, col)] = f2bf(a);
                    } else {
                        int n = col - 512;
                        vt_bf[row*256 + n] = f2bf(a);
                    }
                }
        }
        #pragma unroll
        for (int m = 0; m < 2; m++)
            #pragma unroll
            for (int r = 0; r < 4; r++) {
                float a = pk[m][r], q = pq[m][r];
                #pragma unroll
                for (int msk = 8; msk >= 1; msk >>= 1) {
                    a += __shfl_xor(a, msk);
                    q += __shfl_xor(q, msk);
                }
                if (l15 == 0) {
                    int row = m*16 + l4*4 + r;
                    xdp[wid][row][0] = a; xdp[wid][row][1] = q;
                }
            }
    }
    __syncthreads();
    if (tid < 64) {
        int row = tid >> 1, ty = tid & 1;
        xd2[row][ty] = 0.5f*(xdp[0][row][ty] + xdp[1][row][ty] + xdp[2][row][ty] + xdp[3][row][ty]);
    }

    // ---- P4: v^T coalesced write (thread = n channel) ----
    {
        ushort* dst = vT_out + ((size_t)(b*EMB + tid))*TOK + t0;
        #pragma unroll
        for (int t8 = 0; t8 < 4; t8++) {
            u16x8 pk8;
            #pragma unroll
            for (int j = 0; j < 8; j++) pk8[j] = vt_bf[(t8*8 + j)*256 + tid];
            *(u16x8*)&dst[t8*8] = pk8;
        }
    }
    // ---- P4b: v fragment-major write (k4 residual layout, coalesced 64B/thread) ----
    {
        u16x8 pk8[4];
        #pragma unroll
        for (int m = 0; m < 2; m++)
            #pragma unroll
            for (int nt = 0; nt < 4; nt++)
                #pragma unroll
                for (int r = 0; r < 4; r++) {
                    int row = m*16 + l4*4 + r;
                    int col = wid*64 + nt*16 + l15;
                    int idx = m*16 + nt*4 + r;
                    pk8[idx >> 3][idx & 7] = vt_bf[row*256 + col];
                }
        ushort* dst = vfrag_out + (size_t)blk*8192 + tid*32;
        #pragma unroll
        for (int i = 0; i < 4; i++) *(u16x8*)&dst[i*8] = pk8[i];
    }
    __syncthreads();

    f32x4 acc2[2][4];
    #pragma unroll
    for (int m = 0; m < 2; m++)
        #pragma unroll
        for (int n = 0; n < 4; n++) { acc2[m][n][0]=0.f; acc2[m][n][1]=0.f; acc2[m][n][2]=0.f; acc2[m][n][3]=0.f; }
    {
        const int cbase = (wid >= 2) ? 32 : 0;
        #pragma unroll
        for (int kc = 0; kc < 8; kc++) {
            int chunk = cbase + kc*4 + l4;
            int ch = (chunk ^ (l15 & 7)) << 3;
            bf16x8 a0 = *(const bf16x8*)&kq_bf[ l15      *512 + ch];
            bf16x8 a1 = *(const bf16x8*)&kq_bf[(16 + l15)*512 + ch];
            #pragma unroll
            for (int nt = 0; nt < 4; nt++) {
                int mcol = (wid & 1)*64 + nt*16 + l15;
                bf16x8 bb = *(const bf16x8*)&wprm_bf[mcol*256 + kc*32 + l4*8];
                acc2[0][nt] = __builtin_amdgcn_mfma_f32_16x16x32_bf16(a0, bb, acc2[0][nt], 0, 0, 0);
                acc2[1][nt] = __builtin_amdgcn_mfma_f32_16x16x32_bf16(a1, bb, acc2[1][nt], 0, 0, 0);
            }
        }
    }

    {
        const float scale = 0.08838834764831845f;
        const bool isK = (wid < 2);
        #pragma unroll
        for (int m = 0; m < 2; m++)
            #pragma unroll
            for (int nt = 0; nt < 4; nt++) {
                #pragma unroll
                for (int r = 0; r < 4; r++) {
                    int row = m*16 + l4*4 + r;
                    int mcol = (wid & 1)*64 + nt*16 + l15;
                    float e = expf(acc2[m][nt][r] - xd2[row][isK ? 0 : 1]) * scale;
                    ushort bf = f2bf(e);
                    if (isK) vt_bf[row*256 + mcol] = bf;
                    else qp_out[(size_t)(b*TOK + t0 + row)*MF + mcol] = bf;
                }
            }
    }
    __syncthreads();

    if (tid < 128) {
        ushort* dst = kpT_out + ((size_t)(b*MF + tid))*TOK + t0;
        #pragma unroll
        for (int t8 = 0; t8 < 4; t8++) {
            u16x8 pk8;
            #pragma unroll
            for (int j = 0; j < 8; j++) pk8[j] = vt_bf[(t8*8 + j)*256 + tid];
            *(u16x8*)&dst[t8*8] = pk8;
        }
    }
}

// ---------------- kernel 2: ksum[b][m] = row-sum of kp^T ------------------------
__global__ __launch_bounds__(256) void k2_ksum(const ushort* __restrict__ kpT, float* __restrict__ ksum)
{
    __shared__ float red[4];
    int blk = blockIdx.x;
    int b = blk >> 7, m = blk & 127;
    int tid = threadIdx.x;
    const ushort* row = kpT + (size_t)(b*MF + m)*TOK;
    float s = 0.f;
    for (int i = tid; i < TOK/8; i += 256) {
        u16x8 v = *(const u16x8*)&row[i*8];
        #pragma unroll
        for (int j = 0; j < 8; j++) s += bf2f(v[j]);
    }
    #pragma unroll
    for (int msk = 32; msk >= 1; msk >>= 1) s += __shfl_xor(s, msk);
    if ((tid & 63) == 0) red[tid >> 6] = s;
    __syncthreads();
    if (tid == 0) ksum[b*MF + m] = red[0] + red[1] + red[2] + red[3];
}

// ---------------- kernel 3: kptv partials via MFMA -------------------------------
__global__ __launch_bounds__(256) void k3_kptv_mfma(
    const ushort* __restrict__ vT, const ushort* __restrict__ kpT, float* __restrict__ part)
{
    int blk = blockIdx.x;            // 512: b(2b) | ns(1b) | kc(6b)
    int b = blk >> 7, ns = (blk >> 6) & 1, kc = blk & 63;
    const int tid = threadIdx.x;
    const int wid = tid >> 6;
    const int l15 = tid & 15, l4 = (tid >> 4) & 3;
    const int t0 = kc * 256;
    const int n0 = ns*128 + wid*32;

    f32x4 acc[2][8];
    #pragma unroll
    for (int m = 0; m < 2; m++)
        #pragma unroll
        for (int n = 0; n < 8; n++) { acc[m][n][0]=0.f; acc[m][n][1]=0.f; acc[m][n][2]=0.f; acc[m][n][3]=0.f; }

    #pragma unroll
    for (int ks = 0; ks < 8; ks++) {
        int k0 = t0 + ks*32 + l4*8;
        bf16x8 a0 = *(const bf16x8*)&vT[((size_t)(b*EMB + n0      + l15))*TOK + k0];
        bf16x8 a1 = *(const bf16x8*)&vT[((size_t)(b*EMB + n0 + 16 + l15))*TOK + k0];
        #pragma unroll
        for (int nt = 0; nt < 8; nt++) {
            bf16x8 bb = *(const bf16x8*)&kpT[((size_t)(b*MF + nt*16 + l15))*TOK + k0];
            acc[0][nt] = __builtin_amdgcn_mfma_f32_16x16x32_bf16(a0, bb, acc[0][nt], 0, 0, 0);
            acc[1][nt] = __builtin_amdgcn_mfma_f32_16x16x32_bf16(a1, bb, acc[1][nt], 0, 0, 0);
        }
    }
    #pragma unroll
    for (int mt = 0; mt < 2; mt++)
        #pragma unroll
        for (int nt = 0; nt < 8; nt++) {
            int n = n0 + mt*16 + l4*4;
            int m = nt*16 + l15;
            #pragma unroll
            for (int r = 0; r < 4; r++)
                part[(size_t)kc*131072 + (size_t)((b*EMB + n + r)*MF + m)] = acc[mt][nt][r];
        }
}

// ---------------- kernel 3r: reduce partials -> kptv bf16 ------------------------
__global__ __launch_bounds__(256) void k3r_reduce(const float* __restrict__ part, ushort* __restrict__ kptv_bf)
{
    int e = blockIdx.x*256 + threadIdx.x;
    float s = 0.f;
    #pragma unroll 8
    for (int kc = 0; kc < 64; kc++) s += part[(size_t)kc*131072 + e];
    kptv_bf[e] = f2bf(s);
}

// ---------------- kernel 4 v4: 32 tok/block, vfrag prefetch, padded out staging --
template<int K>
__device__ __forceinline__ void gemm32(const ushort* A_s, const ushort* __restrict__ B,
                                       f32x4 acc[2][4], int l15, int l4, int wid)
{
    __builtin_amdgcn_s_setprio(1);
    #pragma unroll
    for (int kc = 0; kc < (K >> 5); kc++) {
        const int ch = ((kc*4 + l4) ^ (l15 & 7)) << 3;
        bf16x8 a0 = *(const bf16x8*)&A_s[ l15      *256 + ch];
        bf16x8 a1 = *(const bf16x8*)&A_s[(16 + l15)*256 + ch];
        #pragma unroll
        for (int nt = 0; nt < 4; nt++) {
            bf16x8 bb = *(const bf16x8*)&B[(wid*64 + nt*16 + l15)*K + kc*32 + l4*8];
            acc[0][nt] = __builtin_amdgcn_mfma_f32_16x16x32_bf16(a0, bb, acc[0][nt], 0, 0, 0);
            acc[1][nt] = __builtin_amdgcn_mfma_f32_16x16x32_bf16(a1, bb, acc[1][nt], 0, 0, 0);
        }
    }
    __builtin_amdgcn_s_setprio(0);
}

__global__ __launch_bounds__(256, 4) void k4_attn_tail(
    const ushort* __restrict__ qp, const ushort* __restrict__ vfrag,
    const float* __restrict__ ksum, const ushort* __restrict__ kptv_bf,
    const ushort* __restrict__ wT,
    const float* __restrict__ b_proj,
    const float* __restrict__ g2, const float* __restrict__ b2,
    const float* __restrict__ b_mlp1, const float* __restrict__ b_mlp2,
    float* __restrict__ img2)
{
    __shared__ __align__(16) ushort A_s[16448];    // 32.9 KB: bf16 [32][256] GEMM A / f32 [32][257] out-staging
    __shared__ float D_s[32];
    __shared__ float redD[32][8];
    __shared__ float red1[4][32], red2[4][32];
    __shared__ float mu_s[32], iv_s[32];

    const int blk = blockIdx.x;                    // 2048
    const int b  = blk >> 9;
    const int t0 = (blk & 511) << 5;               // 32 tokens/block
    const int tid = threadIdx.x;
    const int wid = tid >> 6;
    const int lane = tid & 63;
    const int l15 = lane & 15, l4 = lane >> 4;

    // ---- prefetch: v residual fragments (64B/thread) + b_proj (T14 issue-early) ----
    u16x8 vreg[4];
    {
        const ushort* vf = vfrag + (size_t)blk*8192 + tid*32;
        #pragma unroll
        for (int i = 0; i < 4; i++) vreg[i] = *(const u16x8*)&vf[i*8];
    }
    float bp[4];
    #pragma unroll
    for (int nt = 0; nt < 4; nt++) bp[nt] = b_proj[wid*64 + nt*16 + l15];

    // ---- stage qp (bf16 swizzled copy) + D = qp . ksum ----
    {
        int tk = tid >> 3, seg = tid & 7;          // 32 rows x 8 segs of 16 cols
        const ushort* qrow = qp + (size_t)(b*TOK + t0 + tk)*MF + seg*16;
        u16x8 q0 = *(const u16x8*)&qrow[0];
        u16x8 q1 = *(const u16x8*)&qrow[8];
        const float* ks = ksum + b*MF + seg*16;
        float dd = 0.f;
        #pragma unroll
        for (int j = 0; j < 8; j++) {
            dd = fmaf(bf2f(q0[j]), ks[j],   dd);
            dd = fmaf(bf2f(q1[j]), ks[j+8], dd);
        }
        redD[tk][seg] = dd;
        int xr = tk & 7;
        *(u16x8*)&A_s[tk*256 + (((seg*2  ) ^ xr) << 3)] = q0;
        *(u16x8*)&A_s[tk*256 + (((seg*2+1) ^ xr) << 3)] = q1;
    }
    __syncthreads();
    if (tid < 32) {
        float s = 0.f;
        #pragma unroll
        for (int j = 0; j < 8; j++) s += redD[tid][j];
        D_s[tid] = s + 1e-8f;
    }

    f32x4 acc[2][4];
    #define ZACC() { _Pragma("unroll") for (int m_=0;m_<2;m_++) _Pragma("unroll") for (int n_=0;n_<4;n_++) { acc[m_][n_][0]=0.f;acc[m_][n_][1]=0.f;acc[m_][n_][2]=0.f;acc[m_][n_][3]=0.f; } }

    // ---- GEMM1: y_att = qp @ kptv^T, /D ----
    ZACC();
    gemm32<MF>(A_s, kptv_bf + (size_t)b*EMB*MF, acc, l15, l4, wid);
    __syncthreads();                               // qp reads done; D_s visible
    #pragma unroll
    for (int m = 0; m < 2; m++)
        #pragma unroll
        for (int nt = 0; nt < 4; nt++) {
            int col = wid*64 + nt*16 + l15;
            #pragma unroll
            for (int r = 0; r < 4; r++) {
                int row = m*16 + l4*4 + r;
                A_s[SWZ256(row, col)] = f2bf(acc[m][nt][r] / D_s[row]);
            }
        }
    __syncthreads();

    // ---- GEMM2: y2 = v + y_att @ w_proj + b_proj (y2 -> 32 f32 regs) ----
    ZACC();
    gemm32<EMB>(A_s, wT, acc, l15, l4, wid);
    float y2[2][4][4];
    #pragma unroll
    for (int nt = 0; nt < 4; nt++) {
        #pragma unroll
        for (int m = 0; m < 2; m++)
            #pragma unroll
            for (int r = 0; r < 4; r++) {
                int idx = m*16 + nt*4 + r;
                y2[m][nt][r] = acc[m][nt][r] + bp[nt] + bf2f(vreg[idx >> 3][idx & 7]);
            }
    }

    // ---- LayerNorm(y2): shfl over l15 + cross-wave LDS ----
    {
        #pragma unroll
        for (int m = 0; m < 2; m++)
            #pragma unroll
            for (int r = 0; r < 4; r++) {
                float s1 = 0.f, s2 = 0.f;
                #pragma unroll
                for (int nt = 0; nt < 4; nt++) {
                    float a = y2[m][nt][r];
                    s1 += a; s2 = fmaf(a, a, s2);
                }
                #pragma unroll
                for (int msk = 8; msk >= 1; msk >>= 1) {
                    s1 += __shfl_xor(s1, msk);
                    s2 += __shfl_xor(s2, msk);
                }
                if (l15 == 0) {
                    int row = m*16 + l4*4 + r;
                    red1[wid][row] = s1; red2[wid][row] = s2;
                }
            }
        __syncthreads();
        if (tid < 32) {
            float a = red1[0][tid] + red1[1][tid] + red1[2][tid] + red1[3][tid];
            float q = red2[0][tid] + red2[1][tid] + red2[2][tid] + red2[3][tid];
            float mu = a * (1.f/EMB);
            mu_s[tid] = mu;
            iv_s[tid] = rsqrtf(q*(1.f/EMB) - mu*mu + 1e-5f);
        }
        __syncthreads();
        #pragma unroll
        for (int nt = 0; nt < 4; nt++) {
            int col = wid*64 + nt*16 + l15;
            float gg = g2[col], bb = b2[col];
            #pragma unroll
            for (int m = 0; m < 2; m++)
                #pragma unroll
                for (int r = 0; r < 4; r++) {
                    int row = m*16 + l4*4 + r;
                    A_s[SWZ256(row, col)] = f2bf((y2[m][nt][r] - mu_s[row])*iv_s[row]*gg + bb);
                }
        }
    }
    __syncthreads();

    // ---- GEMM3: h1 = gelu(z @ w_mlp1 + b_mlp1) ----
    ZACC();
    gemm32<EMB>(A_s, wT + 65536, acc, l15, l4, wid);
    __syncthreads();                               // z reads done
    #pragma unroll
    for (int nt = 0; nt < 4; nt++) {
        int col = wid*64 + nt*16 + l15;
        float bm = b_mlp1[col];
        #pragma unroll
        for (int m = 0; m < 2; m++)
            #pragma unroll
            for (int r = 0; r < 4; r++) {
                int row = m*16 + l4*4 + r;
                float a = acc[m][nt][r] + bm;
                A_s[SWZ256(row, col)] = f2bf(0.5f*a*(1.f + erff(a*0.70710678118654752f)));
            }
    }
    __syncthreads();

    // ---- GEMM4: y3 = y2 + h1 @ w_mlp2 + b_mlp2 ----
    ZACC();
    gemm32<EMB>(A_s, wT + 131072, acc, l15, l4, wid);
    #pragma unroll
    for (int nt = 0; nt < 4; nt++) {
        int col = wid*64 + nt*16 + l15;
        float bm = b_mlp2[col];
        #pragma unroll
        for (int m = 0; m < 2; m++)
            #pragma unroll
            for (int r = 0; r < 4; r++)
                y2[m][nt][r] += acc[m][nt][r] + bm;   // y2 now holds y3
    }
    __syncthreads();                                  // h1 reads done; A_s reusable

    // ---- output: stage f32 [32][257] (pad kills bank conflicts), coalesced write --
    float* A_f = (float*)A_s;                        // [32][257] f32
    #pragma unroll
    for (int nt = 0; nt < 4; nt++) {
        int col = wid*64 + nt*16 + l15;
        #pragma unroll
        for (int m = 0; m < 2; m++)
            #pragma unroll
            for (int r = 0; r < 4; r++)
                A_f[(m*16 + l4*4 + r)*257 + col] = y2[m][nt][r];
    }
    __syncthreads();
    {
        // thread -> (c = pass*32 + tid>>3, t = (tid&7)*4): 8 lanes give 128B-contiguous t
        int tq = tid & 7, cb = tid >> 3;
        #pragma unroll
        for (int pass = 0; pass < 8; pass++) {
            int c = pass*32 + cb;
            f32x4 pk;
            #pragma unroll
            for (int j = 0; j < 4; j++) pk[j] = A_f[(tq*4 + j)*257 + c];
            *(f32x4*)&img2[((size_t)(b*EMB + c))*TOK + t0 + tq*4] = pk;
        }
    }
}

// ---------------- kernel 6: bilinear upsample x2, align_corners=True -------------
__global__ __launch_bounds__(256) void k6_upsample(const float* __restrict__ img2, float* __restrict__ out)
{
    int idx = blockIdx.x*256 + threadIdx.x;
    int wo = idx & 255;
    int ho = (idx >> 8) & 255;
    int c  = (idx >> 16) & 255;
    int b  = idx >> 24;
    const float sc = 127.f/255.f;
    float fh = ho * sc; int h0 = (int)fh; if (h0 > 126) h0 = 126; float th = fh - h0;
    float fw = wo * sc; int w0 = (int)fw; if (w0 > 126) w0 = 126; float tw = fw - w0;
    const float* p = img2 + (((size_t)b*EMB + c)*128 + h0)*128 + w0;
    float a00 = p[0], a01 = p[1], a10 = p[128], a11 = p[129];
    float top = fmaf(a01 - a00, tw, a00);
    float bot = fmaf(a11 - a10, tw, a10);
    out[idx] = fmaf(bot - top, th, top);
}

extern "C" void kernel_launch(void* const* d_in, const int* in_sizes, int n_in,
                              void* d_out, int out_size, void* d_ws, size_t ws_size,
                              hipStream_t stream)
{
    const float* x      = (const float*)d_in[0];
    const float* g1     = (const float*)d_in[1];
    const float* b1     = (const float*)d_in[2];
    const float* w_kqv  = (const float*)d_in[3];
    const float* b_kqv  = (const float*)d_in[4];
    const float* w_prm  = (const float*)d_in[5];
    const float* w_proj = (const float*)d_in[6];
    const float* b_proj = (const float*)d_in[7];
    const float* g2     = (const float*)d_in[8];
    const float* b2     = (const float*)d_in[9];
    const float* w_mlp1 = (const float*)d_in[10];
    const float* b_mlp1 = (const float*)d_in[11];
    const float* w_mlp2 = (const float*)d_in[12];
    const float* b_mlp2 = (const float*)d_in[13];
    float* out = (float*)d_out;
    float* ws  = (float*)d_ws;

    ushort* vfrag   = (ushort*)(ws);               // 16,777,216 ushorts (8,388,608 slots)
    ushort* qp_bf   = (ushort*)(ws + 8388608);     //  8,388,608 ushorts
    ushort* vT_bf   = (ushort*)(ws + 12582912);    // 16,777,216 ushorts
    ushort* kpT_bf  = (ushort*)(ws + 20971520);    //  8,388,608 ushorts
    float*  img2    = ws + 12582912;               // overlays vT+kpT (dead after k3)
    float*  ksum    = ws + 29360128;
    ushort* wkqvT   = (ushort*)(ws + 29360640);
    ushort* wprm_bf = (ushort*)(ws + 29385216);
    ushort* wT3     = (ushort*)(ws + 29401600);
    ushort* kptv_bf = (ushort*)(ws + 29499904);
    float*  part    = ws + 29532672;

    hipLaunchKernelGGL(kprep, dim3(1664), dim3(256), 0, stream,
                       w_kqv, w_prm, w_proj, w_mlp1, w_mlp2, wkqvT, wprm_bf, wT3);
    hipLaunchKernelGGL(k1_mfma, dim3(2048), dim3(256), 0, stream,
                       x, g1, b1, wkqvT, b_kqv, wprm_bf, vfrag, vT_bf, kpT_bf, qp_bf);
    hipLaunchKernelGGL(k2_ksum, dim3(512), dim3(256), 0, stream, kpT_bf, ksum);
    hipLaunchKernelGGL(k3_kptv_mfma, dim3(512), dim3(256), 0, stream, vT_bf, kpT_bf, part);
    hipLaunchKernelGGL(k3r_reduce, dim3(512), dim3(256), 0, stream, part, kptv_bf);
    hipLaunchKernelGGL(k4_attn_tail, dim3(2048), dim3(256), 0, stream,
                       qp_bf, vfrag, ksum, kptv_bf, wT3, b_proj, g2, b2,
                       b_mlp1, b_mlp2, img2);
    hipLaunchKernelGGL(k6_upsample, dim3(262144), dim3(256), 0, stream, img2, out);
}

// Round 7
// 327.368 us; speedup vs baseline: 4.7572x; 1.2348x over previous
//
#include <hip/hip_runtime.h>
#include <math.h>

#define TOK   16384
#define DIM   48
#define EMB   256
#define MF    128
#define IMGsz 129

typedef __attribute__((ext_vector_type(8))) short    bf16x8;
typedef __attribute__((ext_vector_type(8))) unsigned short u16x8;
typedef __attribute__((ext_vector_type(4))) float    f32x4;

__device__ __forceinline__ ushort f2bf(float f) {
    union { float f; unsigned u; } v; v.f = f;
    unsigned u = v.u;
    return (ushort)((u + 0x7fffu + ((u >> 16) & 1u)) >> 16);   // RNE
}
__device__ __forceinline__ float bf2f(ushort h) {
    union { unsigned u; float f; } v; v.u = ((unsigned)h) << 16; return v.f;
}

// swizzles: XOR 16B-chunk index with (row&7) -> conflict-free ds_read_b128
#define SWZ512(r,c) ((r)*512 + (((((c)>>3) ^ ((r)&7))) << 3) + ((c)&7))
#define SWZ64(r,c)  ((r)*64  + (((((c)>>3) ^ ((r)&7)) & 7) << 3) + ((c)&7))
#define SWZ256(r,c) ((r)*256 + (((((c)>>3) ^ ((r)&7))) << 3) + ((c)&7))

// fragment-major dst index for B operands: lane(l4,l15) of (ntile,kc) is contiguous.
// elem (n,k): dst = ((ntile*KC + kc)*4 + l4)*128 + nl*8 + j
__device__ __forceinline__ int fragmajor(int n, int k, int KC) {
    return (((n >> 4)*KC + (k >> 5))*4 + ((k >> 3) & 3))*128 + (n & 15)*8 + (k & 7);
}

// ---------------- kprep: bf16 weight staging (fragment-major) --------------------
__global__ __launch_bounds__(256) void kprep(
    const float* __restrict__ w_kqv, const float* __restrict__ w_prm,
    const float* __restrict__ w_proj, const float* __restrict__ w_mlp1,
    const float* __restrict__ w_mlp2,
    ushort* __restrict__ wkqvT, ushort* __restrict__ wprm_bf, ushort* __restrict__ wT3)
{
    int blk = blockIdx.x, tid = threadIdx.x;
    if (blk < 768) {
        if (tid < 64) {   // col=blk (n, 0..767), k=tid (0..63), K=64 -> KC=2
            float v = (tid < DIM) ? w_kqv[tid*768 + blk] : 0.f;
            wkqvT[fragmajor(blk, tid, 2)] = f2bf(v);
        }
    } else if (blk < 896) {   // m=blk-768 (0..127), k=tid, K=256 -> KC=8
        int m = blk - 768;
        wprm_bf[fragmajor(m, tid, 8)] = f2bf(w_prm[m*256 + tid]);
    } else {                  // n=q&255, k=tid, K=256 -> KC=8
        int q = blk - 896;
        int w = q >> 8, n = q & 255;
        const float* src = (w == 0) ? w_proj : ((w == 1) ? w_mlp1 : w_mlp2);
        wT3[w*65536 + fragmajor(n, tid, 8)] = f2bf(src[tid*256 + n]);
    }
}

// ---------------- kernel 1: unfold+LN+kqv+prm via MFMA (32 tokens/block) ---------
__global__ __launch_bounds__(256, 2) void k1_mfma(
    const float* __restrict__ x, const float* __restrict__ g1, const float* __restrict__ b1,
    const ushort* __restrict__ wkqvT, const float* __restrict__ b_kqv,
    const ushort* __restrict__ wprm_bf,
    ushort* __restrict__ vfrag_out, ushort* __restrict__ vT_out,
    ushort* __restrict__ kpT_out, ushort* __restrict__ qp_out)
{
    __shared__ __align__(16) ushort kq_bf[32*512];
    __shared__ __align__(16) ushort vt_bf[32*256];
    __shared__ float xdp[4][32][2];
    __shared__ float xd2[32][2];
    __shared__ float red1[32][8], red2[32][8];
    __shared__ float mu_s[32], iv_s[32];

    float*  t_s  = (float*)kq_bf;
    ushort* h_bf = vt_bf;

    const int blk = blockIdx.x;                    // 2048
    const int b  = blk >> 9;
    const int t0 = (blk & 511) << 5;
    const int tid = threadIdx.x;
    const int wid = tid >> 6;
    const int l15 = tid & 15, l4 = (tid >> 4) & 3;

    for (int e = tid; e < 32*DIM; e += 256) {
        int tok = e / DIM, j = e - tok*DIM;
        int t = t0 + tok;
        int lh = t >> 7, lw = t & 127;
        int c = j >> 4, kh = (j >> 2) & 3, kw = j & 3;
        int ih = lh + kh - 1, iw = lw + kw - 1;
        float val = 0.f;
        if (ih >= 0 && ih < IMGsz && iw >= 0 && iw < IMGsz)
            val = x[((b*3 + c)*IMGsz + ih)*IMGsz + iw];
        t_s[tok*DIM + j] = val;
    }
    __syncthreads();

    {
        int tg = tid >> 3, sl = tid & 7;
        const float* tr = &t_s[tg*DIM + sl*6];
        float s1 = 0.f, s2 = 0.f;
        #pragma unroll
        for (int j = 0; j < 6; j++) { float a = tr[j]; s1 += a; s2 = fmaf(a, a, s2); }
        red1[tg][sl] = s1; red2[tg][sl] = s2;
        __syncthreads();
        if (tid < 32) {
            float a = 0.f, q = 0.f;
            #pragma unroll
            for (int j = 0; j < 8; j++) { a += red1[tid][j]; q += red2[tid][j]; }
            float mu = a * (1.f/DIM);
            mu_s[tid] = mu;
            iv_s[tid] = rsqrtf(q*(1.f/DIM) - mu*mu + 1e-5f);
        }
        __syncthreads();
        float mu = mu_s[tg], iv = iv_s[tg];
        #pragma unroll
        for (int j = 0; j < 6; j++) {
            int c = sl*6 + j;
            h_bf[SWZ64(tg, c)] = f2bf((tr[j]-mu)*iv*g1[c] + b1[c]);
        }
        h_bf[SWZ64(tg, 48 + sl*2    )] = 0;
        h_bf[SWZ64(tg, 48 + sl*2 + 1)] = 0;
    }
    __syncthreads();

    f32x4 acc[2][12];
    #pragma unroll
    for (int m = 0; m < 2; m++)
        #pragma unroll
        for (int j = 0; j < 12; j++) { acc[m][j][0]=0.f; acc[m][j][1]=0.f; acc[m][j][2]=0.f; acc[m][j][3]=0.f; }
    #pragma unroll
    for (int kc = 0; kc < 2; kc++) {
        int ch = ((kc*4 + l4) ^ (l15 & 7)) << 3;
        bf16x8 a0 = *(const bf16x8*)&h_bf[ l15      *64 + ch];
        bf16x8 a1 = *(const bf16x8*)&h_bf[(16 + l15)*64 + ch];
        #pragma unroll
        for (int j = 0; j < 12; j++) {
            int ntile = wid + 4*j;
            bf16x8 bb = *(const bf16x8*)&wkqvT[(((ntile*2 + kc)*4 + l4)*16 + l15)*8];
            acc[0][j] = __builtin_amdgcn_mfma_f32_16x16x32_bf16(a0, bb, acc[0][j], 0, 0, 0);
            acc[1][j] = __builtin_amdgcn_mfma_f32_16x16x32_bf16(a1, bb, acc[1][j], 0, 0, 0);
        }
    }
    __syncthreads();

    {
        float pk[2][4], pq[2][4];
        #pragma unroll
        for (int m = 0; m < 2; m++)
            #pragma unroll
            for (int r = 0; r < 4; r++) { pk[m][r] = 0.f; pq[m][r] = 0.f; }
        #pragma unroll
        for (int j = 0; j < 12; j++) {
            int col = (wid + 4*j)*16 + l15;
            float bias = b_kqv[col];
            #pragma unroll
            for (int m = 0; m < 2; m++)
                #pragma unroll
                for (int r = 0; r < 4; r++) {
                    int row = m*16 + l4*4 + r;
                    float a = acc[m][j][r] + bias;
                    if (j < 4) {
                        pk[m][r] = fmaf(a, a, pk[m][r]);
                        kq_bf[SWZ512(row, col)] = f2bf(a);
                    } else if (j < 8) {
                        pq[m][r] = fmaf(a, a, pq[m][r]);
                        kq_bf[SWZ512(row, col)] = f2bf(a);
                    } else {
                        int n = col - 512;
                        vt_bf[row*256 + n] = f2bf(a);
                    }
                }
        }
        #pragma unroll
        for (int m = 0; m < 2; m++)
            #pragma unroll
            for (int r = 0; r < 4; r++) {
                float a = pk[m][r], q = pq[m][r];
                #pragma unroll
                for (int msk = 8; msk >= 1; msk >>= 1) {
                    a += __shfl_xor(a, msk);
                    q += __shfl_xor(q, msk);
                }
                if (l15 == 0) {
                    int row = m*16 + l4*4 + r;
                    xdp[wid][row][0] = a; xdp[wid][row][1] = q;
                }
            }
    }
    __syncthreads();
    if (tid < 64) {
        int row = tid >> 1, ty = tid & 1;
        xd2[row][ty] = 0.5f*(xdp[0][row][ty] + xdp[1][row][ty] + xdp[2][row][ty] + xdp[3][row][ty]);
    }

    // ---- P4: v^T coalesced write (thread = n channel) ----
    {
        ushort* dst = vT_out + ((size_t)(b*EMB + tid))*TOK + t0;
        #pragma unroll
        for (int t8 = 0; t8 < 4; t8++) {
            u16x8 pk8;
            #pragma unroll
            for (int j = 0; j < 8; j++) pk8[j] = vt_bf[(t8*8 + j)*256 + tid];
            *(u16x8*)&dst[t8*8] = pk8;
        }
    }
    // ---- P4b: v fragment-major write (k4 residual layout) ----
    {
        u16x8 pk8[4];
        #pragma unroll
        for (int m = 0; m < 2; m++)
            #pragma unroll
            for (int nt = 0; nt < 4; nt++)
                #pragma unroll
                for (int r = 0; r < 4; r++) {
                    int row = m*16 + l4*4 + r;
                    int col = wid*64 + nt*16 + l15;
                    int idx = m*16 + nt*4 + r;
                    pk8[idx >> 3][idx & 7] = vt_bf[row*256 + col];
                }
        ushort* dst = vfrag_out + (size_t)blk*8192 + tid*32;
        #pragma unroll
        for (int i = 0; i < 4; i++) *(u16x8*)&dst[i*8] = pk8[i];
    }
    __syncthreads();

    f32x4 acc2[2][4];
    #pragma unroll
    for (int m = 0; m < 2; m++)
        #pragma unroll
        for (int n = 0; n < 4; n++) { acc2[m][n][0]=0.f; acc2[m][n][1]=0.f; acc2[m][n][2]=0.f; acc2[m][n][3]=0.f; }
    {
        const int cbase = (wid >= 2) ? 32 : 0;
        #pragma unroll
        for (int kc = 0; kc < 8; kc++) {
            int chunk = cbase + kc*4 + l4;
            int ch = (chunk ^ (l15 & 7)) << 3;
            bf16x8 a0 = *(const bf16x8*)&kq_bf[ l15      *512 + ch];
            bf16x8 a1 = *(const bf16x8*)&kq_bf[(16 + l15)*512 + ch];
            #pragma unroll
            for (int nt = 0; nt < 4; nt++) {
                int mtile = (wid & 1)*4 + nt;
                bf16x8 bb = *(const bf16x8*)&wprm_bf[(((mtile*8 + kc)*4 + l4)*16 + l15)*8];
                acc2[0][nt] = __builtin_amdgcn_mfma_f32_16x16x32_bf16(a0, bb, acc2[0][nt], 0, 0, 0);
                acc2[1][nt] = __builtin_amdgcn_mfma_f32_16x16x32_bf16(a1, bb, acc2[1][nt], 0, 0, 0);
            }
        }
    }

    {
        const float scale = 0.08838834764831845f;
        const bool isK = (wid < 2);
        #pragma unroll
        for (int m = 0; m < 2; m++)
            #pragma unroll
            for (int nt = 0; nt < 4; nt++) {
                #pragma unroll
                for (int r = 0; r < 4; r++) {
                    int row = m*16 + l4*4 + r;
                    int mcol = (wid & 1)*64 + nt*16 + l15;
                    float e = expf(acc2[m][nt][r] - xd2[row][isK ? 0 : 1]) * scale;
                    ushort bf = f2bf(e);
                    if (isK) vt_bf[row*256 + mcol] = bf;
                    else qp_out[(size_t)(b*TOK + t0 + row)*MF + mcol] = bf;
                }
            }
    }
    __syncthreads();

    if (tid < 128) {
        ushort* dst = kpT_out + ((size_t)(b*MF + tid))*TOK + t0;
        #pragma unroll
        for (int t8 = 0; t8 < 4; t8++) {
            u16x8 pk8;
            #pragma unroll
            for (int j = 0; j < 8; j++) pk8[j] = vt_bf[(t8*8 + j)*256 + tid];
            *(u16x8*)&dst[t8*8] = pk8;
        }
    }
}

// ---------------- kernel 2: ksum[b][m] = row-sum of kp^T ------------------------
__global__ __launch_bounds__(256) void k2_ksum(const ushort* __restrict__ kpT, float* __restrict__ ksum)
{
    __shared__ float red[4];
    int blk = blockIdx.x;
    int b = blk >> 7, m = blk & 127;
    int tid = threadIdx.x;
    const ushort* row = kpT + (size_t)(b*MF + m)*TOK;
    float s = 0.f;
    for (int i = tid; i < TOK/8; i += 256) {
        u16x8 v = *(const u16x8*)&row[i*8];
        #pragma unroll
        for (int j = 0; j < 8; j++) s += bf2f(v[j]);
    }
    #pragma unroll
    for (int msk = 32; msk >= 1; msk >>= 1) s += __shfl_xor(s, msk);
    if ((tid & 63) == 0) red[tid >> 6] = s;
    __syncthreads();
    if (tid == 0) ksum[b*MF + m] = red[0] + red[1] + red[2] + red[3];
}

// ---------------- kernel 3: kptv partials via MFMA -------------------------------
__global__ __launch_bounds__(256) void k3_kptv_mfma(
    const ushort* __restrict__ vT, const ushort* __restrict__ kpT, float* __restrict__ part)
{
    int blk = blockIdx.x;            // 512: b(2b) | ns(1b) | kc(6b)
    int b = blk >> 7, ns = (blk >> 6) & 1, kc = blk & 63;
    const int tid = threadIdx.x;
    const int wid = tid >> 6;
    const int l15 = tid & 15, l4 = (tid >> 4) & 3;
    const int t0 = kc * 256;
    const int n0 = ns*128 + wid*32;

    f32x4 acc[2][8];
    #pragma unroll
    for (int m = 0; m < 2; m++)
        #pragma unroll
        for (int n = 0; n < 8; n++) { acc[m][n][0]=0.f; acc[m][n][1]=0.f; acc[m][n][2]=0.f; acc[m][n][3]=0.f; }

    #pragma unroll
    for (int ks = 0; ks < 8; ks++) {
        int k0 = t0 + ks*32 + l4*8;
        bf16x8 a0 = *(const bf16x8*)&vT[((size_t)(b*EMB + n0      + l15))*TOK + k0];
        bf16x8 a1 = *(const bf16x8*)&vT[((size_t)(b*EMB + n0 + 16 + l15))*TOK + k0];
        #pragma unroll
        for (int nt = 0; nt < 8; nt++) {
            bf16x8 bb = *(const bf16x8*)&kpT[((size_t)(b*MF + nt*16 + l15))*TOK + k0];
            acc[0][nt] = __builtin_amdgcn_mfma_f32_16x16x32_bf16(a0, bb, acc[0][nt], 0, 0, 0);
            acc[1][nt] = __builtin_amdgcn_mfma_f32_16x16x32_bf16(a1, bb, acc[1][nt], 0, 0, 0);
        }
    }
    #pragma unroll
    for (int mt = 0; mt < 2; mt++)
        #pragma unroll
        for (int nt = 0; nt < 8; nt++) {
            int n = n0 + mt*16 + l4*4;
            int m = nt*16 + l15;
            #pragma unroll
            for (int r = 0; r < 4; r++)
                part[(size_t)kc*131072 + (size_t)((b*EMB + n + r)*MF + m)] = acc[mt][nt][r];
        }
}

// ---------------- kernel 3r: reduce partials -> kptv bf16 (fragment-major) -------
__global__ __launch_bounds__(256) void k3r_reduce(const float* __restrict__ part, ushort* __restrict__ kptv_bf)
{
    int e = blockIdx.x*256 + threadIdx.x;   // 131072 = 4b x 256n x 128m
    float s = 0.f;
    #pragma unroll 8
    for (int kc = 0; kc < 64; kc++) s += part[(size_t)kc*131072 + e];
    int b = e >> 15, n = (e >> 7) & 255, m = e & 127;
    kptv_bf[b*32768 + fragmajor(n, m, 4)] = f2bf(s);
}

// ---------------- kernel 4 v5: fragment-major B loads (1KB/instr coalesced) ------
template<int K>
__device__ __forceinline__ void gemm32(const ushort* A_s, const ushort* __restrict__ B,
                                       f32x4 acc[2][4], int l15, int l4, int wid)
{
    __builtin_amdgcn_s_setprio(1);
    #pragma unroll
    for (int kc = 0; kc < (K >> 5); kc++) {
        const int ch = ((kc*4 + l4) ^ (l15 & 7)) << 3;
        bf16x8 a0 = *(const bf16x8*)&A_s[ l15      *256 + ch];
        bf16x8 a1 = *(const bf16x8*)&A_s[(16 + l15)*256 + ch];
        #pragma unroll
        for (int nt = 0; nt < 4; nt++) {
            int ntile = wid*4 + nt;
            bf16x8 bb = *(const bf16x8*)&B[(((ntile*(K >> 5) + kc)*4 + l4)*16 + l15)*8];
            acc[0][nt] = __builtin_amdgcn_mfma_f32_16x16x32_bf16(a0, bb, acc[0][nt], 0, 0, 0);
            acc[1][nt] = __builtin_amdgcn_mfma_f32_16x16x32_bf16(a1, bb, acc[1][nt], 0, 0, 0);
        }
    }
    __builtin_amdgcn_s_setprio(0);
}

__global__ __launch_bounds__(256, 4) void k4_attn_tail(
    const ushort* __restrict__ qp, const ushort* __restrict__ vfrag,
    const float* __restrict__ ksum, const ushort* __restrict__ kptv_bf,
    const ushort* __restrict__ wT,
    const float* __restrict__ b_proj,
    const float* __restrict__ g2, const float* __restrict__ b2,
    const float* __restrict__ b_mlp1, const float* __restrict__ b_mlp2,
    float* __restrict__ img2)
{
    __shared__ __align__(16) ushort A_s[16448];    // 32.9 KB
    __shared__ float D_s[32];
    __shared__ float redD[32][8];
    __shared__ float red1[4][32], red2[4][32];
    __shared__ float mu_s[32], iv_s[32];

    const int blk = blockIdx.x;                    // 2048
    const int b  = blk >> 9;
    const int t0 = (blk & 511) << 5;               // 32 tokens/block
    const int tid = threadIdx.x;
    const int wid = tid >> 6;
    const int lane = tid & 63;
    const int l15 = lane & 15, l4 = lane >> 4;

    // ---- prefetch: v residual fragments + b_proj ----
    u16x8 vreg[4];
    {
        const ushort* vf = vfrag + (size_t)blk*8192 + tid*32;
        #pragma unroll
        for (int i = 0; i < 4; i++) vreg[i] = *(const u16x8*)&vf[i*8];
    }
    float bp[4];
    #pragma unroll
    for (int nt = 0; nt < 4; nt++) bp[nt] = b_proj[wid*64 + nt*16 + l15];

    // ---- stage qp (bf16 swizzled copy) + D = qp . ksum ----
    {
        int tk = tid >> 3, seg = tid & 7;
        const ushort* qrow = qp + (size_t)(b*TOK + t0 + tk)*MF + seg*16;
        u16x8 q0 = *(const u16x8*)&qrow[0];
        u16x8 q1 = *(const u16x8*)&qrow[8];
        const float* ks = ksum + b*MF + seg*16;
        float dd = 0.f;
        #pragma unroll
        for (int j = 0; j < 8; j++) {
            dd = fmaf(bf2f(q0[j]), ks[j],   dd);
            dd = fmaf(bf2f(q1[j]), ks[j+8], dd);
        }
        redD[tk][seg] = dd;
        int xr = tk & 7;
        *(u16x8*)&A_s[tk*256 + (((seg*2  ) ^ xr) << 3)] = q0;
        *(u16x8*)&A_s[tk*256 + (((seg*2+1) ^ xr) << 3)] = q1;
    }
    __syncthreads();
    if (tid < 32) {
        float s = 0.f;
        #pragma unroll
        for (int j = 0; j < 8; j++) s += redD[tid][j];
        D_s[tid] = s + 1e-8f;
    }

    f32x4 acc[2][4];
    #define ZACC() { _Pragma("unroll") for (int m_=0;m_<2;m_++) _Pragma("unroll") for (int n_=0;n_<4;n_++) { acc[m_][n_][0]=0.f;acc[m_][n_][1]=0.f;acc[m_][n_][2]=0.f;acc[m_][n_][3]=0.f; } }

    // ---- GEMM1: y_att = qp @ kptv^T, /D ----
    ZACC();
    gemm32<MF>(A_s, kptv_bf + (size_t)b*32768, acc, l15, l4, wid);
    __syncthreads();
    #pragma unroll
    for (int m = 0; m < 2; m++)
        #pragma unroll
        for (int nt = 0; nt < 4; nt++) {
            int col = wid*64 + nt*16 + l15;
            #pragma unroll
            for (int r = 0; r < 4; r++) {
                int row = m*16 + l4*4 + r;
                A_s[SWZ256(row, col)] = f2bf(acc[m][nt][r] / D_s[row]);
            }
        }
    __syncthreads();

    // ---- GEMM2: y2 = v + y_att @ w_proj + b_proj ----
    ZACC();
    gemm32<EMB>(A_s, wT, acc, l15, l4, wid);
    float y2[2][4][4];
    #pragma unroll
    for (int nt = 0; nt < 4; nt++) {
        #pragma unroll
        for (int m = 0; m < 2; m++)
            #pragma unroll
            for (int r = 0; r < 4; r++) {
                int idx = m*16 + nt*4 + r;
                y2[m][nt][r] = acc[m][nt][r] + bp[nt] + bf2f(vreg[idx >> 3][idx & 7]);
            }
    }

    // ---- LayerNorm(y2): shfl over l15 + cross-wave LDS ----
    {
        #pragma unroll
        for (int m = 0; m < 2; m++)
            #pragma unroll
            for (int r = 0; r < 4; r++) {
                float s1 = 0.f, s2 = 0.f;
                #pragma unroll
                for (int nt = 0; nt < 4; nt++) {
                    float a = y2[m][nt][r];
                    s1 += a; s2 = fmaf(a, a, s2);
                }
                #pragma unroll
                for (int msk = 8; msk >= 1; msk >>= 1) {
                    s1 += __shfl_xor(s1, msk);
                    s2 += __shfl_xor(s2, msk);
                }
                if (l15 == 0) {
                    int row = m*16 + l4*4 + r;
                    red1[wid][row] = s1; red2[wid][row] = s2;
                }
            }
        __syncthreads();
        if (tid < 32) {
            float a = red1[0][tid] + red1[1][tid] + red1[2][tid] + red1[3][tid];
            float q = red2[0][tid] + red2[1][tid] + red2[2][tid] + red2[3][tid];
            float mu = a * (1.f/EMB);
            mu_s[tid] = mu;
            iv_s[tid] = rsqrtf(q*(1.f/EMB) - mu*mu + 1e-5f);
        }
        __syncthreads();
        #pragma unroll
        for (int nt = 0; nt < 4; nt++) {
            int col = wid*64 + nt*16 + l15;
            float gg = g2[col], bb = b2[col];
            #pragma unroll
            for (int m = 0; m < 2; m++)
                #pragma unroll
                for (int r = 0; r < 4; r++) {
                    int row = m*16 + l4*4 + r;
                    A_s[SWZ256(row, col)] = f2bf((y2[m][nt][r] - mu_s[row])*iv_s[row]*gg + bb);
                }
        }
    }
    __syncthreads();

    // ---- GEMM3: h1 = gelu(z @ w_mlp1 + b_mlp1) ----
    ZACC();
    gemm32<EMB>(A_s, wT + 65536, acc, l15, l4, wid);
    __syncthreads();
    #pragma unroll
    for (int nt = 0; nt < 4; nt++) {
        int col = wid*64 + nt*16 + l15;
        float bm = b_mlp1[col];
        #pragma unroll
        for (int m = 0; m < 2; m++)
            #pragma unroll
            for (int r = 0; r < 4; r++) {
                int row = m*16 + l4*4 + r;
                float a = acc[m][nt][r] + bm;
                A_s[SWZ256(row, col)] = f2bf(0.5f*a*(1.f + erff(a*0.70710678118654752f)));
            }
    }
    __syncthreads();

    // ---- GEMM4: y3 = y2 + h1 @ w_mlp2 + b_mlp2 ----
    ZACC();
    gemm32<EMB>(A_s, wT + 131072, acc, l15, l4, wid);
    #pragma unroll
    for (int nt = 0; nt < 4; nt++) {
        int col = wid*64 + nt*16 + l15;
        float bm = b_mlp2[col];
        #pragma unroll
        for (int m = 0; m < 2; m++)
            #pragma unroll
            for (int r = 0; r < 4; r++)
                y2[m][nt][r] += acc[m][nt][r] + bm;
    }
    __syncthreads();

    // ---- output: stage f32 [32][257], coalesced channel-major write ----
    float* A_f = (float*)A_s;
    #pragma unroll
    for (int nt = 0; nt < 4; nt++) {
        int col = wid*64 + nt*16 + l15;
        #pragma unroll
        for (int m = 0; m < 2; m++)
            #pragma unroll
            for (int r = 0; r < 4; r++)
                A_f[(m*16 + l4*4 + r)*257 + col] = y2[m][nt][r];
    }
    __syncthreads();
    {
        int tq = tid & 7, cb = tid >> 3;
        #pragma unroll
        for (int pass = 0; pass < 8; pass++) {
            int c = pass*32 + cb;
            f32x4 pk;
            #pragma unroll
            for (int j = 0; j < 4; j++) pk[j] = A_f[(tq*4 + j)*257 + c];
            *(f32x4*)&img2[((size_t)(b*EMB + c))*TOK + t0 + tq*4] = pk;
        }
    }
}

// ---------------- kernel 6: bilinear upsample x2, align_corners=True -------------
__global__ __launch_bounds__(256) void k6_upsample(const float* __restrict__ img2, float* __restrict__ out)
{
    int idx = blockIdx.x*256 + threadIdx.x;
    int wo = idx & 255;
    int ho = (idx >> 8) & 255;
    int c  = (idx >> 16) & 255;
    int b  = idx >> 24;
    const float sc = 127.f/255.f;
    float fh = ho * sc; int h0 = (int)fh; if (h0 > 126) h0 = 126; float th = fh - h0;
    float fw = wo * sc; int w0 = (int)fw; if (w0 > 126) w0 = 126; float tw = fw - w0;
    const float* p = img2 + (((size_t)b*EMB + c)*128 + h0)*128 + w0;
    float a00 = p[0], a01 = p[1], a10 = p[128], a11 = p[129];
    float top = fmaf(a01 - a00, tw, a00);
    float bot = fmaf(a11 - a10, tw, a10);
    out[idx] = fmaf(bot - top, th, top);
}

extern "C" void kernel_launch(void* const* d_in, const int* in_sizes, int n_in,
                              void* d_out, int out_size, void* d_ws, size_t ws_size,
                              hipStream_t stream)
{
    const float* x      = (const float*)d_in[0];
    const float* g1     = (const float*)d_in[1];
    const float* b1     = (const float*)d_in[2];
    const float* w_kqv  = (const float*)d_in[3];
    const float* b_kqv  = (const float*)d_in[4];
    const float* w_prm  = (const float*)d_in[5];
    const float* w_proj = (const float*)d_in[6];
    const float* b_proj = (const float*)d_in[7];
    const float* g2     = (const float*)d_in[8];
    const float* b2     = (const float*)d_in[9];
    const float* w_mlp1 = (const float*)d_in[10];
    const float* b_mlp1 = (const float*)d_in[11];
    const float* w_mlp2 = (const float*)d_in[12];
    const float* b_mlp2 = (const float*)d_in[13];
    float* out = (float*)d_out;
    float* ws  = (float*)d_ws;

    ushort* vfrag   = (ushort*)(ws);
    ushort* qp_bf   = (ushort*)(ws + 8388608);
    ushort* vT_bf   = (ushort*)(ws + 12582912);
    ushort* kpT_bf  = (ushort*)(ws + 20971520);
    float*  img2    = ws + 12582912;
    float*  ksum    = ws + 29360128;
    ushort* wkqvT   = (ushort*)(ws + 29360640);
    ushort* wprm_bf = (ushort*)(ws + 29385216);
    ushort* wT3     = (ushort*)(ws + 29401600);
    ushort* kptv_bf = (ushort*)(ws + 29499904);
    float*  part    = ws + 29532672;

    hipLaunchKernelGGL(kprep, dim3(1664), dim3(256), 0, stream,
                       w_kqv, w_prm, w_proj, w_mlp1, w_mlp2, wkqvT, wprm_bf, wT3);
    hipLaunchKernelGGL(k1_mfma, dim3(2048), dim3(256), 0, stream,
                       x, g1, b1, wkqvT, b_kqv, wprm_bf, vfrag, vT_bf, kpT_bf, qp_bf);
    hipLaunchKernelGGL(k2_ksum, dim3(512), dim3(256), 0, stream, kpT_bf, ksum);
    hipLaunchKernelGGL(k3_kptv_mfma, dim3(512), dim3(256), 0, stream, vT_bf, kpT_bf, part);
    hipLaunchKernelGGL(k3r_reduce, dim3(512), dim3(256), 0, stream, part, kptv_bf);
    hipLaunchKernelGGL(k4_attn_tail, dim3(2048), dim3(256), 0, stream,
                       qp_bf, vfrag, ksum, kptv_bf, wT3, b_proj, g2, b2,
                       b_mlp1, b_mlp2, img2);
    hipLaunchKernelGGL(k6_upsample, dim3(262144), dim3(256), 0, stream, img2, out);
}

// Round 8
// 273.244 us; speedup vs baseline: 5.6995x; 1.1981x over previous
//
#include <hip/hip_runtime.h>
#include <math.h>

#define TOK   16384
#define DIM   48
#define EMB   256
#define MF    128
#define IMGsz 129

typedef __attribute__((ext_vector_type(8))) short    bf16x8;
typedef __attribute__((ext_vector_type(8))) unsigned short u16x8;
typedef __attribute__((ext_vector_type(4))) float    f32x4;

__device__ __forceinline__ ushort f2bf(float f) {
    union { float f; unsigned u; } v; v.f = f;
    unsigned u = v.u;
    return (ushort)((u + 0x7fffu + ((u >> 16) & 1u)) >> 16);   // RNE
}
__device__ __forceinline__ float bf2f(ushort h) {
    union { unsigned u; float f; } v; v.u = ((unsigned)h) << 16; return v.f;
}

// swizzles: XOR 16B-chunk index with (row&7) -> conflict-free ds_read_b128
#define SWZ512(r,c) ((r)*512 + (((((c)>>3) ^ ((r)&7))) << 3) + ((c)&7))
#define SWZ64(r,c)  ((r)*64  + (((((c)>>3) ^ ((r)&7)) & 7) << 3) + ((c)&7))
#define SWZ256(r,c) ((r)*256 + (((((c)>>3) ^ ((r)&7))) << 3) + ((c)&7))

// fragment-major dst index for B operands: lane(l4,l15) of (ntile,kc) is contiguous.
__device__ __forceinline__ int fragmajor(int n, int k, int KC) {
    return (((n >> 4)*KC + (k >> 5))*4 + ((k >> 3) & 3))*128 + (n & 15)*8 + (k & 7);
}

// ---------------- kprep: bf16 weight staging (fragment-major) --------------------
__global__ __launch_bounds__(256) void kprep(
    const float* __restrict__ w_kqv, const float* __restrict__ w_prm,
    const float* __restrict__ w_proj, const float* __restrict__ w_mlp1,
    const float* __restrict__ w_mlp2,
    ushort* __restrict__ wkqvT, ushort* __restrict__ wprm_bf, ushort* __restrict__ wT3)
{
    int blk = blockIdx.x, tid = threadIdx.x;
    if (blk < 768) {
        if (tid < 64) {
            float v = (tid < DIM) ? w_kqv[tid*768 + blk] : 0.f;
            wkqvT[fragmajor(blk, tid, 2)] = f2bf(v);
        }
    } else if (blk < 896) {
        int m = blk - 768;
        wprm_bf[fragmajor(m, tid, 8)] = f2bf(w_prm[m*256 + tid]);
    } else {
        int q = blk - 896;
        int w = q >> 8, n = q & 255;
        const float* src = (w == 0) ? w_proj : ((w == 1) ? w_mlp1 : w_mlp2);
        wT3[w*65536 + fragmajor(n, tid, 8)] = f2bf(src[tid*256 + n]);
    }
}

// ---------------- kernel 1: unfold+LN+kqv+prm via MFMA (32 tokens/block) ---------
__global__ __launch_bounds__(256, 2) void k1_mfma(
    const float* __restrict__ x, const float* __restrict__ g1, const float* __restrict__ b1,
    const ushort* __restrict__ wkqvT, const float* __restrict__ b_kqv,
    const ushort* __restrict__ wprm_bf,
    ushort* __restrict__ vfrag_out, ushort* __restrict__ vT_out,
    ushort* __restrict__ kpT_out, ushort* __restrict__ qp_out)
{
    __shared__ __align__(16) ushort kq_bf[32*512];
    __shared__ __align__(16) ushort vt_bf[32*256];
    __shared__ float xdp[4][32][2];
    __shared__ float xd2[32][2];
    __shared__ float red1[32][8], red2[32][8];
    __shared__ float mu_s[32], iv_s[32];

    float*  t_s  = (float*)kq_bf;
    ushort* h_bf = vt_bf;

    const int blk = blockIdx.x;                    // 2048
    const int b  = blk >> 9;
    const int t0 = (blk & 511) << 5;
    const int tid = threadIdx.x;
    const int wid = tid >> 6;
    const int l15 = tid & 15, l4 = (tid >> 4) & 3;

    for (int e = tid; e < 32*DIM; e += 256) {
        int tok = e / DIM, j = e - tok*DIM;
        int t = t0 + tok;
        int lh = t >> 7, lw = t & 127;
        int c = j >> 4, kh = (j >> 2) & 3, kw = j & 3;
        int ih = lh + kh - 1, iw = lw + kw - 1;
        float val = 0.f;
        if (ih >= 0 && ih < IMGsz && iw >= 0 && iw < IMGsz)
            val = x[((b*3 + c)*IMGsz + ih)*IMGsz + iw];
        t_s[tok*DIM + j] = val;
    }
    __syncthreads();

    {
        int tg = tid >> 3, sl = tid & 7;
        const float* tr = &t_s[tg*DIM + sl*6];
        float s1 = 0.f, s2 = 0.f;
        #pragma unroll
        for (int j = 0; j < 6; j++) { float a = tr[j]; s1 += a; s2 = fmaf(a, a, s2); }
        red1[tg][sl] = s1; red2[tg][sl] = s2;
        __syncthreads();
        if (tid < 32) {
            float a = 0.f, q = 0.f;
            #pragma unroll
            for (int j = 0; j < 8; j++) { a += red1[tid][j]; q += red2[tid][j]; }
            float mu = a * (1.f/DIM);
            mu_s[tid] = mu;
            iv_s[tid] = rsqrtf(q*(1.f/DIM) - mu*mu + 1e-5f);
        }
        __syncthreads();
        float mu = mu_s[tg], iv = iv_s[tg];
        #pragma unroll
        for (int j = 0; j < 6; j++) {
            int c = sl*6 + j;
            h_bf[SWZ64(tg, c)] = f2bf((tr[j]-mu)*iv*g1[c] + b1[c]);
        }
        h_bf[SWZ64(tg, 48 + sl*2    )] = 0;
        h_bf[SWZ64(tg, 48 + sl*2 + 1)] = 0;
    }
    __syncthreads();

    f32x4 acc[2][12];
    #pragma unroll
    for (int m = 0; m < 2; m++)
        #pragma unroll
        for (int j = 0; j < 12; j++) { acc[m][j][0]=0.f; acc[m][j][1]=0.f; acc[m][j][2]=0.f; acc[m][j][3]=0.f; }
    #pragma unroll
    for (int kc = 0; kc < 2; kc++) {
        int ch = ((kc*4 + l4) ^ (l15 & 7)) << 3;
        bf16x8 a0 = *(const bf16x8*)&h_bf[ l15      *64 + ch];
        bf16x8 a1 = *(const bf16x8*)&h_bf[(16 + l15)*64 + ch];
        #pragma unroll
        for (int j = 0; j < 12; j++) {
            int ntile = wid + 4*j;
            bf16x8 bb = *(const bf16x8*)&wkqvT[(((ntile*2 + kc)*4 + l4)*16 + l15)*8];
            acc[0][j] = __builtin_amdgcn_mfma_f32_16x16x32_bf16(a0, bb, acc[0][j], 0, 0, 0);
            acc[1][j] = __builtin_amdgcn_mfma_f32_16x16x32_bf16(a1, bb, acc[1][j], 0, 0, 0);
        }
    }
    __syncthreads();

    {
        float pk[2][4], pq[2][4];
        #pragma unroll
        for (int m = 0; m < 2; m++)
            #pragma unroll
            for (int r = 0; r < 4; r++) { pk[m][r] = 0.f; pq[m][r] = 0.f; }
        #pragma unroll
        for (int j = 0; j < 12; j++) {
            int col = (wid + 4*j)*16 + l15;
            float bias = b_kqv[col];
            #pragma unroll
            for (int m = 0; m < 2; m++)
                #pragma unroll
                for (int r = 0; r < 4; r++) {
                    int row = m*16 + l4*4 + r;
                    float a = acc[m][j][r] + bias;
                    if (j < 4) {
                        pk[m][r] = fmaf(a, a, pk[m][r]);
                        kq_bf[SWZ512(row, col)] = f2bf(a);
                    } else if (j < 8) {
                        pq[m][r] = fmaf(a, a, pq[m][r]);
                        kq_bf[SWZ512(row, col)] = f2bf(a);
                    } else {
                        int n = col - 512;
                        vt_bf[row*256 + n] = f2bf(a);
                    }
                }
        }
        #pragma unroll
        for (int m = 0; m < 2; m++)
            #pragma unroll
            for (int r = 0; r < 4; r++) {
                float a = pk[m][r], q = pq[m][r];
                #pragma unroll
                for (int msk = 8; msk >= 1; msk >>= 1) {
                    a += __shfl_xor(a, msk);
                    q += __shfl_xor(q, msk);
                }
                if (l15 == 0) {
                    int row = m*16 + l4*4 + r;
                    xdp[wid][row][0] = a; xdp[wid][row][1] = q;
                }
            }
    }
    __syncthreads();
    if (tid < 64) {
        int row = tid >> 1, ty = tid & 1;
        xd2[row][ty] = 0.5f*(xdp[0][row][ty] + xdp[1][row][ty] + xdp[2][row][ty] + xdp[3][row][ty]);
    }

    // ---- P4: v^T coalesced write (thread = n channel) ----
    {
        ushort* dst = vT_out + ((size_t)(b*EMB + tid))*TOK + t0;
        #pragma unroll
        for (int t8 = 0; t8 < 4; t8++) {
            u16x8 pk8;
            #pragma unroll
            for (int j = 0; j < 8; j++) pk8[j] = vt_bf[(t8*8 + j)*256 + tid];
            *(u16x8*)&dst[t8*8] = pk8;
        }
    }
    // ---- P4b: v fragment-major write (k4 residual layout) ----
    {
        u16x8 pk8[4];
        #pragma unroll
        for (int m = 0; m < 2; m++)
            #pragma unroll
            for (int nt = 0; nt < 4; nt++)
                #pragma unroll
                for (int r = 0; r < 4; r++) {
                    int row = m*16 + l4*4 + r;
                    int col = wid*64 + nt*16 + l15;
                    int idx = m*16 + nt*4 + r;
                    pk8[idx >> 3][idx & 7] = vt_bf[row*256 + col];
                }
        ushort* dst = vfrag_out + (size_t)blk*8192 + tid*32;
        #pragma unroll
        for (int i = 0; i < 4; i++) *(u16x8*)&dst[i*8] = pk8[i];
    }
    __syncthreads();

    f32x4 acc2[2][4];
    #pragma unroll
    for (int m = 0; m < 2; m++)
        #pragma unroll
        for (int n = 0; n < 4; n++) { acc2[m][n][0]=0.f; acc2[m][n][1]=0.f; acc2[m][n][2]=0.f; acc2[m][n][3]=0.f; }
    {
        const int cbase = (wid >= 2) ? 32 : 0;
        #pragma unroll
        for (int kc = 0; kc < 8; kc++) {
            int chunk = cbase + kc*4 + l4;
            int ch = (chunk ^ (l15 & 7)) << 3;
            bf16x8 a0 = *(const bf16x8*)&kq_bf[ l15      *512 + ch];
            bf16x8 a1 = *(const bf16x8*)&kq_bf[(16 + l15)*512 + ch];
            #pragma unroll
            for (int nt = 0; nt < 4; nt++) {
                int mtile = (wid & 1)*4 + nt;
                bf16x8 bb = *(const bf16x8*)&wprm_bf[(((mtile*8 + kc)*4 + l4)*16 + l15)*8];
                acc2[0][nt] = __builtin_amdgcn_mfma_f32_16x16x32_bf16(a0, bb, acc2[0][nt], 0, 0, 0);
                acc2[1][nt] = __builtin_amdgcn_mfma_f32_16x16x32_bf16(a1, bb, acc2[1][nt], 0, 0, 0);
            }
        }
    }

    {
        const float scale = 0.08838834764831845f;
        const bool isK = (wid < 2);
        #pragma unroll
        for (int m = 0; m < 2; m++)
            #pragma unroll
            for (int nt = 0; nt < 4; nt++) {
                #pragma unroll
                for (int r = 0; r < 4; r++) {
                    int row = m*16 + l4*4 + r;
                    int mcol = (wid & 1)*64 + nt*16 + l15;
                    float e = expf(acc2[m][nt][r] - xd2[row][isK ? 0 : 1]) * scale;
                    ushort bf = f2bf(e);
                    if (isK) vt_bf[row*256 + mcol] = bf;
                    else qp_out[(size_t)(b*TOK + t0 + row)*MF + mcol] = bf;
                }
            }
    }
    __syncthreads();

    if (tid < 128) {
        ushort* dst = kpT_out + ((size_t)(b*MF + tid))*TOK + t0;
        #pragma unroll
        for (int t8 = 0; t8 < 4; t8++) {
            u16x8 pk8;
            #pragma unroll
            for (int j = 0; j < 8; j++) pk8[j] = vt_bf[(t8*8 + j)*256 + tid];
            *(u16x8*)&dst[t8*8] = pk8;
        }
    }
}

// ---------------- kernel 2: ksum[b][m] = row-sum of kp^T ------------------------
__global__ __launch_bounds__(256) void k2_ksum(const ushort* __restrict__ kpT, float* __restrict__ ksum)
{
    __shared__ float red[4];
    int blk = blockIdx.x;
    int b = blk >> 7, m = blk & 127;
    int tid = threadIdx.x;
    const ushort* row = kpT + (size_t)(b*MF + m)*TOK;
    float s = 0.f;
    for (int i = tid; i < TOK/8; i += 256) {
        u16x8 v = *(const u16x8*)&row[i*8];
        #pragma unroll
        for (int j = 0; j < 8; j++) s += bf2f(v[j]);
    }
    #pragma unroll
    for (int msk = 32; msk >= 1; msk >>= 1) s += __shfl_xor(s, msk);
    if ((tid & 63) == 0) red[tid >> 6] = s;
    __syncthreads();
    if (tid == 0) ksum[b*MF + m] = red[0] + red[1] + red[2] + red[3];
}

// ---------------- kernel 3: kptv partials via MFMA (32 K-chunks of 512) ----------
__global__ __launch_bounds__(256) void k3_kptv_mfma(
    const ushort* __restrict__ vT, const ushort* __restrict__ kpT, float* __restrict__ part)
{
    int blk = blockIdx.x;            // 256: b(2b) | ns(1b) | kc(5b)
    int b = blk >> 6, ns = (blk >> 5) & 1, kc = blk & 31;
    const int tid = threadIdx.x;
    const int wid = tid >> 6;
    const int l15 = tid & 15, l4 = (tid >> 4) & 3;
    const int t0 = kc * 512;
    const int n0 = ns*128 + wid*32;

    f32x4 acc[2][8];
    #pragma unroll
    for (int m = 0; m < 2; m++)
        #pragma unroll
        for (int n = 0; n < 8; n++) { acc[m][n][0]=0.f; acc[m][n][1]=0.f; acc[m][n][2]=0.f; acc[m][n][3]=0.f; }

    #pragma unroll
    for (int ks = 0; ks < 16; ks++) {
        int k0 = t0 + ks*32 + l4*8;
        bf16x8 a0 = *(const bf16x8*)&vT[((size_t)(b*EMB + n0      + l15))*TOK + k0];
        bf16x8 a1 = *(const bf16x8*)&vT[((size_t)(b*EMB + n0 + 16 + l15))*TOK + k0];
        #pragma unroll
        for (int nt = 0; nt < 8; nt++) {
            bf16x8 bb = *(const bf16x8*)&kpT[((size_t)(b*MF + nt*16 + l15))*TOK + k0];
            acc[0][nt] = __builtin_amdgcn_mfma_f32_16x16x32_bf16(a0, bb, acc[0][nt], 0, 0, 0);
            acc[1][nt] = __builtin_amdgcn_mfma_f32_16x16x32_bf16(a1, bb, acc[1][nt], 0, 0, 0);
        }
    }
    #pragma unroll
    for (int mt = 0; mt < 2; mt++)
        #pragma unroll
        for (int nt = 0; nt < 8; nt++) {
            int n = n0 + mt*16 + l4*4;
            int m = nt*16 + l15;
            #pragma unroll
            for (int r = 0; r < 4; r++)
                part[(size_t)kc*131072 + (size_t)((b*EMB + n + r)*MF + m)] = acc[mt][nt][r];
        }
}

// ---------------- kernel 3r: reduce partials -> kptv f32 -------------------------
__global__ __launch_bounds__(256) void k3r_reduce(const float* __restrict__ part, float* __restrict__ kptv)
{
    int e = blockIdx.x*256 + threadIdx.x;   // 131072 = 4b x 256n x 128m
    float s = 0.f;
    #pragma unroll 8
    for (int kc = 0; kc < 32; kc++) s += part[(size_t)kc*131072 + e];
    kptv[e] = s;
}

// ---------------- kernel 3c: C[b][m][n2] = kptv^T @ w_proj -> bf16 frag-major ----
__global__ __launch_bounds__(256) void k3c_combine(
    const float* __restrict__ kptv, const float* __restrict__ w_proj, ushort* __restrict__ C_bf)
{
    __shared__ float kp_s[256][8];
    int blk = blockIdx.x;            // 64: b(2b) | mg(4b)
    int b = blk >> 4, m0 = (blk & 15)*8;
    int tid = threadIdx.x;

    #pragma unroll
    for (int pass = 0; pass < 8; pass++) {
        int n1 = pass*32 + (tid >> 3);
        kp_s[n1][tid & 7] = kptv[b*32768 + n1*128 + m0 + (tid & 7)];
    }
    __syncthreads();

    float acc[8];
    #pragma unroll
    for (int j = 0; j < 8; j++) acc[j] = 0.f;
    for (int n1 = 0; n1 < 256; n1++) {
        float w = w_proj[n1*256 + tid];
        #pragma unroll
        for (int j = 0; j < 8; j++) acc[j] = fmaf(kp_s[n1][j], w, acc[j]);
    }
    // fragment-major write: contiguous 8 ushorts per thread (k = m0..m0+7)
    u16x8 pk;
    #pragma unroll
    for (int j = 0; j < 8; j++) pk[j] = f2bf(acc[j]);
    int base = (((tid >> 4)*4 + (m0 >> 5))*4 + ((m0 >> 3) & 3))*128 + (tid & 15)*8;
    *(u16x8*)&C_bf[b*32768 + base] = pk;
}

// ---------------- kernel 4 v6: 3 GEMMs (proj fused into C), /D in epilogue -------
template<int K>
__device__ __forceinline__ void gemm32(const ushort* A_s, const ushort* __restrict__ B,
                                       f32x4 acc[2][4], int l15, int l4, int wid)
{
    __builtin_amdgcn_s_setprio(1);
    #pragma unroll
    for (int kc = 0; kc < (K >> 5); kc++) {
        const int ch = ((kc*4 + l4) ^ (l15 & 7)) << 3;
        bf16x8 a0 = *(const bf16x8*)&A_s[ l15      *256 + ch];
        bf16x8 a1 = *(const bf16x8*)&A_s[(16 + l15)*256 + ch];
        #pragma unroll
        for (int nt = 0; nt < 4; nt++) {
            int ntile = wid*4 + nt;
            bf16x8 bb = *(const bf16x8*)&B[(((ntile*(K >> 5) + kc)*4 + l4)*16 + l15)*8];
            acc[0][nt] = __builtin_amdgcn_mfma_f32_16x16x32_bf16(a0, bb, acc[0][nt], 0, 0, 0);
            acc[1][nt] = __builtin_amdgcn_mfma_f32_16x16x32_bf16(a1, bb, acc[1][nt], 0, 0, 0);
        }
    }
    __builtin_amdgcn_s_setprio(0);
}

__global__ __launch_bounds__(256, 4) void k4_attn_tail(
    const ushort* __restrict__ qp, const ushort* __restrict__ vfrag,
    const float* __restrict__ ksum, const ushort* __restrict__ C_bf,
    const ushort* __restrict__ wT,
    const float* __restrict__ b_proj,
    const float* __restrict__ g2, const float* __restrict__ b2,
    const float* __restrict__ b_mlp1, const float* __restrict__ b_mlp2,
    float* __restrict__ img2)
{
    __shared__ __align__(16) ushort A_s[16448];    // 32.9 KB
    __shared__ float D_s[32];
    __shared__ float redD[32][8];
    __shared__ float red1[4][32], red2[4][32];
    __shared__ float mu_s[32], iv_s[32];

    const int blk = blockIdx.x;                    // 2048
    const int b  = blk >> 9;
    const int t0 = (blk & 511) << 5;               // 32 tokens/block
    const int tid = threadIdx.x;
    const int wid = tid >> 6;
    const int lane = tid & 63;
    const int l15 = lane & 15, l4 = lane >> 4;

    // ---- prefetch: v residual fragments + b_proj ----
    u16x8 vreg[4];
    {
        const ushort* vf = vfrag + (size_t)blk*8192 + tid*32;
        #pragma unroll
        for (int i = 0; i < 4; i++) vreg[i] = *(const u16x8*)&vf[i*8];
    }
    float bp[4];
    #pragma unroll
    for (int nt = 0; nt < 4; nt++) bp[nt] = b_proj[wid*64 + nt*16 + l15];

    // ---- stage qp (bf16 swizzled copy) + D = qp . ksum ----
    {
        int tk = tid >> 3, seg = tid & 7;
        const ushort* qrow = qp + (size_t)(b*TOK + t0 + tk)*MF + seg*16;
        u16x8 q0 = *(const u16x8*)&qrow[0];
        u16x8 q1 = *(const u16x8*)&qrow[8];
        const float* ks = ksum + b*MF + seg*16;
        float dd = 0.f;
        #pragma unroll
        for (int j = 0; j < 8; j++) {
            dd = fmaf(bf2f(q0[j]), ks[j],   dd);
            dd = fmaf(bf2f(q1[j]), ks[j+8], dd);
        }
        redD[tk][seg] = dd;
        int xr = tk & 7;
        *(u16x8*)&A_s[tk*256 + (((seg*2  ) ^ xr) << 3)] = q0;
        *(u16x8*)&A_s[tk*256 + (((seg*2+1) ^ xr) << 3)] = q1;
    }
    __syncthreads();
    if (tid < 32) {
        float s = 0.f;
        #pragma unroll
        for (int j = 0; j < 8; j++) s += redD[tid][j];
        D_s[tid] = s + 1e-8f;
    }

    f32x4 acc[2][4];
    #define ZACC() { _Pragma("unroll") for (int m_=0;m_<2;m_++) _Pragma("unroll") for (int n_=0;n_<4;n_++) { acc[m_][n_][0]=0.f;acc[m_][n_][1]=0.f;acc[m_][n_][2]=0.f;acc[m_][n_][3]=0.f; } }

    // ---- GEMMc: y2 = (qp @ C)/D + b_proj + v   (C = kptv^T @ w_proj, K=128) ----
    ZACC();
    gemm32<MF>(A_s, C_bf + (size_t)b*32768, acc, l15, l4, wid);
    __syncthreads();                               // D_s visible; qp reads done
    float y2[2][4][4];
    #pragma unroll
    for (int nt = 0; nt < 4; nt++) {
        #pragma unroll
        for (int m = 0; m < 2; m++)
            #pragma unroll
            for (int r = 0; r < 4; r++) {
                int row = m*16 + l4*4 + r;
                int idx = m*16 + nt*4 + r;
                y2[m][nt][r] = acc[m][nt][r]/D_s[row] + bp[nt] + bf2f(vreg[idx >> 3][idx & 7]);
            }
    }

    // ---- LayerNorm(y2): shfl over l15 + cross-wave LDS ----
    {
        #pragma unroll
        for (int m = 0; m < 2; m++)
            #pragma unroll
            for (int r = 0; r < 4; r++) {
                float s1 = 0.f, s2 = 0.f;
                #pragma unroll
                for (int nt = 0; nt < 4; nt++) {
                    float a = y2[m][nt][r];
                    s1 += a; s2 = fmaf(a, a, s2);
                }
                #pragma unroll
                for (int msk = 8; msk >= 1; msk >>= 1) {
                    s1 += __shfl_xor(s1, msk);
                    s2 += __shfl_xor(s2, msk);
                }
                if (l15 == 0) {
                    int row = m*16 + l4*4 + r;
                    red1[wid][row] = s1; red2[wid][row] = s2;
                }
            }
        __syncthreads();
        if (tid < 32) {
            float a = red1[0][tid] + red1[1][tid] + red1[2][tid] + red1[3][tid];
            float q = red2[0][tid] + red2[1][tid] + red2[2][tid] + red2[3][tid];
            float mu = a * (1.f/EMB);
            mu_s[tid] = mu;
            iv_s[tid] = rsqrtf(q*(1.f/EMB) - mu*mu + 1e-5f);
        }
        __syncthreads();
        #pragma unroll
        for (int nt = 0; nt < 4; nt++) {
            int col = wid*64 + nt*16 + l15;
            float gg = g2[col], bb = b2[col];
            #pragma unroll
            for (int m = 0; m < 2; m++)
                #pragma unroll
                for (int r = 0; r < 4; r++) {
                    int row = m*16 + l4*4 + r;
                    A_s[SWZ256(row, col)] = f2bf((y2[m][nt][r] - mu_s[row])*iv_s[row]*gg + bb);
                }
        }
    }
    __syncthreads();

    // ---- GEMM3: h1 = gelu(z @ w_mlp1 + b_mlp1) ----
    ZACC();
    gemm32<EMB>(A_s, wT + 65536, acc, l15, l4, wid);
    __syncthreads();
    #pragma unroll
    for (int nt = 0; nt < 4; nt++) {
        int col = wid*64 + nt*16 + l15;
        float bm = b_mlp1[col];
        #pragma unroll
        for (int m = 0; m < 2; m++)
            #pragma unroll
            for (int r = 0; r < 4; r++) {
                int row = m*16 + l4*4 + r;
                float a = acc[m][nt][r] + bm;
                A_s[SWZ256(row, col)] = f2bf(0.5f*a*(1.f + erff(a*0.70710678118654752f)));
            }
    }
    __syncthreads();

    // ---- GEMM4: y3 = y2 + h1 @ w_mlp2 + b_mlp2 ----
    ZACC();
    gemm32<EMB>(A_s, wT + 131072, acc, l15, l4, wid);
    #pragma unroll
    for (int nt = 0; nt < 4; nt++) {
        int col = wid*64 + nt*16 + l15;
        float bm = b_mlp2[col];
        #pragma unroll
        for (int m = 0; m < 2; m++)
            #pragma unroll
            for (int r = 0; r < 4; r++)
                y2[m][nt][r] += acc[m][nt][r] + bm;
    }
    __syncthreads();

    // ---- output: stage f32 [32][257], coalesced channel-major write ----
    float* A_f = (float*)A_s;
    #pragma unroll
    for (int nt = 0; nt < 4; nt++) {
        int col = wid*64 + nt*16 + l15;
        #pragma unroll
        for (int m = 0; m < 2; m++)
            #pragma unroll
            for (int r = 0; r < 4; r++)
                A_f[(m*16 + l4*4 + r)*257 + col] = y2[m][nt][r];
    }
    __syncthreads();
    {
        int tq = tid & 7, cb = tid >> 3;
        #pragma unroll
        for (int pass = 0; pass < 8; pass++) {
            int c = pass*32 + cb;
            f32x4 pk;
            #pragma unroll
            for (int j = 0; j < 4; j++) pk[j] = A_f[(tq*4 + j)*257 + c];
            *(f32x4*)&img2[((size_t)(b*EMB + c))*TOK + t0 + tq*4] = pk;
        }
    }
}

// ---------------- kernel 6: bilinear upsample x2 (4 outputs/thread) --------------
__global__ __launch_bounds__(256) void k6_upsample(const float* __restrict__ img2, float* __restrict__ out)
{
    int idx = blockIdx.x*256 + threadIdx.x;       // 16,777,216 threads
    int wq = idx & 63;
    int ho = (idx >> 6) & 255;
    int c  = (idx >> 14) & 255;
    int b  = idx >> 22;
    const float sc = 127.f/255.f;
    float fh = ho * sc; int h0 = (int)fh; if (h0 > 126) h0 = 126; float th = fh - h0;
    int wo = wq*4;
    int w0[4]; float tw[4];
    #pragma unroll
    for (int j = 0; j < 4; j++) {
        float fw = (wo + j) * sc;
        int w = (int)fw; if (w > 126) w = 126;
        w0[j] = w; tw[j] = fw - w;
    }
    int wsrt = w0[0] > 124 ? 124 : w0[0];
    const float* p = img2 + (((size_t)(b*EMB + c))*128 + h0)*128 + wsrt;
    f32x4 r0 = *(const f32x4*)p;
    f32x4 r1 = *(const f32x4*)(p + 128);
    f32x4 o;
    #pragma unroll
    for (int j = 0; j < 4; j++) {
        int i = w0[j] - wsrt;                     // 0..2
        float a00 = (i == 0) ? r0[0] : ((i == 1) ? r0[1] : r0[2]);
        float a01 = (i == 0) ? r0[1] : ((i == 1) ? r0[2] : r0[3]);
        float a10 = (i == 0) ? r1[0] : ((i == 1) ? r1[1] : r1[2]);
        float a11 = (i == 0) ? r1[1] : ((i == 1) ? r1[2] : r1[3]);
        float top = fmaf(a01 - a00, tw[j], a00);
        float bot = fmaf(a11 - a10, tw[j], a10);
        o[j] = fmaf(bot - top, th, top);
    }
    *(f32x4*)&out[(size_t)idx*4] = o;
}

extern "C" void kernel_launch(void* const* d_in, const int* in_sizes, int n_in,
                              void* d_out, int out_size, void* d_ws, size_t ws_size,
                              hipStream_t stream)
{
    const float* x      = (const float*)d_in[0];
    const float* g1     = (const float*)d_in[1];
    const float* b1     = (const float*)d_in[2];
    const float* w_kqv  = (const float*)d_in[3];
    const float* b_kqv  = (const float*)d_in[4];
    const float* w_prm  = (const float*)d_in[5];
    const float* w_proj = (const float*)d_in[6];
    const float* b_proj = (const float*)d_in[7];
    const float* g2     = (const float*)d_in[8];
    const float* b2     = (const float*)d_in[9];
    const float* w_mlp1 = (const float*)d_in[10];
    const float* b_mlp1 = (const float*)d_in[11];
    const float* w_mlp2 = (const float*)d_in[12];
    const float* b_mlp2 = (const float*)d_in[13];
    float* out = (float*)d_out;
    float* ws  = (float*)d_ws;

    ushort* vfrag    = (ushort*)(ws);              //  8,388,608 slots
    ushort* qp_bf    = (ushort*)(ws + 8388608);    //  4,194,304 slots
    ushort* vT_bf    = (ushort*)(ws + 12582912);   //  8,388,608 slots
    ushort* kpT_bf   = (ushort*)(ws + 20971520);   //  4,194,304 slots
    float*  img2     = ws + 12582912;              // overlays vT+kpT (dead after k3)
    float*  ksum     = ws + 29360128;              //        512
    ushort* wkqvT    = (ushort*)(ws + 29360640);   //     24,576 slots
    ushort* wprm_bf  = (ushort*)(ws + 29385216);   //     16,384 slots
    ushort* wT3      = (ushort*)(ws + 29401600);   //     98,304 slots
    float*  kptv_f32 = ws + 29499904;              //    131,072 slots
    ushort* C_bf     = (ushort*)(ws + 29630976);   //     65,536 slots
    float*  part     = ws + 29696512;              //  4,194,304 slots (ends 33,890,816)

    hipLaunchKernelGGL(kprep, dim3(1664), dim3(256), 0, stream,
                       w_kqv, w_prm, w_proj, w_mlp1, w_mlp2, wkqvT, wprm_bf, wT3);
    hipLaunchKernelGGL(k1_mfma, dim3(2048), dim3(256), 0, stream,
                       x, g1, b1, wkqvT, b_kqv, wprm_bf, vfrag, vT_bf, kpT_bf, qp_bf);
    hipLaunchKernelGGL(k2_ksum, dim3(512), dim3(256), 0, stream, kpT_bf, ksum);
    hipLaunchKernelGGL(k3_kptv_mfma, dim3(256), dim3(256), 0, stream, vT_bf, kpT_bf, part);
    hipLaunchKernelGGL(k3r_reduce, dim3(512), dim3(256), 0, stream, part, kptv_f32);
    hipLaunchKernelGGL(k3c_combine, dim3(64), dim3(256), 0, stream, kptv_f32, w_proj, C_bf);
    hipLaunchKernelGGL(k4_attn_tail, dim3(2048), dim3(256), 0, stream,
                       qp_bf, vfrag, ksum, C_bf, wT3, b_proj, g2, b2,
                       b_mlp1, b_mlp2, img2);
    hipLaunchKernelGGL(k6_upsample, dim3(65536), dim3(256), 0, stream, img2, out);
}